// Round 10
// baseline (677.685 us; speedup 1.0000x reference)
//
#include <hip/hip_runtime.h>

#define RELU(x) fmaxf((x), 0.0f)

typedef __attribute__((ext_vector_type(2))) float f32x2;
typedef __attribute__((ext_vector_type(4))) short short4v;
typedef __attribute__((ext_vector_type(8))) short short8v;
typedef __attribute__((ext_vector_type(16))) float f32x16;

__device__ __forceinline__ float bf2f(unsigned short u) {
  unsigned v = ((unsigned)u) << 16;
  float f; __builtin_memcpy(&f, &v, 4); return f;
}
__device__ __forceinline__ unsigned short f2bf(float f) {
  unsigned u; __builtin_memcpy(&u, &f, 4);
  unsigned r = (u + 0x7FFFu + ((u >> 16) & 1u)) >> 16;
  return (unsigned short)r;
}
// HW packed convert: dst = {lo: bf16(a), hi: bf16(b)} (RNE).
__device__ __forceinline__ unsigned cvtpk(float a, float b) {
  unsigned r;
  asm("v_cvt_pk_bf16_f32 %0, %1, %2" : "=v"(r) : "v"(a), "v"(b));
  return r;
}
// packed f32 add (gfx90a+): one instruction, two adds.
__device__ __forceinline__ f32x2 pk_add(f32x2 a, f32x2 b) {
  f32x2 d;
  asm("v_pk_add_f32 %0, %1, %2" : "=v"(d) : "v"(a), "v"(b));
  return d;
}
// unpack uint (2 bf16) -> f32 pair: lo = u<<16, hi = u & 0xFFFF0000.
__device__ __forceinline__ f32x2 unpk(unsigned u) {
  unsigned lo = u << 16, hi = u & 0xFFFF0000u;
  float fx, fy;
  __builtin_memcpy(&fx, &lo, 4);
  __builtin_memcpy(&fy, &hi, 4);
  f32x2 r = {fx, fy};
  return r;
}

#define PREPB 512

__device__ __forceinline__ void gridbar(int* bar, int phase) {
  __syncthreads();
  if (threadIdx.x == 0) {
    __threadfence();
    __hip_atomic_fetch_add(bar, 1, __ATOMIC_ACQ_REL, __HIP_MEMORY_SCOPE_AGENT);
    while (__hip_atomic_load(bar, __ATOMIC_ACQUIRE, __HIP_MEMORY_SCOPE_AGENT) <
           PREPB * phase)
      __builtin_amdgcn_s_sleep(2);
  }
  __syncthreads();
}

// ---------------------------------------------------------------------------
// prep: ONE persistent kernel (512 blocks co-resident via launch_bounds):
// P0 deg histogram + weight repack | P1 per-block deg sums | P2 block-offset
// scan | P3 per-block exclusive scan -> ptr/wptr | P4 scatter + node_pre MFMA.
// Requires ceil(N/PREPB) <= 256 (N <= 131072).
// ---------------------------------------------------------------------------
__global__ __launch_bounds__(256, 2) void prep_kernel(
    const int* __restrict__ row, const int* __restrict__ col, int E,
    const float* __restrict__ We1, const float* __restrict__ Wv1,
    const float* __restrict__ We2, const float* __restrict__ Wc1,
    const float* __restrict__ Wn1, const float* __restrict__ Wn2,
    unsigned short* __restrict__ WF,
    const float* __restrict__ h,
    const float* __restrict__ be1, const float* __restrict__ bv1,
    const float* __restrict__ Wv2, const float* __restrict__ bv2,
    float* __restrict__ Hr, float* __restrict__ Hc, float* __restrict__ velfac,
    int* __restrict__ deg, int* bar, int* __restrict__ ptr,
    int* __restrict__ wptr, int* __restrict__ rowS, int* __restrict__ colS,
    int* __restrict__ bsum, int* __restrict__ boff, int N)
{
  const int t = threadIdx.x;
  const int bid = blockIdx.x;
  const int gsz = PREPB * 256;
  const int gtid = bid * 256 + t;

  __shared__ __align__(16) unsigned short Ah[4096];
  __shared__ float Wv2s[128];
  __shared__ float vpart[32][4];
  __shared__ int sc[2][512];

  // ---- P0: deg histogram + weight repack ----
  for (int i = gtid; i < E; i += gsz) atomicAdd(&deg[row[i]], 1);
  for (int gi = gtid; gi < 8 * 16384; gi += gsz) {
    const int g = gi >> 14, idx = gi & 16383;
    const float* W;
    switch (g) {
      case 0: W = We1; break;
      case 1: W = We1 + 16384; break;
      case 2: W = Wv1; break;
      case 3: W = We2; break;
      case 4: W = Wc1; break;
      case 5: W = Wn1; break;
      case 6: W = Wn1 + 16384; break;
      default: W = Wn2; break;
    }
    int j = idx & 7, l = (idx >> 3) & 63, s = (idx >> 9) & 7, n = idx >> 12;
    WF[gi] = f2bf(W[(size_t)(s * 16 + ((l >> 5) << 3) + j) * 128 + (n * 32 + (l & 31))]);
  }
  gridbar(bar, 1);

  // ---- P1: per-block deg chunk sums ----
  const int C = (N + PREPB - 1) / PREPB;   // <= 256
  const int blo = bid * C;
  const int cnt = (N - blo < C) ? (N - blo) : C;  // may be <= 0
  {
    sc[0][t] = (t < cnt) ? deg[blo + t] : 0;
    __syncthreads();
    for (int off2 = 128; off2 >= 1; off2 >>= 1) {
      if (t < off2) sc[0][t] += sc[0][t + off2];
      __syncthreads();
    }
    if (t == 0) bsum[bid] = sc[0][0];
  }
  gridbar(bar, 2);

  // ---- P2: block 0 exclusive-scans bsum[512] -> boff ----
  if (bid == 0) {
    sc[0][t] = bsum[t];
    sc[0][t + 256] = bsum[t + 256];
    __syncthreads();
    int src = 0;
    for (int off2 = 1; off2 < 512; off2 <<= 1) {
      const int d = src ^ 1;
      for (int idx = t; idx < 512; idx += 256) {
        int v = sc[src][idx];
        if (idx >= off2) v += sc[src][idx - off2];
        sc[d][idx] = v;
      }
      __syncthreads();
      src ^= 1;
    }
    for (int idx = t; idx < 512; idx += 256)
      boff[idx] = idx ? sc[src][idx - 1] : 0;
  }
  gridbar(bar, 3);

  // ---- P3: per-block exclusive scan of deg chunk -> ptr/wptr ----
  {
    sc[0][t] = (t < cnt) ? deg[blo + t] : 0;
    __syncthreads();
    int src = 0;
    for (int off2 = 1; off2 < 256; off2 <<= 1) {
      const int d = src ^ 1;
      int v = sc[src][t];
      if (t >= off2) v += sc[src][t - off2];
      sc[d][t] = v;
      __syncthreads();
      src ^= 1;
    }
    if (t < cnt) {
      int ex = boff[bid] + (t ? sc[src][t - 1] : 0);
      ptr[blo + t] = ex;
      wptr[blo + t] = ex;
    }
    if (bid == 0 && t == 0) ptr[N] = E;
  }
  gridbar(bar, 4);

  // ---- P4: scatter (sorted rowS/colS) + node_pre MFMA ----
  for (int i = gtid; i < E; i += gsz) {
    int r = row[i];
    int pos = atomicAdd(&wptr[r], 1);
    rowS[pos] = r;
    colS[pos] = col[i];
  }
  if (t < 128) Wv2s[t] = Wv2[t];
  const int wv = t >> 6, lane = t & 63;
  const int eA = lane & 31, khalf = (lane >> 5) << 3, swA = eA << 2;
  const int baseA = eA << 7;
  const unsigned short* b1 = WF + ((wv << 12) | (lane << 3));
  const unsigned short* b2 = b1 + 16384;
  const unsigned short* b3 = b1 + 2 * 16384;
  const int colb = (wv << 5) | (lane & 31);
  const int ebase2 = (lane >> 5) << 2;
  const int ntiles = (N + 31) / 32;
  for (int tile = bid; tile < ntiles; tile += PREPB) {
    const int n0 = tile * 32;
    {
      const int e = t >> 3, kc = (t & 7) << 4;
      const int n = n0 + e;
      unsigned pk[8];
      if (n < N) {
        const float* hp = h + (size_t)n * 128 + kc;
        #pragma unroll
        for (int qc = 0; qc < 4; ++qc) {
          float4 v = *(const float4*)(hp + qc * 4);
          pk[qc * 2] = cvtpk(v.x, v.y); pk[qc * 2 + 1] = cvtpk(v.z, v.w);
        }
      } else {
        #pragma unroll
        for (int q = 0; q < 8; ++q) pk[q] = 0u;
      }
      const int sw = e << 2, rb = e << 7;
      #pragma unroll
      for (int q = 0; q < 4; ++q)
        *(uint2*)&Ah[rb + ((kc + 4 * q) ^ sw)] = make_uint2(pk[2 * q], pk[2 * q + 1]);
    }
    __syncthreads();
    f32x16 aR = {0.f}, aC = {0.f}, aV = {0.f};
    #pragma unroll
    for (int s = 0; s < 8; ++s) {
      const int k1 = s * 16 + khalf;
      short4v a0 = *(const short4v*)&Ah[baseA + (k1 ^ swA)];
      short4v a1 = *(const short4v*)&Ah[baseA + ((k1 + 4) ^ swA)];
      short8v z = __builtin_shufflevector(a0, a1, 0, 1, 2, 3, 4, 5, 6, 7);
      aR = __builtin_amdgcn_mfma_f32_32x32x16_bf16(z, *(const short8v*)(b1 + (s << 9)), aR, 0, 0, 0);
      aC = __builtin_amdgcn_mfma_f32_32x32x16_bf16(z, *(const short8v*)(b2 + (s << 9)), aC, 0, 0, 0);
      aV = __builtin_amdgcn_mfma_f32_32x32x16_bf16(z, *(const short8v*)(b3 + (s << 9)), aV, 0, 0, 0);
    }
    const float be1j = be1[colb], bv1j = bv1[colb], wv2j = Wv2s[colb];
    #pragma unroll
    for (int r = 0; r < 16; ++r) {
      const int e = (r & 3) + 8 * (r >> 2) + ebase2;
      const int n = n0 + e;
      if (n < N) {
        Hr[(size_t)n * 128 + colb] = aR[r] + be1j;
        Hc[(size_t)n * 128 + colb] = aC[r];
      }
      float v = RELU(aV[r] + bv1j) * wv2j;
      v += __shfl_xor(v, 1); v += __shfl_xor(v, 2); v += __shfl_xor(v, 4);
      v += __shfl_xor(v, 8); v += __shfl_xor(v, 16);
      if ((lane & 31) == 0) vpart[e][wv] = v;
    }
    __syncthreads();
    if (t < 32) {
      const int n = n0 + t;
      if (n < N)
        velfac[n] = vpart[t][0] + vpart[t][1] + vpart[t][2] + vpart[t][3] + bv2[0];
    }
    __syncthreads();
  }
}

// ---------------------------------------------------------------------------
// Edge kernel (MFMA) — R9 structure verbatim (303 µs proven).
// ---------------------------------------------------------------------------
#define ET 32

__global__ __launch_bounds__(256) void edge_mfma_kernel(
    const int* __restrict__ rowS, const int* __restrict__ colS,
    const float* __restrict__ Hr, const float* __restrict__ Hc,
    const float* __restrict__ coord, const float* __restrict__ vel,
    const float* __restrict__ We1,
    const unsigned short* __restrict__ WFe2,
    const unsigned short* __restrict__ WFc1,
    const float* __restrict__ be2, const float* __restrict__ bc1,
    const float* __restrict__ Wc2,
    unsigned short* __restrict__ efbuf, float* __restrict__ transbuf,
    int lo, int hi)
{
  const int t    = threadIdx.x;
  const int wv   = t >> 6;
  const int lane = t & 63;
  const int iblk = lo + blockIdx.x * ET;

  __shared__ __align__(16) unsigned short Z4[4 * 4096];
  __shared__ __align__(16) float Wc2s[256];
  __shared__ float ped[11][32];
  __shared__ int rs[32], cs[32];
  __shared__ float cmE[32][2];

  if (t < ET) {
    int i = iblk + t;
    int r = 0, c = 0;
    if (i < hi) { r = rowS[i]; c = colS[i]; }
    rs[t] = r; cs[t] = c;
    float crx = coord[2 * r], cry = coord[2 * r + 1];
    float ccx = coord[2 * c], ccy = coord[2 * c + 1];
    ped[0][t] = crx; ped[1][t] = cry; ped[2][t] = ccx; ped[3][t] = ccy;
    ped[4][t] = vel[2 * r]; ped[5][t] = vel[2 * r + 1];
    ped[6][t] = vel[2 * c]; ped[7][t] = vel[2 * c + 1];
    float dx = crx - ccx, dy = cry - ccy;
    ped[8][t] = dx; ped[9][t] = dy; ped[10][t] = dx * dx + dy * dy;
  }
  Wc2s[t] = Wc2[t];
  __syncthreads();

  {
    const int kq = t & 31;
    const int eg = t >> 5;
    const int kc = kq << 2;
    float4 w0 = *(const float4*)&We1[(size_t)(256 + 0) * 128 + kc];
    float4 w1 = *(const float4*)&We1[(size_t)(256 + 1) * 128 + kc];
    float4 w2 = *(const float4*)&We1[(size_t)(256 + 2) * 128 + kc];
    float4 w3 = *(const float4*)&We1[(size_t)(256 + 3) * 128 + kc];
    float4 w4 = *(const float4*)&We1[(size_t)(256 + 4) * 128 + kc];
    float4 w5 = *(const float4*)&We1[(size_t)(256 + 5) * 128 + kc];
    float4 w6 = *(const float4*)&We1[(size_t)(256 + 6) * 128 + kc];
    float4 w7 = *(const float4*)&We1[(size_t)(256 + 7) * 128 + kc];
    float4 w8 = *(const float4*)&We1[(size_t)(256 + 8) * 128 + kc];
    float wa0[4] = {w0.x, w0.y, w0.z, w0.w};
    float wa1[4] = {w1.x, w1.y, w1.z, w1.w};
    float wa2[4] = {w2.x, w2.y, w2.z, w2.w};
    float wa3[4] = {w3.x, w3.y, w3.z, w3.w};
    float wa4[4] = {w4.x, w4.y, w4.z, w4.w};
    float wa5[4] = {w5.x, w5.y, w5.z, w5.w};
    float wa6[4] = {w6.x, w6.y, w6.z, w6.w};
    float wa7[4] = {w7.x, w7.y, w7.z, w7.w};
    float wa8[4] = {w8.x, w8.y, w8.z, w8.w};
    #pragma unroll
    for (int ee = 0; ee < 4; ++ee) {
      const int e = (eg << 2) + ee;
      const int r = rs[e], c = cs[e];
      float4 h4 = *(const float4*)(Hr + (size_t)r * 128 + kc);
      float4 c4 = *(const float4*)(Hc + (size_t)c * 128 + kc);
      float hb[4] = {h4.x, h4.y, h4.z, h4.w};
      float cb[4] = {c4.x, c4.y, c4.z, c4.w};
      const float xr = ped[0][e], yr = ped[1][e], xc = ped[2][e], yc = ped[3][e];
      const float vrx = ped[4][e], vry = ped[5][e], vcx = ped[6][e], vcy = ped[7][e];
      const float d2 = ped[10][e];
      float z0[4], z1[4], z2[4], z3[4];
      #pragma unroll
      for (int m = 0; m < 4; ++m) {
        float base = fmaf(d2, wa4[m], hb[m] + cb[m]);
        float A = fmaf(xr, wa0[m], fmaf(xc, wa2[m], fmaf(vrx, wa5[m], vcx * wa7[m])));
        float B = fmaf(yr, wa1[m], fmaf(yc, wa3[m], fmaf(vry, wa6[m], vcy * wa8[m])));
        float bp = base + A, bm = base - A;
        z0[m] = RELU(bp + B);
        z1[m] = RELU(bm - B);
        z2[m] = RELU(bm + B);
        z3[m] = RELU(bp - B);
      }
      const int ia = (e << 7) + (kc ^ (e << 2));
      *(uint2*)&Z4[ia]         = make_uint2(cvtpk(z0[0], z0[1]), cvtpk(z0[2], z0[3]));
      *(uint2*)&Z4[4096 + ia]  = make_uint2(cvtpk(z1[0], z1[1]), cvtpk(z1[2], z1[3]));
      *(uint2*)&Z4[8192 + ia]  = make_uint2(cvtpk(z2[0], z2[1]), cvtpk(z2[2], z2[3]));
      *(uint2*)&Z4[12288 + ia] = make_uint2(cvtpk(z3[0], z3[1]), cvtpk(z3[2], z3[3]));
    }
  }
  __syncthreads();

  const int eA    = lane & 31;
  const int khalf = (lane >> 5) << 3;
  const int swA   = eA << 2;
  const int baseA = eA << 7;
  f32x16 ac0 = {0.f}, ac1 = {0.f}, ac2 = {0.f}, ac3 = {0.f};
  {
    const unsigned short* WFw = WFe2 + ((wv << 12) | (lane << 3));
    #pragma unroll
    for (int s = 0; s < 8; ++s) {
      short8v bw = *(const short8v*)(WFw + (s << 9));
      const int k1 = s * 16 + khalf;
      const int i0 = baseA + (k1 ^ swA);
      const int i1 = baseA + ((k1 + 4) ^ swA);
      short8v z0 = __builtin_shufflevector(*(const short4v*)&Z4[i0],
                                           *(const short4v*)&Z4[i1], 0,1,2,3,4,5,6,7);
      short8v z1 = __builtin_shufflevector(*(const short4v*)&Z4[4096 + i0],
                                           *(const short4v*)&Z4[4096 + i1], 0,1,2,3,4,5,6,7);
      short8v z2 = __builtin_shufflevector(*(const short4v*)&Z4[8192 + i0],
                                           *(const short4v*)&Z4[8192 + i1], 0,1,2,3,4,5,6,7);
      short8v z3 = __builtin_shufflevector(*(const short4v*)&Z4[12288 + i0],
                                           *(const short4v*)&Z4[12288 + i1], 0,1,2,3,4,5,6,7);
      ac0 = __builtin_amdgcn_mfma_f32_32x32x16_bf16(z0, bw, ac0, 0, 0, 0);
      ac1 = __builtin_amdgcn_mfma_f32_32x32x16_bf16(z1, bw, ac1, 0, 0, 0);
      ac2 = __builtin_amdgcn_mfma_f32_32x32x16_bf16(z2, bw, ac2, 0, 0, 0);
      ac3 = __builtin_amdgcn_mfma_f32_32x32x16_bf16(z3, bw, ac3, 0, 0, 0);
    }
  }
  __syncthreads();

  {
    const int j = (wv << 5) | (lane & 31);
    const float be2j = be2[j];
    const int ebase = (lane >> 5) << 2;
    #pragma unroll
    for (int r_ = 0; r_ < 16; ++r_) {
      int e = (r_ & 3) + 8 * (r_ >> 2) + ebase;
      float v = RELU(ac0[r_] + be2j) + RELU(ac1[r_] + be2j) +
                RELU(ac2[r_] + be2j) + RELU(ac3[r_] + be2j);
      Z4[(e << 7) + (j ^ (e << 2))] = f2bf(0.25f * v);
    }
  }
  __syncthreads();

  {
    const int e  = t >> 3;
    const int kc = (t & 7) << 4;
    int i = iblk + e;
    if (i < hi) {
      const int sw = e << 2, rb = e << 7;
      uint2 c0 = *(const uint2*)&Z4[rb + ((kc + 0) ^ sw)];
      uint2 c1 = *(const uint2*)&Z4[rb + ((kc + 4) ^ sw)];
      uint2 c2 = *(const uint2*)&Z4[rb + ((kc + 8) ^ sw)];
      uint2 c3 = *(const uint2*)&Z4[rb + ((kc + 12) ^ sw)];
      *(uint4*)&efbuf[(size_t)(i - lo) * 128 + kc]     = make_uint4(c0.x, c0.y, c1.x, c1.y);
      *(uint4*)&efbuf[(size_t)(i - lo) * 128 + kc + 8] = make_uint4(c2.x, c2.y, c3.x, c3.y);
    }
  }

  f32x16 a2 = {0.f};
  {
    const unsigned short* WFc = WFc1 + ((wv << 12) | (lane << 3));
    #pragma unroll
    for (int s = 0; s < 8; ++s) {
      short8v bw = *(const short8v*)(WFc + (s << 9));
      const int k1 = s * 16 + khalf;
      const int i0 = baseA + (k1 ^ swA);
      const int i1 = baseA + ((k1 + 4) ^ swA);
      short8v af = __builtin_shufflevector(*(const short4v*)&Z4[i0],
                                           *(const short4v*)&Z4[i1], 0,1,2,3,4,5,6,7);
      a2 = __builtin_amdgcn_mfma_f32_32x32x16_bf16(af, bw, a2, 0, 0, 0);
    }
  }
  {
    const int j = (wv << 5) | (lane & 31);
    const float bc1j = bc1[j];
    const int ebase = (lane >> 5) << 2;
    #pragma unroll
    for (int r_ = 0; r_ < 16; ++r_) {
      int e = (r_ & 3) + 8 * (r_ >> 2) + ebase;
      Z4[4096 + (e << 7) + (j ^ (e << 2))] = f2bf(RELU(a2[r_] + bc1j));
    }
  }
  __syncthreads();

  {
    const int e  = t >> 3;
    const int jc = (t & 7) << 4;
    const int sw = e << 2, rb = e << 7;
    uint2 d0 = *(const uint2*)&Z4[4096 + rb + ((jc + 0) ^ sw)];
    uint2 d1 = *(const uint2*)&Z4[4096 + rb + ((jc + 4) ^ sw)];
    uint2 d2 = *(const uint2*)&Z4[4096 + rb + ((jc + 8) ^ sw)];
    uint2 d3 = *(const uint2*)&Z4[4096 + rb + ((jc + 12) ^ sw)];
    unsigned uu[8] = {d0.x, d0.y, d1.x, d1.y, d2.x, d2.y, d3.x, d3.y};
    float cx = 0.f, cy = 0.f;
    #pragma unroll
    for (int q = 0; q < 8; ++q) {
      float t0 = bf2f((unsigned short)(uu[q] & 0xFFFFu));
      float t1 = bf2f((unsigned short)(uu[q] >> 16));
      float2 wA = *(const float2*)&Wc2s[2 * (jc + 2 * q)];
      float2 wB = *(const float2*)&Wc2s[2 * (jc + 2 * q + 1)];
      cx = fmaf(t0, wA.x, cx); cy = fmaf(t0, wA.y, cy);
      cx = fmaf(t1, wB.x, cx); cy = fmaf(t1, wB.y, cy);
    }
    cx += __shfl_xor(cx, 1); cy += __shfl_xor(cy, 1);
    cx += __shfl_xor(cx, 2); cy += __shfl_xor(cy, 2);
    cx += __shfl_xor(cx, 4); cy += __shfl_xor(cy, 4);
    if ((t & 7) == 0) { cmE[e][0] = cx; cmE[e][1] = cy; }
  }
  __syncthreads();
  if (t < ET) {
    int i = iblk + t;
    if (i < hi) {
      float tx = fminf(fmaxf(ped[8][t] * cmE[t][0], -100.0f), 100.0f);
      float ty = fminf(fmaxf(ped[9][t] * cmE[t][1], -100.0f), 100.0f);
      transbuf[(size_t)i * 2]     = tx;
      transbuf[(size_t)i * 2 + 1] = ty;
    }
  }
}

// ---------------------------------------------------------------------------
// Fused gather + node_final (nch==1). pk_add accumulation.
// ---------------------------------------------------------------------------
__global__ __launch_bounds__(256) void gather_final_mfma(
    const float* __restrict__ h, const float* __restrict__ coord,
    const float* __restrict__ vel,
    const unsigned short* __restrict__ WFn1a,
    const unsigned short* __restrict__ WFn1b,
    const unsigned short* __restrict__ WFn2,
    const float* __restrict__ bn1, const float* __restrict__ bn2,
    const int* __restrict__ ptr, const unsigned short* __restrict__ efbuf,
    const float* __restrict__ transbuf, const float* __restrict__ velfac,
    float* __restrict__ hout, float* __restrict__ cout, int N)
{
  const int t = threadIdx.x, wv = t >> 6, lane = t & 63;
  const int n0 = blockIdx.x * 32;
  __shared__ __align__(16) unsigned short Ah[4096];
  __shared__ __align__(16) unsigned short Ag[4096];
  __shared__ __align__(16) unsigned short Mid[4096];
  __shared__ float trs[32][2];

  {
    const int e = t >> 3, kc = (t & 7) << 4;
    const int n = n0 + e;
    const int sw = (e & 15) << 3, rb = e << 7;
    unsigned pk[8];
    f32x2 ac2[8];
    #pragma unroll
    for (int q = 0; q < 8; ++q) { f32x2 z = {0.f, 0.f}; ac2[q] = z; }
    float tx = 0.f, ty = 0.f;
    if (n < N) {
      const float* hp = h + (size_t)n * 128 + kc;
      #pragma unroll
      for (int qc = 0; qc < 4; ++qc) {
        float4 v = *(const float4*)(hp + qc * 4);
        pk[qc * 2] = cvtpk(v.x, v.y); pk[qc * 2 + 1] = cvtpk(v.z, v.w);
      }
      const int p0 = ptr[n], p1 = ptr[n + 1];
      for (int i = p0; i < p1; ++i) {
        uint4 a = *(const uint4*)&efbuf[(size_t)i * 128 + kc];
        uint4 b = *(const uint4*)&efbuf[(size_t)i * 128 + kc + 8];
        unsigned uu[8] = {a.x, a.y, a.z, a.w, b.x, b.y, b.z, b.w};
        #pragma unroll
        for (int q = 0; q < 8; ++q) ac2[q] = pk_add(ac2[q], unpk(uu[q]));
      }
      for (int i = p0 + (t & 7); i < p1; i += 8) {
        tx += transbuf[(size_t)i * 2];
        ty += transbuf[(size_t)i * 2 + 1];
      }
    } else {
      #pragma unroll
      for (int q = 0; q < 8; ++q) pk[q] = 0u;
    }
    tx += __shfl_xor(tx, 1); ty += __shfl_xor(ty, 1);
    tx += __shfl_xor(tx, 2); ty += __shfl_xor(ty, 2);
    tx += __shfl_xor(tx, 4); ty += __shfl_xor(ty, 4);
    if ((t & 7) == 0) { trs[e][0] = tx; trs[e][1] = ty; }
    *(uint4*)&Ah[rb + (kc ^ sw)]       = make_uint4(pk[0], pk[1], pk[2], pk[3]);
    *(uint4*)&Ah[rb + ((kc + 8) ^ sw)] = make_uint4(pk[4], pk[5], pk[6], pk[7]);
    unsigned gk[8];
    #pragma unroll
    for (int q = 0; q < 8; ++q) gk[q] = cvtpk(ac2[q].x, ac2[q].y);
    *(uint4*)&Ag[rb + (kc ^ sw)]       = make_uint4(gk[0], gk[1], gk[2], gk[3]);
    *(uint4*)&Ag[rb + ((kc + 8) ^ sw)] = make_uint4(gk[4], gk[5], gk[6], gk[7]);
  }
  __syncthreads();

  const int eA = lane & 31, khalf = (lane >> 5) << 3, swA = (eA & 15) << 3;
  const int baseA = eA << 7;
  f32x16 m = {0.f};
  {
    const unsigned short* p1 = WFn1a + ((wv << 12) | (lane << 3));
    const unsigned short* p2 = WFn1b + ((wv << 12) | (lane << 3));
    #pragma unroll
    for (int s = 0; s < 8; ++s) {
      const int i0 = baseA + ((s * 16 + khalf) ^ swA);
      short8v zh = *(const short8v*)&Ah[i0];
      short8v zg = *(const short8v*)&Ag[i0];
      m = __builtin_amdgcn_mfma_f32_32x32x16_bf16(zh, *(const short8v*)(p1 + (s << 9)), m, 0, 0, 0);
      m = __builtin_amdgcn_mfma_f32_32x32x16_bf16(zg, *(const short8v*)(p2 + (s << 9)), m, 0, 0, 0);
    }
  }
  const int colb = (wv << 5) | (lane & 31);
  const float bn1j = bn1[colb];
  const int ebase = (lane >> 5) << 2;
  #pragma unroll
  for (int r = 0; r < 16; ++r) {
    const int e = (r & 3) + 8 * (r >> 2) + ebase;
    Mid[(e << 7) + (colb ^ ((e & 15) << 3))] = f2bf(RELU(m[r] + bn1j));
  }
  __syncthreads();

  f32x16 o = {0.f};
  {
    const unsigned short* p3 = WFn2 + ((wv << 12) | (lane << 3));
    #pragma unroll
    for (int s = 0; s < 8; ++s) {
      const int i0 = baseA + ((s * 16 + khalf) ^ swA);
      short8v zm = *(const short8v*)&Mid[i0];
      o = __builtin_amdgcn_mfma_f32_32x32x16_bf16(zm, *(const short8v*)(p3 + (s << 9)), o, 0, 0, 0);
    }
  }
  const float bn2j = bn2[colb];
  #pragma unroll
  for (int r = 0; r < 16; ++r) {
    const int e = (r & 3) + 8 * (r >> 2) + ebase;
    const int n = n0 + e;
    if (n < N)
      hout[(size_t)n * 128 + colb] = h[(size_t)n * 128 + colb] + o[r] + bn2j;
  }
  if (t < 32) {
    const int n = n0 + t;
    if (n < N) {
      float c = (float)(ptr[n + 1] - ptr[n]);
      float vf = velfac[n];
      float inv = 1.0f / fmaxf(c, 1.0f);
      cout[(size_t)n * 2]     = coord[(size_t)n * 2]     + trs[t][0] * inv + vf * vel[(size_t)n * 2];
      cout[(size_t)n * 2 + 1] = coord[(size_t)n * 2 + 1] + trs[t][1] * inv + vf * vel[(size_t)n * 2 + 1];
    }
  }
}

// ---------------------------------------------------------------------------
// Chunked fallback (nch>1): gather + node_final.
// ---------------------------------------------------------------------------
__global__ __launch_bounds__(256) void gather_kernel(
    const int* __restrict__ ptr, const unsigned short* __restrict__ efbuf,
    const float* __restrict__ transbuf,
    unsigned short* __restrict__ aggnb, float* __restrict__ agg,
    int N, int lo, int hi, int first)
{
  const int wv = threadIdx.x >> 6, lane = threadIdx.x & 63;
  const int n = blockIdx.x * 4 + wv;
  if (n >= N) return;
  const int p0 = ptr[n], p1 = ptr[n + 1];
  const int a = p0 > lo ? p0 : lo;
  const int b = p1 < hi ? p1 : hi;
  const int sub = lane >> 4, c8 = (lane & 15) << 3;
  f32x2 ac2[4];
  #pragma unroll
  for (int q = 0; q < 4; ++q) { f32x2 z = {0.f, 0.f}; ac2[q] = z; }
  for (int i = a + sub; i < b; i += 4) {
    uint4 v = *(const uint4*)&efbuf[(size_t)(i - lo) * 128 + c8];
    unsigned uu[4] = {v.x, v.y, v.z, v.w};
    #pragma unroll
    for (int q = 0; q < 4; ++q) ac2[q] = pk_add(ac2[q], unpk(uu[q]));
  }
  #pragma unroll
  for (int q = 0; q < 4; ++q) {
    ac2[q].x += __shfl_xor(ac2[q].x, 16);
    ac2[q].y += __shfl_xor(ac2[q].y, 16);
    ac2[q].x += __shfl_xor(ac2[q].x, 32);
    ac2[q].y += __shfl_xor(ac2[q].y, 32);
  }
  if (lane < 16) {
    if (!first) {
      uint4 old = *(const uint4*)&aggnb[(size_t)n * 128 + c8];
      unsigned uo[4] = {old.x, old.y, old.z, old.w};
      #pragma unroll
      for (int q = 0; q < 4; ++q) ac2[q] = pk_add(ac2[q], unpk(uo[q]));
    }
    unsigned pk[4];
    #pragma unroll
    for (int q = 0; q < 4; ++q) pk[q] = cvtpk(ac2[q].x, ac2[q].y);
    *(uint4*)&aggnb[(size_t)n * 128 + c8] = make_uint4(pk[0], pk[1], pk[2], pk[3]);
  }
  if (lane < 2) {
    float tacc = first ? 0.f : agg[(size_t)n * 2 + lane];
    for (int i = a; i < b; ++i) tacc += transbuf[(size_t)i * 2 + lane];
    agg[(size_t)n * 2 + lane] = tacc;
  }
}

__global__ __launch_bounds__(256) void node_final_mfma(
    const float* __restrict__ h, const float* __restrict__ coord,
    const float* __restrict__ vel,
    const unsigned short* __restrict__ WFn1a,
    const unsigned short* __restrict__ WFn1b,
    const unsigned short* __restrict__ WFn2,
    const float* __restrict__ bn1, const float* __restrict__ bn2,
    const float* __restrict__ agg, const int* __restrict__ ptr,
    const unsigned short* __restrict__ aggnb, const float* __restrict__ velfac,
    float* __restrict__ hout, float* __restrict__ cout, int N)
{
  const int t = threadIdx.x, wv = t >> 6, lane = t & 63;
  const int n0 = blockIdx.x * 32;
  __shared__ __align__(16) unsigned short Ah[4096];
  __shared__ __align__(16) unsigned short Ag[4096];
  __shared__ __align__(16) unsigned short Mid[4096];

  {
    const int e = t >> 3, kc = (t & 7) << 4;
    const int n = n0 + e;
    unsigned pk[8], gk[8];
    if (n < N) {
      const float* hp = h + (size_t)n * 128 + kc;
      #pragma unroll
      for (int qc = 0; qc < 4; ++qc) {
        float4 v = *(const float4*)(hp + qc * 4);
        pk[qc * 2] = cvtpk(v.x, v.y); pk[qc * 2 + 1] = cvtpk(v.z, v.w);
      }
      uint4 g0 = *(const uint4*)&aggnb[(size_t)n * 128 + kc];
      uint4 g1 = *(const uint4*)&aggnb[(size_t)n * 128 + kc + 8];
      gk[0] = g0.x; gk[1] = g0.y; gk[2] = g0.z; gk[3] = g0.w;
      gk[4] = g1.x; gk[5] = g1.y; gk[6] = g1.z; gk[7] = g1.w;
    } else {
      #pragma unroll
      for (int q = 0; q < 8; ++q) { pk[q] = 0u; gk[q] = 0u; }
    }
    const int sw = (e & 15) << 3, rb = e << 7;
    *(uint4*)&Ah[rb + (kc ^ sw)]       = make_uint4(pk[0], pk[1], pk[2], pk[3]);
    *(uint4*)&Ah[rb + ((kc + 8) ^ sw)] = make_uint4(pk[4], pk[5], pk[6], pk[7]);
    *(uint4*)&Ag[rb + (kc ^ sw)]       = make_uint4(gk[0], gk[1], gk[2], gk[3]);
    *(uint4*)&Ag[rb + ((kc + 8) ^ sw)] = make_uint4(gk[4], gk[5], gk[6], gk[7]);
  }
  __syncthreads();

  const int eA = lane & 31, khalf = (lane >> 5) << 3, swA = (eA & 15) << 3;
  const int baseA = eA << 7;
  f32x16 m = {0.f};
  {
    const unsigned short* p1 = WFn1a + ((wv << 12) | (lane << 3));
    const unsigned short* p2 = WFn1b + ((wv << 12) | (lane << 3));
    #pragma unroll
    for (int s = 0; s < 8; ++s) {
      const int i0 = baseA + ((s * 16 + khalf) ^ swA);
      short8v zh = *(const short8v*)&Ah[i0];
      short8v zg = *(const short8v*)&Ag[i0];
      m = __builtin_amdgcn_mfma_f32_32x32x16_bf16(zh, *(const short8v*)(p1 + (s << 9)), m, 0, 0, 0);
      m = __builtin_amdgcn_mfma_f32_32x32x16_bf16(zg, *(const short8v*)(p2 + (s << 9)), m, 0, 0, 0);
    }
  }
  const int colb = (wv << 5) | (lane & 31);
  const float bn1j = bn1[colb];
  const int ebase = (lane >> 5) << 2;
  #pragma unroll
  for (int r = 0; r < 16; ++r) {
    const int e = (r & 3) + 8 * (r >> 2) + ebase;
    Mid[(e << 7) + (colb ^ ((e & 15) << 3))] = f2bf(RELU(m[r] + bn1j));
  }
  __syncthreads();

  f32x16 o = {0.f};
  {
    const unsigned short* p3 = WFn2 + ((wv << 12) | (lane << 3));
    #pragma unroll
    for (int s = 0; s < 8; ++s) {
      const int i0 = baseA + ((s * 16 + khalf) ^ swA);
      short8v zm = *(const short8v*)&Mid[i0];
      o = __builtin_amdgcn_mfma_f32_32x32x16_bf16(zm, *(const short8v*)(p3 + (s << 9)), o, 0, 0, 0);
    }
  }
  const float bn2j = bn2[colb];
  #pragma unroll
  for (int r = 0; r < 16; ++r) {
    const int e = (r & 3) + 8 * (r >> 2) + ebase;
    const int n = n0 + e;
    if (n < N)
      hout[(size_t)n * 128 + colb] = h[(size_t)n * 128 + colb] + o[r] + bn2j;
  }
  if (t < 32) {
    const int n = n0 + t;
    if (n < N) {
      float c = (float)(ptr[n + 1] - ptr[n]);
      float vf = velfac[n];
      float inv = 1.0f / fmaxf(c, 1.0f);
      cout[(size_t)n * 2]     = coord[(size_t)n * 2]     + agg[(size_t)n * 2] * inv     + vf * vel[(size_t)n * 2];
      cout[(size_t)n * 2 + 1] = coord[(size_t)n * 2 + 1] + agg[(size_t)n * 2 + 1] * inv + vf * vel[(size_t)n * 2 + 1];
    }
  }
}

// ---------------------------------------------------------------------------
// Legacy fp32 fallback kernels (ws too small for efbuf).
// ---------------------------------------------------------------------------
__global__ __launch_bounds__(256) void edge_kernel_legacy(
    const int* __restrict__ row, const int* __restrict__ col,
    const float* __restrict__ Hr, const float* __restrict__ Hc,
    const float* __restrict__ coord, const float* __restrict__ vel,
    const float* __restrict__ We1, const float* __restrict__ We2,
    const float* __restrict__ be2, const float* __restrict__ Wc1,
    const float* __restrict__ bc1, const float* __restrict__ Wc2,
    float* __restrict__ agg, float* __restrict__ cnt, float* __restrict__ aggn,
    int E)
{
  const int t  = threadIdx.x;
  const int el = t & 31;
  const int jg = t >> 5;
  const int j0 = jg * 16;
  const int e0 = blockIdx.x * ET;

  __shared__ __align__(16) float Wch[32][128];
  __shared__ __align__(16) float Zbuf[4256];
  __shared__ __align__(16) float W9[9][128];
  __shared__ float ped[11][32];
  __shared__ int   rs[32], cs[32], vE[32];
  __shared__ float cmP[8][32][2];

#define Z4L(g, e_, k_) Zbuf[((g) * 32 + (e_)) * 33 + (k_)]
#define EFL(e_, k_)    Zbuf[(e_) * 133 + (k_)]

  if (t < ET) {
    int e = e0 + t;
    int r = 0, c = 0, v = 0;
    if (e < E) { r = row[e]; c = col[e]; v = 1; }
    rs[t] = r; cs[t] = c; vE[t] = v;
    float crx = coord[2 * r], cry = coord[2 * r + 1];
    float ccx = coord[2 * c], ccy = coord[2 * c + 1];
    ped[0][t] = crx; ped[1][t] = cry; ped[2][t] = ccx; ped[3][t] = ccy;
    ped[4][t] = vel[2 * r]; ped[5][t] = vel[2 * r + 1];
    ped[6][t] = vel[2 * c]; ped[7][t] = vel[2 * c + 1];
    float dx = crx - ccx, dy = cry - ccy;
    ped[8][t] = dx; ped[9][t] = dy; ped[10][t] = dx * dx + dy * dy;
  }
  for (int idx = t; idx < 9 * 128; idx += 256)
    W9[idx >> 7][idx & 127] = We1[(size_t)(256 + (idx >> 7)) * 128 + (idx & 127)];

  float outg[4][16];
  #pragma unroll
  for (int g = 0; g < 4; ++g)
    #pragma unroll
    for (int jj = 0; jj < 16; ++jj) outg[g][jj] = 0.0f;

  for (int kc = 0; kc < 4; ++kc) {
    const int kb = kc * 32;
    __syncthreads();
    #pragma unroll
    for (int s = 0; s < 4; ++s) {
      int idx4 = t + s * 256;
      int kl = idx4 >> 5, jc = (idx4 & 31) * 4;
      *(float4*)&Wch[kl][jc] = *(const float4*)&We2[(size_t)(kb + kl) * 128 + jc];
    }
    {
      const int kk = kb + (jg << 2);
      const int kl = jg << 2;
      const int r = rs[el], c = cs[el];
      float4 a4 = *(const float4*)(Hr + (size_t)r * 128 + kk);
      float4 b4 = *(const float4*)(Hc + (size_t)c * 128 + kk);
      float hr[4] = {a4.x, a4.y, a4.z, a4.w};
      float hcv[4] = {b4.x, b4.y, b4.z, b4.w};
      float4 q;
      q = *(const float4*)&W9[0][kk]; float w0[4] = {q.x, q.y, q.z, q.w};
      q = *(const float4*)&W9[1][kk]; float w1[4] = {q.x, q.y, q.z, q.w};
      q = *(const float4*)&W9[2][kk]; float w2[4] = {q.x, q.y, q.z, q.w};
      q = *(const float4*)&W9[3][kk]; float w3[4] = {q.x, q.y, q.z, q.w};
      q = *(const float4*)&W9[4][kk]; float w4[4] = {q.x, q.y, q.z, q.w};
      q = *(const float4*)&W9[5][kk]; float w5[4] = {q.x, q.y, q.z, q.w};
      q = *(const float4*)&W9[6][kk]; float w6[4] = {q.x, q.y, q.z, q.w};
      q = *(const float4*)&W9[7][kk]; float w7[4] = {q.x, q.y, q.z, q.w};
      q = *(const float4*)&W9[8][kk]; float w8[4] = {q.x, q.y, q.z, q.w};
      float xr = ped[0][el], yr = ped[1][el], xc = ped[2][el], yc = ped[3][el];
      float vrx = ped[4][el], vry = ped[5][el], vcx = ped[6][el], vcy = ped[7][el];
      float d2 = ped[10][el];
      #pragma unroll
      for (int i = 0; i < 4; ++i) {
        float base = hr[i] + hcv[i] + d2 * w4[i];
        float A = xr * w0[i] + xc * w2[i] + vrx * w5[i] + vcx * w7[i];
        float B = yr * w1[i] + yc * w3[i] + vry * w6[i] + vcy * w8[i];
        Z4L(0, el, kl + i) = RELU(base + A + B);
        Z4L(1, el, kl + i) = RELU(base - A - B);
        Z4L(2, el, kl + i) = RELU(base - A + B);
        Z4L(3, el, kl + i) = RELU(base + A - B);
      }
    }
    __syncthreads();
    #pragma unroll 2
    for (int k = 0; k < 32; ++k) {
      float4 wa = *(const float4*)&Wch[k][j0];
      float4 wb = *(const float4*)&Wch[k][j0 + 4];
      float4 wc4 = *(const float4*)&Wch[k][j0 + 8];
      float4 wd = *(const float4*)&Wch[k][j0 + 12];
      float w[16] = {wa.x, wa.y, wa.z, wa.w, wb.x, wb.y, wb.z, wb.w,
                     wc4.x, wc4.y, wc4.z, wc4.w, wd.x, wd.y, wd.z, wd.w};
      float z0 = Z4L(0, el, k), z1 = Z4L(1, el, k);
      float z2 = Z4L(2, el, k), z3 = Z4L(3, el, k);
      #pragma unroll
      for (int jj = 0; jj < 16; ++jj) {
        outg[0][jj] = fmaf(z0, w[jj], outg[0][jj]);
        outg[1][jj] = fmaf(z1, w[jj], outg[1][jj]);
        outg[2][jj] = fmaf(z2, w[jj], outg[2][jj]);
        outg[3][jj] = fmaf(z3, w[jj], outg[3][jj]);
      }
    }
  }

  __syncthreads();
  float4 q0 = *(const float4*)(be2 + j0);
  float4 q1 = *(const float4*)(be2 + j0 + 4);
  float4 q2 = *(const float4*)(be2 + j0 + 8);
  float4 q3 = *(const float4*)(be2 + j0 + 12);
  float beA[16] = {q0.x, q0.y, q0.z, q0.w, q1.x, q1.y, q1.z, q1.w,
                   q2.x, q2.y, q2.z, q2.w, q3.x, q3.y, q3.z, q3.w};
  float ef[16];
  #pragma unroll
  for (int jj = 0; jj < 16; ++jj) {
    float s = RELU(outg[0][jj] + beA[jj]) + RELU(outg[1][jj] + beA[jj]) +
              RELU(outg[2][jj] + beA[jj]) + RELU(outg[3][jj] + beA[jj]);
    ef[jj] = 0.25f * s;
  }
  #pragma unroll
  for (int jj = 0; jj < 16; ++jj) EFL(el, j0 + jj) = ef[jj];
  {
    const int r = rs[el];
    if (vE[el]) {
      #pragma unroll
      for (int jj = 0; jj < 16; ++jj)
        unsafeAtomicAdd(&aggn[(size_t)r * 128 + j0 + jj], ef[jj]);
    }
  }

  float acc2[16];
  #pragma unroll
  for (int jj = 0; jj < 16; ++jj) acc2[jj] = 0.0f;
  for (int kc = 0; kc < 4; ++kc) {
    const int kb = kc * 32;
    __syncthreads();
    #pragma unroll
    for (int s = 0; s < 4; ++s) {
      int idx4 = t + s * 256;
      int kl = idx4 >> 5, jc = (idx4 & 31) * 4;
      *(float4*)&Wch[kl][jc] = *(const float4*)&Wc1[(size_t)(kb + kl) * 128 + jc];
    }
    __syncthreads();
    #pragma unroll 4
    for (int k = 0; k < 32; ++k) {
      float4 wa = *(const float4*)&Wch[k][j0];
      float4 wb = *(const float4*)&Wch[k][j0 + 4];
      float4 wc4 = *(const float4*)&Wch[k][j0 + 8];
      float4 wd = *(const float4*)&Wch[k][j0 + 12];
      float w[16] = {wa.x, wa.y, wa.z, wa.w, wb.x, wb.y, wb.z, wb.w,
                     wc4.x, wc4.y, wc4.z, wc4.w, wd.x, wd.y, wd.z, wd.w};
      float efk = EFL(el, kb + k);
      #pragma unroll
      for (int jj = 0; jj < 16; ++jj) acc2[jj] = fmaf(efk, w[jj], acc2[jj]);
    }
  }

  float cm0 = 0.f, cm1 = 0.f;
  #pragma unroll
  for (int jj = 0; jj < 16; ++jj) {
    float tv = RELU(acc2[jj] + bc1[j0 + jj]);
    float2 wp = *(const float2*)(Wc2 + 2 * (j0 + jj));
    cm0 = fmaf(tv, wp.x, cm0);
    cm1 = fmaf(tv, wp.y, cm1);
  }
  cmP[jg][el][0] = cm0; cmP[jg][el][1] = cm1;
  __syncthreads();
  if (t < ET && vE[t]) {
    float c0 = 0.f, c1 = 0.f;
    #pragma unroll
    for (int g = 0; g < 8; ++g) { c0 += cmP[g][t][0]; c1 += cmP[g][t][1]; }
    float dx = ped[8][t], dy = ped[9][t];
    float tx = fminf(fmaxf(dx * c0, -100.0f), 100.0f);
    float ty = fminf(fmaxf(dy * c1, -100.0f), 100.0f);
    const int r = rs[t];
    unsafeAtomicAdd(&agg[(size_t)r * 2], tx);
    unsafeAtomicAdd(&agg[(size_t)r * 2 + 1], ty);
    unsafeAtomicAdd(&cnt[r], 1.0f);
  }
}

__global__ __launch_bounds__(128) void node_pre_legacy(
    const float* __restrict__ h, const float* __restrict__ We1,
    const float* __restrict__ be1,
    const float* __restrict__ Wv1, const float* __restrict__ bv1,
    const float* __restrict__ Wv2, const float* __restrict__ bv2,
    float* __restrict__ Hr, float* __restrict__ Hc, float* __restrict__ velfac)
{
  const int j = threadIdx.x;
  const int n0 = blockIdx.x * 8;
  __shared__ __align__(16) float hl[128][8];
  __shared__ float vp[8][128];

  #pragma unroll
  for (int s = 0; s < 8; ++s) hl[j][s] = h[(size_t)(n0 + s) * 128 + j];
  __syncthreads();

  float aR[8], aC[8], aV[8];
  #pragma unroll
  for (int n = 0; n < 8; ++n) { aR[n] = 0.f; aC[n] = 0.f; aV[n] = 0.f; }

  for (int k = 0; k < 128; ++k) {
    float wr = We1[(size_t)k * 128 + j];
    float wc = We1[(size_t)(128 + k) * 128 + j];
    float wv = Wv1[(size_t)k * 128 + j];
    float4 h0 = *(const float4*)&hl[k][0];
    float4 h1 = *(const float4*)&hl[k][4];
    float hv[8] = {h0.x, h0.y, h0.z, h0.w, h1.x, h1.y, h1.z, h1.w};
    #pragma unroll
    for (int n = 0; n < 8; ++n) {
      aR[n] = fmaf(hv[n], wr, aR[n]);
      aC[n] = fmaf(hv[n], wc, aC[n]);
      aV[n] = fmaf(hv[n], wv, aV[n]);
    }
  }
  float b1 = be1[j], bv = bv1[j], w2 = Wv2[j];
  #pragma unroll
  for (int n = 0; n < 8; ++n) {
    Hr[(size_t)(n0 + n) * 128 + j] = aR[n] + b1;
    Hc[(size_t)(n0 + n) * 128 + j] = aC[n];
    vp[n][j] = RELU(aV[n] + bv) * w2;
  }
  __syncthreads();
  if (j < 8) {
    float s = 0.f;
    for (int k = 0; k < 128; ++k) s += vp[j][k];
    velfac[n0 + j] = s + bv2[0];
  }
}

__global__ __launch_bounds__(128) void node_final_legacy(
    const float* __restrict__ h, const float* __restrict__ coord,
    const float* __restrict__ vel,
    const float* __restrict__ Wn1, const float* __restrict__ bn1,
    const float* __restrict__ Wn2, const float* __restrict__ bn2,
    const float* __restrict__ agg, const float* __restrict__ cntbuf,
    const float* __restrict__ aggn, const float* __restrict__ velfac,
    float* __restrict__ hout, float* __restrict__ cout)
{
  const int j = threadIdx.x;
  const int n0 = blockIdx.x * 4;
  __shared__ __align__(16) float xl[256][4];
  __shared__ __align__(16) float tl[128][4];

  #pragma unroll
  for (int s = 0; s < 8; ++s) {
    int idx = s * 128 + j;
    int n = idx >> 8, k = idx & 255;
    float v = (k < 128) ? h[(size_t)(n0 + n) * 128 + k]
                        : aggn[(size_t)(n0 + n) * 128 + (k - 128)];
    xl[k][n] = v;
  }
  __syncthreads();
  float acc[4] = {0.f, 0.f, 0.f, 0.f};
  for (int k = 0; k < 256; ++k) {
    float w = Wn1[(size_t)k * 128 + j];
    float4 xv = *(const float4*)&xl[k][0];
    acc[0] = fmaf(xv.x, w, acc[0]);
    acc[1] = fmaf(xv.y, w, acc[1]);
    acc[2] = fmaf(xv.z, w, acc[2]);
    acc[3] = fmaf(xv.w, w, acc[3]);
  }
  float b = bn1[j];
  #pragma unroll
  for (int n = 0; n < 4; ++n) tl[j][n] = RELU(acc[n] + b);
  __syncthreads();
  float a2[4] = {0.f, 0.f, 0.f, 0.f};
  for (int k = 0; k < 128; ++k) {
    float w = Wn2[(size_t)k * 128 + j];
    float4 tv = *(const float4*)&tl[k][0];
    a2[0] = fmaf(tv.x, w, a2[0]);
    a2[1] = fmaf(tv.y, w, a2[1]);
    a2[2] = fmaf(tv.z, w, a2[2]);
    a2[3] = fmaf(tv.w, w, a2[3]);
  }
  float b2 = bn2[j];
  #pragma unroll
  for (int n = 0; n < 4; ++n)
    hout[(size_t)(n0 + n) * 128 + j] = h[(size_t)(n0 + n) * 128 + j] + a2[n] + b2;
  if (j < 8) {
    int n = j >> 1, d = j & 1;
    int node = n0 + n;
    float cdel = agg[(size_t)node * 2 + d] / fmaxf(cntbuf[node], 1.0f);
    cout[(size_t)node * 2 + d] =
        coord[(size_t)node * 2 + d] + cdel + velfac[node] * vel[(size_t)node * 2 + d];
  }
}

// ---------------------------------------------------------------------------
extern "C" void kernel_launch(void* const* d_in, const int* in_sizes, int n_in,
                              void* d_out, int out_size, void* d_ws, size_t ws_size,
                              hipStream_t stream)
{
  const float* h     = (const float*)d_in[0];
  const float* coord = (const float*)d_in[1];
  const float* vel   = (const float*)d_in[2];
  const float* We1   = (const float*)d_in[3];
  const float* be1   = (const float*)d_in[4];
  const float* We2   = (const float*)d_in[5];
  const float* be2   = (const float*)d_in[6];
  const float* Wc1   = (const float*)d_in[7];
  const float* bc1   = (const float*)d_in[8];
  const float* Wc2   = (const float*)d_in[9];
  const float* Wn1   = (const float*)d_in[10];
  const float* bn1   = (const float*)d_in[11];
  const float* Wn2   = (const float*)d_in[12];
  const float* bn2   = (const float*)d_in[13];
  const float* Wv1   = (const float*)d_in[14];
  const float* bv1   = (const float*)d_in[15];
  const float* Wv2   = (const float*)d_in[16];
  const float* bv2   = (const float*)d_in[17];
  const int*   ei    = (const int*)d_in[18];

  const int N = in_sizes[0] / 128;
  const int E = in_sizes[18] / 2;
  const int* row = ei;
  const int* col = ei + E;

  char* base = (char*)d_ws;
  size_t off = 0;
  auto alloc = [&](size_t bytes) -> char* {
    char* p = base + off;
    off += (bytes + 255) & ~(size_t)255;
    return p;
  };
  float* Hr     = (float*)alloc((size_t)N * 128 * 4);
  float* Hc     = (float*)alloc((size_t)N * 128 * 4);
  float* velfac = (float*)alloc((size_t)N * 4);
  // zblk: deg[N] | bar[64] | agg[2N] | cnt[N] | aggn[128N]
  float* zblk   = (float*)alloc(((size_t)132 * N + 64) * 4);
  int*   deg    = (int*)zblk;
  int*   bar    = deg + N;
  float* agg    = zblk + N + 64;
  float* cnt    = agg + (size_t)2 * N;
  float* aggn   = cnt + N;
  unsigned short* aggnb = (unsigned short*)aggn;
  int*   ptr    = (int*)alloc((size_t)(N + 1) * 4);
  int*   wptr   = (int*)alloc((size_t)N * 4);
  int*   rowS   = (int*)alloc((size_t)E * 4);
  int*   colS   = (int*)alloc((size_t)E * 4);
  float* trans  = (float*)alloc((size_t)E * 2 * 4);
  unsigned short* wfall = (unsigned short*)alloc((size_t)8 * 16384 * 2);
  int*   bsum   = (int*)alloc((size_t)PREPB * 4);
  int*   boff   = (int*)alloc((size_t)PREPB * 4);
  size_t fixed_end = off;
  unsigned short* efbuf = (unsigned short*)(base + fixed_end);

  unsigned short* WFe2  = wfall + 3 * 16384;
  unsigned short* WFc1  = wfall + 4 * 16384;
  unsigned short* WFn1a = wfall + 5 * 16384;
  unsigned short* WFn1b = wfall + 6 * 16384;
  unsigned short* WFn2  = wfall + 7 * 16384;

  int use_csr = 0, EC = 0, nch = 1;
  if (ws_size > fixed_end) {
    size_t ec_max = (ws_size - fixed_end) / 256;
    ec_max &= ~(size_t)31;
    if (ec_max >= 32768 && (N + PREPB - 1) / PREPB <= 256) {
      use_csr = 1;
      size_t e_pad = ((size_t)E + 31) & ~(size_t)31;
      EC = (int)((ec_max < e_pad) ? ec_max : e_pad);
      nch = (E + EC - 1) / EC;
    }
  }

  const int nblk32 = (N + 31) / 32;
  float* hout = (float*)d_out;
  float* cout = hout + (size_t)N * 128;

  if (use_csr) {
    hipMemsetAsync(deg, 0, (size_t)(N + 64) * 4, stream);
    hipLaunchKernelGGL(prep_kernel, dim3(PREPB), dim3(256), 0, stream,
                       row, col, E, We1, Wv1, We2, Wc1, Wn1, Wn2, wfall,
                       h, be1, bv1, Wv2, bv2, Hr, Hc, velfac,
                       deg, bar, ptr, wptr, rowS, colS, bsum, boff, N);
    if (nch == 1) {
      hipLaunchKernelGGL(edge_mfma_kernel, dim3((E + ET - 1) / ET), dim3(256), 0,
                         stream, rowS, colS, Hr, Hc, coord, vel, We1,
                         WFe2, WFc1, be2, bc1, Wc2, efbuf, trans, 0, E);
      hipLaunchKernelGGL(gather_final_mfma, dim3(nblk32), dim3(256), 0, stream,
                         h, coord, vel, WFn1a, WFn1b, WFn2, bn1, bn2,
                         ptr, efbuf, trans, velfac, hout, cout, N);
    } else {
      for (int c = 0; c < nch; ++c) {
        int lo = c * EC;
        int hi = (lo + EC < E) ? lo + EC : E;
        int nb = (hi - lo + ET - 1) / ET;
        hipLaunchKernelGGL(edge_mfma_kernel, dim3(nb), dim3(256), 0, stream,
                           rowS, colS, Hr, Hc, coord, vel, We1,
                           WFe2, WFc1, be2, bc1, Wc2, efbuf, trans, lo, hi);
        hipLaunchKernelGGL(gather_kernel, dim3((N + 3) / 4), dim3(256), 0, stream,
                           ptr, efbuf, trans, aggnb, agg, N, lo, hi, (c == 0) ? 1 : 0);
      }
      hipLaunchKernelGGL(node_final_mfma, dim3(nblk32), dim3(256), 0, stream,
                         h, coord, vel, WFn1a, WFn1b, WFn2, bn1, bn2,
                         agg, ptr, aggnb, velfac, hout, cout, N);
    }
  } else {
    hipMemsetAsync(zblk, 0, ((size_t)132 * N + 64) * 4, stream);
    hipLaunchKernelGGL(node_pre_legacy, dim3(N / 8), dim3(128), 0, stream,
                       h, We1, be1, Wv1, bv1, Wv2, bv2, Hr, Hc, velfac);
    hipLaunchKernelGGL(edge_kernel_legacy, dim3((E + ET - 1) / ET), dim3(256), 0,
                       stream, row, col, Hr, Hc, coord, vel, We1, We2, be2,
                       Wc1, bc1, Wc2, agg, cnt, aggn, E);
    hipLaunchKernelGGL(node_final_legacy, dim3(N / 4), dim3(128), 0, stream,
                       h, coord, vel, Wn1, bn1, Wn2, bn2, agg, cnt,
                       aggn, velfac, hout, cout);
  }
}

// Round 11
// 649.058 us; speedup vs baseline: 1.0441x; 1.0441x over previous
//
#include <hip/hip_runtime.h>

#define RELU(x) fmaxf((x), 0.0f)

typedef __attribute__((ext_vector_type(2))) float f32x2;
typedef __attribute__((ext_vector_type(4))) short short4v;
typedef __attribute__((ext_vector_type(8))) short short8v;
typedef __attribute__((ext_vector_type(16))) float f32x16;

__device__ __forceinline__ float bf2f(unsigned short u) {
  unsigned v = ((unsigned)u) << 16;
  float f; __builtin_memcpy(&f, &v, 4); return f;
}
__device__ __forceinline__ unsigned short f2bf(float f) {
  unsigned u; __builtin_memcpy(&u, &f, 4);
  unsigned r = (u + 0x7FFFu + ((u >> 16) & 1u)) >> 16;
  return (unsigned short)r;
}
// HW packed convert: dst = {lo: bf16(a), hi: bf16(b)} (RNE).
__device__ __forceinline__ unsigned cvtpk(float a, float b) {
  unsigned r;
  asm("v_cvt_pk_bf16_f32 %0, %1, %2" : "=v"(r) : "v"(a), "v"(b));
  return r;
}
// packed f32 add: one instruction, two adds.
__device__ __forceinline__ f32x2 pk_add(f32x2 a, f32x2 b) {
  f32x2 d;
  asm("v_pk_add_f32 %0, %1, %2" : "=v"(d) : "v"(a), "v"(b));
  return d;
}
// unpack uint (2 bf16) -> f32 pair: lo = u<<16, hi = u & 0xFFFF0000.
__device__ __forceinline__ f32x2 unpk(unsigned u) {
  unsigned lo = u << 16, hi = u & 0xFFFF0000u;
  float fx, fy;
  __builtin_memcpy(&fx, &lo, 4);
  __builtin_memcpy(&fy, &hi, 4);
  f32x2 r = {fx, fy};
  return r;
}

// ---------------------------------------------------------------------------
// Fused: deg histogram + wprep8.
// ---------------------------------------------------------------------------
__global__ __launch_bounds__(256) void deg_wprep_kernel(
    const int* __restrict__ row, int* __restrict__ deg, int E, int degB,
    const float* __restrict__ We1, const float* __restrict__ Wv1,
    const float* __restrict__ We2, const float* __restrict__ Wc1,
    const float* __restrict__ Wn1, const float* __restrict__ Wn2,
    unsigned short* __restrict__ WF)
{
  if ((int)blockIdx.x < degB) {
    int e = blockIdx.x * 256 + threadIdx.x;
    if (e < E) atomicAdd(&deg[row[e]], 1);
    return;
  }
  const int bid = blockIdx.x - degB;
  const int g = bid >> 6;
  const int idx = (bid & 63) * 256 + threadIdx.x;
  const float* W;
  switch (g) {
    case 0: W = We1; break;
    case 1: W = We1 + 16384; break;
    case 2: W = Wv1; break;
    case 3: W = We2; break;
    case 4: W = Wc1; break;
    case 5: W = Wn1; break;
    case 6: W = Wn1 + 16384; break;
    default: W = Wn2; break;
  }
  int j = idx & 7, l = (idx >> 3) & 63, s = (idx >> 9) & 7, n = idx >> 12;
  int k = s * 16 + ((l >> 5) << 3) + j;
  int c = n * 32 + (l & 31);
  WF[g * 16384 + idx] = f2bf(W[k * 128 + c]);
}

// ---------------------------------------------------------------------------
// scan: single-block exclusive prefix over deg.
// ---------------------------------------------------------------------------
__global__ __launch_bounds__(1024) void scan_kernel(
    const int* __restrict__ deg, int* __restrict__ ptr, int* __restrict__ wptr,
    int N, int E)
{
  __shared__ int s[1024];
  const int t = threadIdx.x;
  const int chunk = (N + 1023) / 1024;
  const int lo = t * chunk;
  const int hi = (lo + chunk < N) ? lo + chunk : N;
  int sum = 0;
  for (int i = lo; i < hi; ++i) sum += deg[i];
  s[t] = sum;
  __syncthreads();
  for (int off = 1; off < 1024; off <<= 1) {
    int v = (t >= off) ? s[t - off] : 0;
    __syncthreads();
    s[t] += v;
    __syncthreads();
  }
  int run = s[t] - sum;
  for (int i = lo; i < hi; ++i) {
    ptr[i] = run; wptr[i] = run;
    run += deg[i];
  }
  if (t == 1023) ptr[N] = E;
}

// ---------------------------------------------------------------------------
// Fused: scatter (writes SORTED rowS/colS) + node_pre MFMA.
// ---------------------------------------------------------------------------
__global__ __launch_bounds__(256) void scatter_nodepre_kernel(
    const int* __restrict__ row, const int* __restrict__ col,
    int* __restrict__ wptr,
    int* __restrict__ rowS, int* __restrict__ colS, int E, int scatB,
    const float* __restrict__ h,
    const unsigned short* __restrict__ WFe1r,
    const unsigned short* __restrict__ WFe1c,
    const unsigned short* __restrict__ WFv1,
    const float* __restrict__ be1, const float* __restrict__ bv1,
    const float* __restrict__ Wv2, const float* __restrict__ bv2,
    float* __restrict__ Hr, float* __restrict__ Hc, float* __restrict__ velfac,
    int N)
{
  __shared__ __align__(16) unsigned short Ah[4096];
  __shared__ float Wv2s[128];
  __shared__ float vpart[32][4];

  if ((int)blockIdx.x < scatB) {
    int e = blockIdx.x * 256 + threadIdx.x;
    if (e < E) {
      int r = row[e];
      int pos = atomicAdd(&wptr[r], 1);
      rowS[pos] = r;
      colS[pos] = col[e];
    }
    return;
  }
  const int t = threadIdx.x, wv = t >> 6, lane = t & 63;
  const int n0 = (blockIdx.x - scatB) * 32;

  if (t < 128) Wv2s[t] = Wv2[t];
  {
    const int e = t >> 3, kc = (t & 7) << 4;
    const int n = n0 + e;
    unsigned pk[8];
    if (n < N) {
      const float* hp = h + (size_t)n * 128 + kc;
      #pragma unroll
      for (int qc = 0; qc < 4; ++qc) {
        float4 v = *(const float4*)(hp + qc * 4);
        pk[qc * 2] = cvtpk(v.x, v.y); pk[qc * 2 + 1] = cvtpk(v.z, v.w);
      }
    } else {
      #pragma unroll
      for (int q = 0; q < 8; ++q) pk[q] = 0u;
    }
    const int sw = e << 2, rb = e << 7;
    #pragma unroll
    for (int q = 0; q < 4; ++q)
      *(uint2*)&Ah[rb + ((kc + 4 * q) ^ sw)] = make_uint2(pk[2 * q], pk[2 * q + 1]);
  }
  __syncthreads();

  const int eA = lane & 31, khalf = (lane >> 5) << 3, swA = eA << 2;
  const int baseA = eA << 7;
  f32x16 aR = {0.f}, aC = {0.f}, aV = {0.f};
  const unsigned short* b1 = WFe1r + ((wv << 12) | (lane << 3));
  const unsigned short* b2 = WFe1c + ((wv << 12) | (lane << 3));
  const unsigned short* b3 = WFv1 + ((wv << 12) | (lane << 3));
  #pragma unroll
  for (int s = 0; s < 8; ++s) {
    const int k1 = s * 16 + khalf;
    short4v a0 = *(const short4v*)&Ah[baseA + (k1 ^ swA)];
    short4v a1 = *(const short4v*)&Ah[baseA + ((k1 + 4) ^ swA)];
    short8v z = __builtin_shufflevector(a0, a1, 0, 1, 2, 3, 4, 5, 6, 7);
    aR = __builtin_amdgcn_mfma_f32_32x32x16_bf16(z, *(const short8v*)(b1 + (s << 9)), aR, 0, 0, 0);
    aC = __builtin_amdgcn_mfma_f32_32x32x16_bf16(z, *(const short8v*)(b2 + (s << 9)), aC, 0, 0, 0);
    aV = __builtin_amdgcn_mfma_f32_32x32x16_bf16(z, *(const short8v*)(b3 + (s << 9)), aV, 0, 0, 0);
  }
  const int colb = (wv << 5) | (lane & 31);
  const float be1j = be1[colb], bv1j = bv1[colb], wv2j = Wv2s[colb];
  const int ebase = (lane >> 5) << 2;
  #pragma unroll
  for (int r = 0; r < 16; ++r) {
    const int e = (r & 3) + 8 * (r >> 2) + ebase;
    const int n = n0 + e;
    if (n < N) {
      Hr[(size_t)n * 128 + colb] = aR[r] + be1j;
      Hc[(size_t)n * 128 + colb] = aC[r];
    }
    float v = RELU(aV[r] + bv1j) * wv2j;
    v += __shfl_xor(v, 1); v += __shfl_xor(v, 2); v += __shfl_xor(v, 4);
    v += __shfl_xor(v, 8); v += __shfl_xor(v, 16);
    if ((lane & 31) == 0) vpart[e][wv] = v;
  }
  __syncthreads();
  if (t < 32) {
    const int n = n0 + t;
    if (n < N)
      velfac[n] = vpart[t][0] + vpart[t][1] + vpart[t][2] + vpart[t][3] + bv2[0];
  }
}

// ---------------------------------------------------------------------------
// Edge kernel (MFMA) — R9 structure; ef/tv epilogue via cvtpk pairs.
// ---------------------------------------------------------------------------
#define ET 32

__global__ __launch_bounds__(256) void edge_mfma_kernel(
    const int* __restrict__ rowS, const int* __restrict__ colS,
    const float* __restrict__ Hr, const float* __restrict__ Hc,
    const float* __restrict__ coord, const float* __restrict__ vel,
    const float* __restrict__ We1,
    const unsigned short* __restrict__ WFe2,
    const unsigned short* __restrict__ WFc1,
    const float* __restrict__ be2, const float* __restrict__ bc1,
    const float* __restrict__ Wc2,
    unsigned short* __restrict__ efbuf, float* __restrict__ transbuf,
    int lo, int hi)
{
  const int t    = threadIdx.x;
  const int wv   = t >> 6;
  const int lane = t & 63;
  const int iblk = lo + blockIdx.x * ET;

  __shared__ __align__(16) unsigned short Z4[4 * 4096];
  __shared__ __align__(16) float Wc2s[256];
  __shared__ float ped[11][32];
  __shared__ int rs[32], cs[32];
  __shared__ float cmE[32][2];

  if (t < ET) {
    int i = iblk + t;
    int r = 0, c = 0;
    if (i < hi) { r = rowS[i]; c = colS[i]; }
    rs[t] = r; cs[t] = c;
    float crx = coord[2 * r], cry = coord[2 * r + 1];
    float ccx = coord[2 * c], ccy = coord[2 * c + 1];
    ped[0][t] = crx; ped[1][t] = cry; ped[2][t] = ccx; ped[3][t] = ccy;
    ped[4][t] = vel[2 * r]; ped[5][t] = vel[2 * r + 1];
    ped[6][t] = vel[2 * c]; ped[7][t] = vel[2 * c + 1];
    float dx = crx - ccx, dy = cry - ccy;
    ped[8][t] = dx; ped[9][t] = dy; ped[10][t] = dx * dx + dy * dy;
  }
  Wc2s[t] = Wc2[t];
  __syncthreads();

  // ---- Z-compute: 4 k's (kq) x 4 edges (eg) per thread ----
  {
    const int kq = t & 31;
    const int eg = t >> 5;
    const int kc = kq << 2;
    float4 w0 = *(const float4*)&We1[(size_t)(256 + 0) * 128 + kc];
    float4 w1 = *(const float4*)&We1[(size_t)(256 + 1) * 128 + kc];
    float4 w2 = *(const float4*)&We1[(size_t)(256 + 2) * 128 + kc];
    float4 w3 = *(const float4*)&We1[(size_t)(256 + 3) * 128 + kc];
    float4 w4 = *(const float4*)&We1[(size_t)(256 + 4) * 128 + kc];
    float4 w5 = *(const float4*)&We1[(size_t)(256 + 5) * 128 + kc];
    float4 w6 = *(const float4*)&We1[(size_t)(256 + 6) * 128 + kc];
    float4 w7 = *(const float4*)&We1[(size_t)(256 + 7) * 128 + kc];
    float4 w8 = *(const float4*)&We1[(size_t)(256 + 8) * 128 + kc];
    float wa0[4] = {w0.x, w0.y, w0.z, w0.w};
    float wa1[4] = {w1.x, w1.y, w1.z, w1.w};
    float wa2[4] = {w2.x, w2.y, w2.z, w2.w};
    float wa3[4] = {w3.x, w3.y, w3.z, w3.w};
    float wa4[4] = {w4.x, w4.y, w4.z, w4.w};
    float wa5[4] = {w5.x, w5.y, w5.z, w5.w};
    float wa6[4] = {w6.x, w6.y, w6.z, w6.w};
    float wa7[4] = {w7.x, w7.y, w7.z, w7.w};
    float wa8[4] = {w8.x, w8.y, w8.z, w8.w};
    #pragma unroll
    for (int ee = 0; ee < 4; ++ee) {
      const int e = (eg << 2) + ee;
      const int r = rs[e], c = cs[e];
      float4 h4 = *(const float4*)(Hr + (size_t)r * 128 + kc);
      float4 c4 = *(const float4*)(Hc + (size_t)c * 128 + kc);
      float hb[4] = {h4.x, h4.y, h4.z, h4.w};
      float cb[4] = {c4.x, c4.y, c4.z, c4.w};
      const float xr = ped[0][e], yr = ped[1][e], xc = ped[2][e], yc = ped[3][e];
      const float vrx = ped[4][e], vry = ped[5][e], vcx = ped[6][e], vcy = ped[7][e];
      const float d2 = ped[10][e];
      float z0[4], z1[4], z2[4], z3[4];
      #pragma unroll
      for (int m = 0; m < 4; ++m) {
        float base = fmaf(d2, wa4[m], hb[m] + cb[m]);
        float A = fmaf(xr, wa0[m], fmaf(xc, wa2[m], fmaf(vrx, wa5[m], vcx * wa7[m])));
        float B = fmaf(yr, wa1[m], fmaf(yc, wa3[m], fmaf(vry, wa6[m], vcy * wa8[m])));
        float bp = base + A, bm = base - A;
        z0[m] = RELU(bp + B);
        z1[m] = RELU(bm - B);
        z2[m] = RELU(bm + B);
        z3[m] = RELU(bp - B);
      }
      const int ia = (e << 7) + (kc ^ (e << 2));
      *(uint2*)&Z4[ia]         = make_uint2(cvtpk(z0[0], z0[1]), cvtpk(z0[2], z0[3]));
      *(uint2*)&Z4[4096 + ia]  = make_uint2(cvtpk(z1[0], z1[1]), cvtpk(z1[2], z1[3]));
      *(uint2*)&Z4[8192 + ia]  = make_uint2(cvtpk(z2[0], z2[1]), cvtpk(z2[2], z2[3]));
      *(uint2*)&Z4[12288 + ia] = make_uint2(cvtpk(z3[0], z3[1]), cvtpk(z3[2], z3[3]));
    }
  }
  __syncthreads();

  // ---- stage 1: 4 groups x 8 K-steps of 32x32x16 MFMA ----
  const int eA    = lane & 31;
  const int khalf = (lane >> 5) << 3;
  const int swA   = eA << 2;
  const int baseA = eA << 7;
  f32x16 ac0 = {0.f}, ac1 = {0.f}, ac2 = {0.f}, ac3 = {0.f};
  {
    const unsigned short* WFw = WFe2 + ((wv << 12) | (lane << 3));
    #pragma unroll
    for (int s = 0; s < 8; ++s) {
      short8v bw = *(const short8v*)(WFw + (s << 9));
      const int k1 = s * 16 + khalf;
      const int i0 = baseA + (k1 ^ swA);
      const int i1 = baseA + ((k1 + 4) ^ swA);
      short8v z0 = __builtin_shufflevector(*(const short4v*)&Z4[i0],
                                           *(const short4v*)&Z4[i1], 0,1,2,3,4,5,6,7);
      short8v z1 = __builtin_shufflevector(*(const short4v*)&Z4[4096 + i0],
                                           *(const short4v*)&Z4[4096 + i1], 0,1,2,3,4,5,6,7);
      short8v z2 = __builtin_shufflevector(*(const short4v*)&Z4[8192 + i0],
                                           *(const short4v*)&Z4[8192 + i1], 0,1,2,3,4,5,6,7);
      short8v z3 = __builtin_shufflevector(*(const short4v*)&Z4[12288 + i0],
                                           *(const short4v*)&Z4[12288 + i1], 0,1,2,3,4,5,6,7);
      ac0 = __builtin_amdgcn_mfma_f32_32x32x16_bf16(z0, bw, ac0, 0, 0, 0);
      ac1 = __builtin_amdgcn_mfma_f32_32x32x16_bf16(z1, bw, ac1, 0, 0, 0);
      ac2 = __builtin_amdgcn_mfma_f32_32x32x16_bf16(z2, bw, ac2, 0, 0, 0);
      ac3 = __builtin_amdgcn_mfma_f32_32x32x16_bf16(z3, bw, ac3, 0, 0, 0);
    }
  }
  __syncthreads();   // all Z4 reads done; region 0 -> ef, region 1 -> tv

  // ---- ef = 0.25 * sum_g relu(out_g + be2) -> LDS bf16 (cvtpk pairs) ----
  {
    const int j = (wv << 5) | (lane & 31);
    const float be2j = be2[j];
    const int ebase = (lane >> 5) << 2;
    #pragma unroll
    for (int q = 0; q < 8; ++q) {
      const int r0 = 2 * q;
      float v0 = RELU(ac0[r0] + be2j) + RELU(ac1[r0] + be2j) +
                 RELU(ac2[r0] + be2j) + RELU(ac3[r0] + be2j);
      float v1 = RELU(ac0[r0 + 1] + be2j) + RELU(ac1[r0 + 1] + be2j) +
                 RELU(ac2[r0 + 1] + be2j) + RELU(ac3[r0 + 1] + be2j);
      unsigned p = cvtpk(0.25f * v0, 0.25f * v1);
      const int e0_ = (r0 & 3) + 8 * (r0 >> 2) + ebase;
      const int e1_ = e0_ + 1;
      Z4[(e0_ << 7) + (j ^ (e0_ << 2))] = (unsigned short)p;
      Z4[(e1_ << 7) + (j ^ (e1_ << 2))] = (unsigned short)(p >> 16);
    }
  }
  __syncthreads();

  // ---- write efbuf (global, coalesced) ----
  {
    const int e  = t >> 3;
    const int kc = (t & 7) << 4;
    int i = iblk + e;
    if (i < hi) {
      const int sw = e << 2, rb = e << 7;
      uint2 c0 = *(const uint2*)&Z4[rb + ((kc + 0) ^ sw)];
      uint2 c1 = *(const uint2*)&Z4[rb + ((kc + 4) ^ sw)];
      uint2 c2 = *(const uint2*)&Z4[rb + ((kc + 8) ^ sw)];
      uint2 c3 = *(const uint2*)&Z4[rb + ((kc + 12) ^ sw)];
      *(uint4*)&efbuf[(size_t)(i - lo) * 128 + kc]     = make_uint4(c0.x, c0.y, c1.x, c1.y);
      *(uint4*)&efbuf[(size_t)(i - lo) * 128 + kc + 8] = make_uint4(c2.x, c2.y, c3.x, c3.y);
    }
  }

  // ---- stage 2: EF @ Wc1 ----
  f32x16 a2 = {0.f};
  {
    const unsigned short* WFc = WFc1 + ((wv << 12) | (lane << 3));
    #pragma unroll
    for (int s = 0; s < 8; ++s) {
      short8v bw = *(const short8v*)(WFc + (s << 9));
      const int k1 = s * 16 + khalf;
      const int i0 = baseA + (k1 ^ swA);
      const int i1 = baseA + ((k1 + 4) ^ swA);
      short8v af = __builtin_shufflevector(*(const short4v*)&Z4[i0],
                                           *(const short4v*)&Z4[i1], 0,1,2,3,4,5,6,7);
      a2 = __builtin_amdgcn_mfma_f32_32x32x16_bf16(af, bw, a2, 0, 0, 0);
    }
  }
  // ---- tv = relu(a2 + bc1) -> LDS region 1 (cvtpk pairs) ----
  {
    const int j = (wv << 5) | (lane & 31);
    const float bc1j = bc1[j];
    const int ebase = (lane >> 5) << 2;
    #pragma unroll
    for (int q = 0; q < 8; ++q) {
      const int r0 = 2 * q;
      unsigned p = cvtpk(RELU(a2[r0] + bc1j), RELU(a2[r0 + 1] + bc1j));
      const int e0_ = (r0 & 3) + 8 * (r0 >> 2) + ebase;
      const int e1_ = e0_ + 1;
      Z4[4096 + (e0_ << 7) + (j ^ (e0_ << 2))] = (unsigned short)p;
      Z4[4096 + (e1_ << 7) + (j ^ (e1_ << 2))] = (unsigned short)(p >> 16);
    }
  }
  __syncthreads();

  // ---- cm[e] = tv[e][:] @ Wc2 : 8 threads/edge, shfl reduce ----
  {
    const int e  = t >> 3;
    const int jc = (t & 7) << 4;
    const int sw = e << 2, rb = e << 7;
    uint2 d0 = *(const uint2*)&Z4[4096 + rb + ((jc + 0) ^ sw)];
    uint2 d1 = *(const uint2*)&Z4[4096 + rb + ((jc + 4) ^ sw)];
    uint2 d2 = *(const uint2*)&Z4[4096 + rb + ((jc + 8) ^ sw)];
    uint2 d3 = *(const uint2*)&Z4[4096 + rb + ((jc + 12) ^ sw)];
    unsigned uu[8] = {d0.x, d0.y, d1.x, d1.y, d2.x, d2.y, d3.x, d3.y};
    float cx = 0.f, cy = 0.f;
    #pragma unroll
    for (int q = 0; q < 8; ++q) {
      float t0 = bf2f((unsigned short)(uu[q] & 0xFFFFu));
      float t1 = bf2f((unsigned short)(uu[q] >> 16));
      float2 wA = *(const float2*)&Wc2s[2 * (jc + 2 * q)];
      float2 wB = *(const float2*)&Wc2s[2 * (jc + 2 * q + 1)];
      cx = fmaf(t0, wA.x, cx); cy = fmaf(t0, wA.y, cy);
      cx = fmaf(t1, wB.x, cx); cy = fmaf(t1, wB.y, cy);
    }
    cx += __shfl_xor(cx, 1); cy += __shfl_xor(cy, 1);
    cx += __shfl_xor(cx, 2); cy += __shfl_xor(cy, 2);
    cx += __shfl_xor(cx, 4); cy += __shfl_xor(cy, 4);
    if ((t & 7) == 0) { cmE[e][0] = cx; cmE[e][1] = cy; }
  }
  __syncthreads();
  if (t < ET) {
    int i = iblk + t;
    if (i < hi) {
      float tx = fminf(fmaxf(ped[8][t] * cmE[t][0], -100.0f), 100.0f);
      float ty = fminf(fmaxf(ped[9][t] * cmE[t][1], -100.0f), 100.0f);
      transbuf[(size_t)i * 2]     = tx;
      transbuf[(size_t)i * 2 + 1] = ty;
    }
  }
}

// ---------------------------------------------------------------------------
// Fused gather + node_final (nch==1). pk_add accumulation.
// ---------------------------------------------------------------------------
__global__ __launch_bounds__(256) void gather_final_mfma(
    const float* __restrict__ h, const float* __restrict__ coord,
    const float* __restrict__ vel,
    const unsigned short* __restrict__ WFn1a,
    const unsigned short* __restrict__ WFn1b,
    const unsigned short* __restrict__ WFn2,
    const float* __restrict__ bn1, const float* __restrict__ bn2,
    const int* __restrict__ ptr, const unsigned short* __restrict__ efbuf,
    const float* __restrict__ transbuf, const float* __restrict__ velfac,
    float* __restrict__ hout, float* __restrict__ cout, int N)
{
  const int t = threadIdx.x, wv = t >> 6, lane = t & 63;
  const int n0 = blockIdx.x * 32;
  __shared__ __align__(16) unsigned short Ah[4096];
  __shared__ __align__(16) unsigned short Ag[4096];
  __shared__ __align__(16) unsigned short Mid[4096];
  __shared__ float trs[32][2];

  {
    const int e = t >> 3, kc = (t & 7) << 4;
    const int n = n0 + e;
    const int sw = (e & 15) << 3, rb = e << 7;
    unsigned pk[8];
    f32x2 ac2[8];
    #pragma unroll
    for (int q = 0; q < 8; ++q) { f32x2 z = {0.f, 0.f}; ac2[q] = z; }
    float tx = 0.f, ty = 0.f;
    if (n < N) {
      const float* hp = h + (size_t)n * 128 + kc;
      #pragma unroll
      for (int qc = 0; qc < 4; ++qc) {
        float4 v = *(const float4*)(hp + qc * 4);
        pk[qc * 2] = cvtpk(v.x, v.y); pk[qc * 2 + 1] = cvtpk(v.z, v.w);
      }
      const int p0 = ptr[n], p1 = ptr[n + 1];
      for (int i = p0; i < p1; ++i) {
        uint4 a = *(const uint4*)&efbuf[(size_t)i * 128 + kc];
        uint4 b = *(const uint4*)&efbuf[(size_t)i * 128 + kc + 8];
        unsigned uu[8] = {a.x, a.y, a.z, a.w, b.x, b.y, b.z, b.w};
        #pragma unroll
        for (int q = 0; q < 8; ++q) ac2[q] = pk_add(ac2[q], unpk(uu[q]));
      }
      for (int i = p0 + (t & 7); i < p1; i += 8) {
        tx += transbuf[(size_t)i * 2];
        ty += transbuf[(size_t)i * 2 + 1];
      }
    } else {
      #pragma unroll
      for (int q = 0; q < 8; ++q) pk[q] = 0u;
    }
    tx += __shfl_xor(tx, 1); ty += __shfl_xor(ty, 1);
    tx += __shfl_xor(tx, 2); ty += __shfl_xor(ty, 2);
    tx += __shfl_xor(tx, 4); ty += __shfl_xor(ty, 4);
    if ((t & 7) == 0) { trs[e][0] = tx; trs[e][1] = ty; }
    *(uint4*)&Ah[rb + (kc ^ sw)]       = make_uint4(pk[0], pk[1], pk[2], pk[3]);
    *(uint4*)&Ah[rb + ((kc + 8) ^ sw)] = make_uint4(pk[4], pk[5], pk[6], pk[7]);
    unsigned gk[8];
    #pragma unroll
    for (int q = 0; q < 8; ++q) gk[q] = cvtpk(ac2[q].x, ac2[q].y);
    *(uint4*)&Ag[rb + (kc ^ sw)]       = make_uint4(gk[0], gk[1], gk[2], gk[3]);
    *(uint4*)&Ag[rb + ((kc + 8) ^ sw)] = make_uint4(gk[4], gk[5], gk[6], gk[7]);
  }
  __syncthreads();

  const int eA = lane & 31, khalf = (lane >> 5) << 3, swA = (eA & 15) << 3;
  const int baseA = eA << 7;
  f32x16 m = {0.f};
  {
    const unsigned short* p1 = WFn1a + ((wv << 12) | (lane << 3));
    const unsigned short* p2 = WFn1b + ((wv << 12) | (lane << 3));
    #pragma unroll
    for (int s = 0; s < 8; ++s) {
      const int i0 = baseA + ((s * 16 + khalf) ^ swA);
      short8v zh = *(const short8v*)&Ah[i0];
      short8v zg = *(const short8v*)&Ag[i0];
      m = __builtin_amdgcn_mfma_f32_32x32x16_bf16(zh, *(const short8v*)(p1 + (s << 9)), m, 0, 0, 0);
      m = __builtin_amdgcn_mfma_f32_32x32x16_bf16(zg, *(const short8v*)(p2 + (s << 9)), m, 0, 0, 0);
    }
  }
  const int colb = (wv << 5) | (lane & 31);
  const float bn1j = bn1[colb];
  const int ebase = (lane >> 5) << 2;
  #pragma unroll
  for (int r = 0; r < 16; ++r) {
    const int e = (r & 3) + 8 * (r >> 2) + ebase;
    Mid[(e << 7) + (colb ^ ((e & 15) << 3))] = f2bf(RELU(m[r] + bn1j));
  }
  __syncthreads();

  f32x16 o = {0.f};
  {
    const unsigned short* p3 = WFn2 + ((wv << 12) | (lane << 3));
    #pragma unroll
    for (int s = 0; s < 8; ++s) {
      const int i0 = baseA + ((s * 16 + khalf) ^ swA);
      short8v zm = *(const short8v*)&Mid[i0];
      o = __builtin_amdgcn_mfma_f32_32x32x16_bf16(zm, *(const short8v*)(p3 + (s << 9)), o, 0, 0, 0);
    }
  }
  const float bn2j = bn2[colb];
  #pragma unroll
  for (int r = 0; r < 16; ++r) {
    const int e = (r & 3) + 8 * (r >> 2) + ebase;
    const int n = n0 + e;
    if (n < N)
      hout[(size_t)n * 128 + colb] = h[(size_t)n * 128 + colb] + o[r] + bn2j;
  }
  if (t < 32) {
    const int n = n0 + t;
    if (n < N) {
      float c = (float)(ptr[n + 1] - ptr[n]);
      float vf = velfac[n];
      float inv = 1.0f / fmaxf(c, 1.0f);
      cout[(size_t)n * 2]     = coord[(size_t)n * 2]     + trs[t][0] * inv + vf * vel[(size_t)n * 2];
      cout[(size_t)n * 2 + 1] = coord[(size_t)n * 2 + 1] + trs[t][1] * inv + vf * vel[(size_t)n * 2 + 1];
    }
  }
}

// ---------------------------------------------------------------------------
// Chunked fallback (nch>1): gather + node_final.
// ---------------------------------------------------------------------------
__global__ __launch_bounds__(256) void gather_kernel(
    const int* __restrict__ ptr, const unsigned short* __restrict__ efbuf,
    const float* __restrict__ transbuf,
    unsigned short* __restrict__ aggnb, float* __restrict__ agg,
    int N, int lo, int hi, int first)
{
  const int wv = threadIdx.x >> 6, lane = threadIdx.x & 63;
  const int n = blockIdx.x * 4 + wv;
  if (n >= N) return;
  const int p0 = ptr[n], p1 = ptr[n + 1];
  const int a = p0 > lo ? p0 : lo;
  const int b = p1 < hi ? p1 : hi;
  const int sub = lane >> 4, c8 = (lane & 15) << 3;
  f32x2 ac2[4];
  #pragma unroll
  for (int q = 0; q < 4; ++q) { f32x2 z = {0.f, 0.f}; ac2[q] = z; }
  for (int i = a + sub; i < b; i += 4) {
    uint4 v = *(const uint4*)&efbuf[(size_t)(i - lo) * 128 + c8];
    unsigned uu[4] = {v.x, v.y, v.z, v.w};
    #pragma unroll
    for (int q = 0; q < 4; ++q) ac2[q] = pk_add(ac2[q], unpk(uu[q]));
  }
  #pragma unroll
  for (int q = 0; q < 4; ++q) {
    ac2[q].x += __shfl_xor(ac2[q].x, 16);
    ac2[q].y += __shfl_xor(ac2[q].y, 16);
    ac2[q].x += __shfl_xor(ac2[q].x, 32);
    ac2[q].y += __shfl_xor(ac2[q].y, 32);
  }
  if (lane < 16) {
    if (!first) {
      uint4 old = *(const uint4*)&aggnb[(size_t)n * 128 + c8];
      unsigned uo[4] = {old.x, old.y, old.z, old.w};
      #pragma unroll
      for (int q = 0; q < 4; ++q) ac2[q] = pk_add(ac2[q], unpk(uo[q]));
    }
    unsigned pk[4];
    #pragma unroll
    for (int q = 0; q < 4; ++q) pk[q] = cvtpk(ac2[q].x, ac2[q].y);
    *(uint4*)&aggnb[(size_t)n * 128 + c8] = make_uint4(pk[0], pk[1], pk[2], pk[3]);
  }
  if (lane < 2) {
    float tacc = first ? 0.f : agg[(size_t)n * 2 + lane];
    for (int i = a; i < b; ++i) tacc += transbuf[(size_t)i * 2 + lane];
    agg[(size_t)n * 2 + lane] = tacc;
  }
}

__global__ __launch_bounds__(256) void node_final_mfma(
    const float* __restrict__ h, const float* __restrict__ coord,
    const float* __restrict__ vel,
    const unsigned short* __restrict__ WFn1a,
    const unsigned short* __restrict__ WFn1b,
    const unsigned short* __restrict__ WFn2,
    const float* __restrict__ bn1, const float* __restrict__ bn2,
    const float* __restrict__ agg, const int* __restrict__ ptr,
    const unsigned short* __restrict__ aggnb, const float* __restrict__ velfac,
    float* __restrict__ hout, float* __restrict__ cout, int N)
{
  const int t = threadIdx.x, wv = t >> 6, lane = t & 63;
  const int n0 = blockIdx.x * 32;
  __shared__ __align__(16) unsigned short Ah[4096];
  __shared__ __align__(16) unsigned short Ag[4096];
  __shared__ __align__(16) unsigned short Mid[4096];

  {
    const int e = t >> 3, kc = (t & 7) << 4;
    const int n = n0 + e;
    unsigned pk[8], gk[8];
    if (n < N) {
      const float* hp = h + (size_t)n * 128 + kc;
      #pragma unroll
      for (int qc = 0; qc < 4; ++qc) {
        float4 v = *(const float4*)(hp + qc * 4);
        pk[qc * 2] = cvtpk(v.x, v.y); pk[qc * 2 + 1] = cvtpk(v.z, v.w);
      }
      uint4 g0 = *(const uint4*)&aggnb[(size_t)n * 128 + kc];
      uint4 g1 = *(const uint4*)&aggnb[(size_t)n * 128 + kc + 8];
      gk[0] = g0.x; gk[1] = g0.y; gk[2] = g0.z; gk[3] = g0.w;
      gk[4] = g1.x; gk[5] = g1.y; gk[6] = g1.z; gk[7] = g1.w;
    } else {
      #pragma unroll
      for (int q = 0; q < 8; ++q) { pk[q] = 0u; gk[q] = 0u; }
    }
    const int sw = (e & 15) << 3, rb = e << 7;
    *(uint4*)&Ah[rb + (kc ^ sw)]       = make_uint4(pk[0], pk[1], pk[2], pk[3]);
    *(uint4*)&Ah[rb + ((kc + 8) ^ sw)] = make_uint4(pk[4], pk[5], pk[6], pk[7]);
    *(uint4*)&Ag[rb + (kc ^ sw)]       = make_uint4(gk[0], gk[1], gk[2], gk[3]);
    *(uint4*)&Ag[rb + ((kc + 8) ^ sw)] = make_uint4(gk[4], gk[5], gk[6], gk[7]);
  }
  __syncthreads();

  const int eA = lane & 31, khalf = (lane >> 5) << 3, swA = (eA & 15) << 3;
  const int baseA = eA << 7;
  f32x16 m = {0.f};
  {
    const unsigned short* p1 = WFn1a + ((wv << 12) | (lane << 3));
    const unsigned short* p2 = WFn1b + ((wv << 12) | (lane << 3));
    #pragma unroll
    for (int s = 0; s < 8; ++s) {
      const int i0 = baseA + ((s * 16 + khalf) ^ swA);
      short8v zh = *(const short8v*)&Ah[i0];
      short8v zg = *(const short8v*)&Ag[i0];
      m = __builtin_amdgcn_mfma_f32_32x32x16_bf16(zh, *(const short8v*)(p1 + (s << 9)), m, 0, 0, 0);
      m = __builtin_amdgcn_mfma_f32_32x32x16_bf16(zg, *(const short8v*)(p2 + (s << 9)), m, 0, 0, 0);
    }
  }
  const int colb = (wv << 5) | (lane & 31);
  const float bn1j = bn1[colb];
  const int ebase = (lane >> 5) << 2;
  #pragma unroll
  for (int r = 0; r < 16; ++r) {
    const int e = (r & 3) + 8 * (r >> 2) + ebase;
    Mid[(e << 7) + (colb ^ ((e & 15) << 3))] = f2bf(RELU(m[r] + bn1j));
  }
  __syncthreads();

  f32x16 o = {0.f};
  {
    const unsigned short* p3 = WFn2 + ((wv << 12) | (lane << 3));
    #pragma unroll
    for (int s = 0; s < 8; ++s) {
      const int i0 = baseA + ((s * 16 + khalf) ^ swA);
      short8v zm = *(const short8v*)&Mid[i0];
      o = __builtin_amdgcn_mfma_f32_32x32x16_bf16(zm, *(const short8v*)(p3 + (s << 9)), o, 0, 0, 0);
    }
  }
  const float bn2j = bn2[colb];
  #pragma unroll
  for (int r = 0; r < 16; ++r) {
    const int e = (r & 3) + 8 * (r >> 2) + ebase;
    const int n = n0 + e;
    if (n < N)
      hout[(size_t)n * 128 + colb] = h[(size_t)n * 128 + colb] + o[r] + bn2j;
  }
  if (t < 32) {
    const int n = n0 + t;
    if (n < N) {
      float c = (float)(ptr[n + 1] - ptr[n]);
      float vf = velfac[n];
      float inv = 1.0f / fmaxf(c, 1.0f);
      cout[(size_t)n * 2]     = coord[(size_t)n * 2]     + agg[(size_t)n * 2] * inv     + vf * vel[(size_t)n * 2];
      cout[(size_t)n * 2 + 1] = coord[(size_t)n * 2 + 1] + agg[(size_t)n * 2 + 1] * inv + vf * vel[(size_t)n * 2 + 1];
    }
  }
}

// ---------------------------------------------------------------------------
// Legacy fp32 fallback kernels (ws too small for efbuf).
// ---------------------------------------------------------------------------
__global__ __launch_bounds__(256) void edge_kernel_legacy(
    const int* __restrict__ row, const int* __restrict__ col,
    const float* __restrict__ Hr, const float* __restrict__ Hc,
    const float* __restrict__ coord, const float* __restrict__ vel,
    const float* __restrict__ We1, const float* __restrict__ We2,
    const float* __restrict__ be2, const float* __restrict__ Wc1,
    const float* __restrict__ bc1, const float* __restrict__ Wc2,
    float* __restrict__ agg, float* __restrict__ cnt, float* __restrict__ aggn,
    int E)
{
  const int t  = threadIdx.x;
  const int el = t & 31;
  const int jg = t >> 5;
  const int j0 = jg * 16;
  const int e0 = blockIdx.x * ET;

  __shared__ __align__(16) float Wch[32][128];
  __shared__ __align__(16) float Zbuf[4256];
  __shared__ __align__(16) float W9[9][128];
  __shared__ float ped[11][32];
  __shared__ int   rs[32], cs[32], vE[32];
  __shared__ float cmP[8][32][2];

#define Z4L(g, e_, k_) Zbuf[((g) * 32 + (e_)) * 33 + (k_)]
#define EFL(e_, k_)    Zbuf[(e_) * 133 + (k_)]

  if (t < ET) {
    int e = e0 + t;
    int r = 0, c = 0, v = 0;
    if (e < E) { r = row[e]; c = col[e]; v = 1; }
    rs[t] = r; cs[t] = c; vE[t] = v;
    float crx = coord[2 * r], cry = coord[2 * r + 1];
    float ccx = coord[2 * c], ccy = coord[2 * c + 1];
    ped[0][t] = crx; ped[1][t] = cry; ped[2][t] = ccx; ped[3][t] = ccy;
    ped[4][t] = vel[2 * r]; ped[5][t] = vel[2 * r + 1];
    ped[6][t] = vel[2 * c]; ped[7][t] = vel[2 * c + 1];
    float dx = crx - ccx, dy = cry - ccy;
    ped[8][t] = dx; ped[9][t] = dy; ped[10][t] = dx * dx + dy * dy;
  }
  for (int idx = t; idx < 9 * 128; idx += 256)
    W9[idx >> 7][idx & 127] = We1[(size_t)(256 + (idx >> 7)) * 128 + (idx & 127)];

  float outg[4][16];
  #pragma unroll
  for (int g = 0; g < 4; ++g)
    #pragma unroll
    for (int jj = 0; jj < 16; ++jj) outg[g][jj] = 0.0f;

  for (int kc = 0; kc < 4; ++kc) {
    const int kb = kc * 32;
    __syncthreads();
    #pragma unroll
    for (int s = 0; s < 4; ++s) {
      int idx4 = t + s * 256;
      int kl = idx4 >> 5, jc = (idx4 & 31) * 4;
      *(float4*)&Wch[kl][jc] = *(const float4*)&We2[(size_t)(kb + kl) * 128 + jc];
    }
    {
      const int kk = kb + (jg << 2);
      const int kl = jg << 2;
      const int r = rs[el], c = cs[el];
      float4 a4 = *(const float4*)(Hr + (size_t)r * 128 + kk);
      float4 b4 = *(const float4*)(Hc + (size_t)c * 128 + kk);
      float hr[4] = {a4.x, a4.y, a4.z, a4.w};
      float hcv[4] = {b4.x, b4.y, b4.z, b4.w};
      float4 q;
      q = *(const float4*)&W9[0][kk]; float w0[4] = {q.x, q.y, q.z, q.w};
      q = *(const float4*)&W9[1][kk]; float w1[4] = {q.x, q.y, q.z, q.w};
      q = *(const float4*)&W9[2][kk]; float w2[4] = {q.x, q.y, q.z, q.w};
      q = *(const float4*)&W9[3][kk]; float w3[4] = {q.x, q.y, q.z, q.w};
      q = *(const float4*)&W9[4][kk]; float w4[4] = {q.x, q.y, q.z, q.w};
      q = *(const float4*)&W9[5][kk]; float w5[4] = {q.x, q.y, q.z, q.w};
      q = *(const float4*)&W9[6][kk]; float w6[4] = {q.x, q.y, q.z, q.w};
      q = *(const float4*)&W9[7][kk]; float w7[4] = {q.x, q.y, q.z, q.w};
      q = *(const float4*)&W9[8][kk]; float w8[4] = {q.x, q.y, q.z, q.w};
      float xr = ped[0][el], yr = ped[1][el], xc = ped[2][el], yc = ped[3][el];
      float vrx = ped[4][el], vry = ped[5][el], vcx = ped[6][el], vcy = ped[7][el];
      float d2 = ped[10][el];
      #pragma unroll
      for (int i = 0; i < 4; ++i) {
        float base = hr[i] + hcv[i] + d2 * w4[i];
        float A = xr * w0[i] + xc * w2[i] + vrx * w5[i] + vcx * w7[i];
        float B = yr * w1[i] + yc * w3[i] + vry * w6[i] + vcy * w8[i];
        Z4L(0, el, kl + i) = RELU(base + A + B);
        Z4L(1, el, kl + i) = RELU(base - A - B);
        Z4L(2, el, kl + i) = RELU(base - A + B);
        Z4L(3, el, kl + i) = RELU(base + A - B);
      }
    }
    __syncthreads();
    #pragma unroll 2
    for (int k = 0; k < 32; ++k) {
      float4 wa = *(const float4*)&Wch[k][j0];
      float4 wb = *(const float4*)&Wch[k][j0 + 4];
      float4 wc4 = *(const float4*)&Wch[k][j0 + 8];
      float4 wd = *(const float4*)&Wch[k][j0 + 12];
      float w[16] = {wa.x, wa.y, wa.z, wa.w, wb.x, wb.y, wb.z, wb.w,
                     wc4.x, wc4.y, wc4.z, wc4.w, wd.x, wd.y, wd.z, wd.w};
      float z0 = Z4L(0, el, k), z1 = Z4L(1, el, k);
      float z2 = Z4L(2, el, k), z3 = Z4L(3, el, k);
      #pragma unroll
      for (int jj = 0; jj < 16; ++jj) {
        outg[0][jj] = fmaf(z0, w[jj], outg[0][jj]);
        outg[1][jj] = fmaf(z1, w[jj], outg[1][jj]);
        outg[2][jj] = fmaf(z2, w[jj], outg[2][jj]);
        outg[3][jj] = fmaf(z3, w[jj], outg[3][jj]);
      }
    }
  }

  __syncthreads();
  float4 q0 = *(const float4*)(be2 + j0);
  float4 q1 = *(const float4*)(be2 + j0 + 4);
  float4 q2 = *(const float4*)(be2 + j0 + 8);
  float4 q3 = *(const float4*)(be2 + j0 + 12);
  float beA[16] = {q0.x, q0.y, q0.z, q0.w, q1.x, q1.y, q1.z, q1.w,
                   q2.x, q2.y, q2.z, q2.w, q3.x, q3.y, q3.z, q3.w};
  float ef[16];
  #pragma unroll
  for (int jj = 0; jj < 16; ++jj) {
    float s = RELU(outg[0][jj] + beA[jj]) + RELU(outg[1][jj] + beA[jj]) +
              RELU(outg[2][jj] + beA[jj]) + RELU(outg[3][jj] + beA[jj]);
    ef[jj] = 0.25f * s;
  }
  #pragma unroll
  for (int jj = 0; jj < 16; ++jj) EFL(el, j0 + jj) = ef[jj];
  {
    const int r = rs[el];
    if (vE[el]) {
      #pragma unroll
      for (int jj = 0; jj < 16; ++jj)
        unsafeAtomicAdd(&aggn[(size_t)r * 128 + j0 + jj], ef[jj]);
    }
  }

  float acc2[16];
  #pragma unroll
  for (int jj = 0; jj < 16; ++jj) acc2[jj] = 0.0f;
  for (int kc = 0; kc < 4; ++kc) {
    const int kb = kc * 32;
    __syncthreads();
    #pragma unroll
    for (int s = 0; s < 4; ++s) {
      int idx4 = t + s * 256;
      int kl = idx4 >> 5, jc = (idx4 & 31) * 4;
      *(float4*)&Wch[kl][jc] = *(const float4*)&Wc1[(size_t)(kb + kl) * 128 + jc];
    }
    __syncthreads();
    #pragma unroll 4
    for (int k = 0; k < 32; ++k) {
      float4 wa = *(const float4*)&Wch[k][j0];
      float4 wb = *(const float4*)&Wch[k][j0 + 4];
      float4 wc4 = *(const float4*)&Wch[k][j0 + 8];
      float4 wd = *(const float4*)&Wch[k][j0 + 12];
      float w[16] = {wa.x, wa.y, wa.z, wa.w, wb.x, wb.y, wb.z, wb.w,
                     wc4.x, wc4.y, wc4.z, wc4.w, wd.x, wd.y, wd.z, wd.w};
      float efk = EFL(el, kb + k);
      #pragma unroll
      for (int jj = 0; jj < 16; ++jj) acc2[jj] = fmaf(efk, w[jj], acc2[jj]);
    }
  }

  float cm0 = 0.f, cm1 = 0.f;
  #pragma unroll
  for (int jj = 0; jj < 16; ++jj) {
    float tv = RELU(acc2[jj] + bc1[j0 + jj]);
    float2 wp = *(const float2*)(Wc2 + 2 * (j0 + jj));
    cm0 = fmaf(tv, wp.x, cm0);
    cm1 = fmaf(tv, wp.y, cm1);
  }
  cmP[jg][el][0] = cm0; cmP[jg][el][1] = cm1;
  __syncthreads();
  if (t < ET && vE[t]) {
    float c0 = 0.f, c1 = 0.f;
    #pragma unroll
    for (int g = 0; g < 8; ++g) { c0 += cmP[g][t][0]; c1 += cmP[g][t][1]; }
    float dx = ped[8][t], dy = ped[9][t];
    float tx = fminf(fmaxf(dx * c0, -100.0f), 100.0f);
    float ty = fminf(fmaxf(dy * c1, -100.0f), 100.0f);
    const int r = rs[t];
    unsafeAtomicAdd(&agg[(size_t)r * 2], tx);
    unsafeAtomicAdd(&agg[(size_t)r * 2 + 1], ty);
    unsafeAtomicAdd(&cnt[r], 1.0f);
  }
}

__global__ __launch_bounds__(128) void node_pre_legacy(
    const float* __restrict__ h, const float* __restrict__ We1,
    const float* __restrict__ be1,
    const float* __restrict__ Wv1, const float* __restrict__ bv1,
    const float* __restrict__ Wv2, const float* __restrict__ bv2,
    float* __restrict__ Hr, float* __restrict__ Hc, float* __restrict__ velfac)
{
  const int j = threadIdx.x;
  const int n0 = blockIdx.x * 8;
  __shared__ __align__(16) float hl[128][8];
  __shared__ float vp[8][128];

  #pragma unroll
  for (int s = 0; s < 8; ++s) hl[j][s] = h[(size_t)(n0 + s) * 128 + j];
  __syncthreads();

  float aR[8], aC[8], aV[8];
  #pragma unroll
  for (int n = 0; n < 8; ++n) { aR[n] = 0.f; aC[n] = 0.f; aV[n] = 0.f; }

  for (int k = 0; k < 128; ++k) {
    float wr = We1[(size_t)k * 128 + j];
    float wc = We1[(size_t)(128 + k) * 128 + j];
    float wv = Wv1[(size_t)k * 128 + j];
    float4 h0 = *(const float4*)&hl[k][0];
    float4 h1 = *(const float4*)&hl[k][4];
    float hv[8] = {h0.x, h0.y, h0.z, h0.w, h1.x, h1.y, h1.z, h1.w};
    #pragma unroll
    for (int n = 0; n < 8; ++n) {
      aR[n] = fmaf(hv[n], wr, aR[n]);
      aC[n] = fmaf(hv[n], wc, aC[n]);
      aV[n] = fmaf(hv[n], wv, aV[n]);
    }
  }
  float b1 = be1[j], bv = bv1[j], w2 = Wv2[j];
  #pragma unroll
  for (int n = 0; n < 8; ++n) {
    Hr[(size_t)(n0 + n) * 128 + j] = aR[n] + b1;
    Hc[(size_t)(n0 + n) * 128 + j] = aC[n];
    vp[n][j] = RELU(aV[n] + bv) * w2;
  }
  __syncthreads();
  if (j < 8) {
    float s = 0.f;
    for (int k = 0; k < 128; ++k) s += vp[j][k];
    velfac[n0 + j] = s + bv2[0];
  }
}

__global__ __launch_bounds__(128) void node_final_legacy(
    const float* __restrict__ h, const float* __restrict__ coord,
    const float* __restrict__ vel,
    const float* __restrict__ Wn1, const float* __restrict__ bn1,
    const float* __restrict__ Wn2, const float* __restrict__ bn2,
    const float* __restrict__ agg, const float* __restrict__ cntbuf,
    const float* __restrict__ aggn, const float* __restrict__ velfac,
    float* __restrict__ hout, float* __restrict__ cout)
{
  const int j = threadIdx.x;
  const int n0 = blockIdx.x * 4;
  __shared__ __align__(16) float xl[256][4];
  __shared__ __align__(16) float tl[128][4];

  #pragma unroll
  for (int s = 0; s < 8; ++s) {
    int idx = s * 128 + j;
    int n = idx >> 8, k = idx & 255;
    float v = (k < 128) ? h[(size_t)(n0 + n) * 128 + k]
                        : aggn[(size_t)(n0 + n) * 128 + (k - 128)];
    xl[k][n] = v;
  }
  __syncthreads();
  float acc[4] = {0.f, 0.f, 0.f, 0.f};
  for (int k = 0; k < 256; ++k) {
    float w = Wn1[(size_t)k * 128 + j];
    float4 xv = *(const float4*)&xl[k][0];
    acc[0] = fmaf(xv.x, w, acc[0]);
    acc[1] = fmaf(xv.y, w, acc[1]);
    acc[2] = fmaf(xv.z, w, acc[2]);
    acc[3] = fmaf(xv.w, w, acc[3]);
  }
  float b = bn1[j];
  #pragma unroll
  for (int n = 0; n < 4; ++n) tl[j][n] = RELU(acc[n] + b);
  __syncthreads();
  float a2[4] = {0.f, 0.f, 0.f, 0.f};
  for (int k = 0; k < 128; ++k) {
    float w = Wn2[(size_t)k * 128 + j];
    float4 tv = *(const float4*)&tl[k][0];
    a2[0] = fmaf(tv.x, w, a2[0]);
    a2[1] = fmaf(tv.y, w, a2[1]);
    a2[2] = fmaf(tv.z, w, a2[2]);
    a2[3] = fmaf(tv.w, w, a2[3]);
  }
  float b2 = bn2[j];
  #pragma unroll
  for (int n = 0; n < 4; ++n)
    hout[(size_t)(n0 + n) * 128 + j] = h[(size_t)(n0 + n) * 128 + j] + a2[n] + b2;
  if (j < 8) {
    int n = j >> 1, d = j & 1;
    int node = n0 + n;
    float cdel = agg[(size_t)node * 2 + d] / fmaxf(cntbuf[node], 1.0f);
    cout[(size_t)node * 2 + d] =
        coord[(size_t)node * 2 + d] + cdel + velfac[node] * vel[(size_t)node * 2 + d];
  }
}

// ---------------------------------------------------------------------------
extern "C" void kernel_launch(void* const* d_in, const int* in_sizes, int n_in,
                              void* d_out, int out_size, void* d_ws, size_t ws_size,
                              hipStream_t stream)
{
  const float* h     = (const float*)d_in[0];
  const float* coord = (const float*)d_in[1];
  const float* vel   = (const float*)d_in[2];
  const float* We1   = (const float*)d_in[3];
  const float* be1   = (const float*)d_in[4];
  const float* We2   = (const float*)d_in[5];
  const float* be2   = (const float*)d_in[6];
  const float* Wc1   = (const float*)d_in[7];
  const float* bc1   = (const float*)d_in[8];
  const float* Wc2   = (const float*)d_in[9];
  const float* Wn1   = (const float*)d_in[10];
  const float* bn1   = (const float*)d_in[11];
  const float* Wn2   = (const float*)d_in[12];
  const float* bn2   = (const float*)d_in[13];
  const float* Wv1   = (const float*)d_in[14];
  const float* bv1   = (const float*)d_in[15];
  const float* Wv2   = (const float*)d_in[16];
  const float* bv2   = (const float*)d_in[17];
  const int*   ei    = (const int*)d_in[18];

  const int N = in_sizes[0] / 128;
  const int E = in_sizes[18] / 2;
  const int* row = ei;
  const int* col = ei + E;

  char* base = (char*)d_ws;
  size_t off = 0;
  auto alloc = [&](size_t bytes) -> char* {
    char* p = base + off;
    off += (bytes + 255) & ~(size_t)255;
    return p;
  };
  float* Hr     = (float*)alloc((size_t)N * 128 * 4);
  float* Hc     = (float*)alloc((size_t)N * 128 * 4);
  float* velfac = (float*)alloc((size_t)N * 4);
  float* zblk   = (float*)alloc((size_t)132 * N * 4);  // deg|agg|cnt|aggn
  int*   deg    = (int*)zblk;
  float* agg    = zblk + N;
  float* cnt    = agg + (size_t)2 * N;
  float* aggn   = cnt + N;
  unsigned short* aggnb = (unsigned short*)aggn;
  int*   ptr    = (int*)alloc((size_t)(N + 1) * 4);
  int*   wptr   = (int*)alloc((size_t)N * 4);
  int*   rowS   = (int*)alloc((size_t)E * 4);
  int*   colS   = (int*)alloc((size_t)E * 4);
  float* trans  = (float*)alloc((size_t)E * 2 * 4);
  unsigned short* wfall = (unsigned short*)alloc((size_t)8 * 16384 * 2);
  size_t fixed_end = off;
  unsigned short* efbuf = (unsigned short*)(base + fixed_end);

  unsigned short* WFe1r = wfall;
  unsigned short* WFe1c = wfall + 16384;
  unsigned short* WFv1  = wfall + 2 * 16384;
  unsigned short* WFe2  = wfall + 3 * 16384;
  unsigned short* WFc1  = wfall + 4 * 16384;
  unsigned short* WFn1a = wfall + 5 * 16384;
  unsigned short* WFn1b = wfall + 6 * 16384;
  unsigned short* WFn2  = wfall + 7 * 16384;

  int use_csr = 0, EC = 0, nch = 1;
  if (ws_size > fixed_end) {
    size_t ec_max = (ws_size - fixed_end) / 256;
    ec_max &= ~(size_t)31;
    if (ec_max >= 32768) {
      use_csr = 1;
      size_t e_pad = ((size_t)E + 31) & ~(size_t)31;
      EC = (int)((ec_max < e_pad) ? ec_max : e_pad);
      nch = (E + EC - 1) / EC;
    }
  }

  const int nblk32 = (N + 31) / 32;
  float* hout = (float*)d_out;
  float* cout = hout + (size_t)N * 128;

  if (use_csr) {
    const int degB = (E + 255) / 256;
    const int scatB = (E + 255) / 256;
    hipMemsetAsync(deg, 0, (size_t)N * 4, stream);
    hipLaunchKernelGGL(deg_wprep_kernel, dim3(degB + 512), dim3(256), 0, stream,
                       row, deg, E, degB, We1, Wv1, We2, Wc1, Wn1, Wn2, wfall);
    hipLaunchKernelGGL(scan_kernel, dim3(1), dim3(1024), 0, stream,
                       deg, ptr, wptr, N, E);
    hipLaunchKernelGGL(scatter_nodepre_kernel, dim3(scatB + nblk32), dim3(256), 0,
                       stream, row, col, wptr, rowS, colS, E, scatB,
                       h, WFe1r, WFe1c, WFv1, be1, bv1, Wv2, bv2,
                       Hr, Hc, velfac, N);
    if (nch == 1) {
      hipLaunchKernelGGL(edge_mfma_kernel, dim3((E + ET - 1) / ET), dim3(256), 0,
                         stream, rowS, colS, Hr, Hc, coord, vel, We1,
                         WFe2, WFc1, be2, bc1, Wc2, efbuf, trans, 0, E);
      hipLaunchKernelGGL(gather_final_mfma, dim3(nblk32), dim3(256), 0, stream,
                         h, coord, vel, WFn1a, WFn1b, WFn2, bn1, bn2,
                         ptr, efbuf, trans, velfac, hout, cout, N);
    } else {
      for (int c = 0; c < nch; ++c) {
        int lo = c * EC;
        int hi = (lo + EC < E) ? lo + EC : E;
        int nb = (hi - lo + ET - 1) / ET;
        hipLaunchKernelGGL(edge_mfma_kernel, dim3(nb), dim3(256), 0, stream,
                           rowS, colS, Hr, Hc, coord, vel, We1,
                           WFe2, WFc1, be2, bc1, Wc2, efbuf, trans, lo, hi);
        hipLaunchKernelGGL(gather_kernel, dim3((N + 3) / 4), dim3(256), 0, stream,
                           ptr, efbuf, trans, aggnb, agg, N, lo, hi, (c == 0) ? 1 : 0);
      }
      hipLaunchKernelGGL(node_final_mfma, dim3(nblk32), dim3(256), 0, stream,
                         h, coord, vel, WFn1a, WFn1b, WFn2, bn1, bn2,
                         agg, ptr, aggnb, velfac, hout, cout, N);
    }
  } else {
    hipMemsetAsync(zblk, 0, (size_t)132 * N * 4, stream);
    hipLaunchKernelGGL(node_pre_legacy, dim3(N / 8), dim3(128), 0, stream,
                       h, We1, be1, Wv1, bv1, Wv2, bv2, Hr, Hc, velfac);
    hipLaunchKernelGGL(edge_kernel_legacy, dim3((E + ET - 1) / ET), dim3(256), 0,
                       stream, row, col, Hr, Hc, coord, vel, We1, We2, be2,
                       Wc1, bc1, Wc2, agg, cnt, aggn, E);
    hipLaunchKernelGGL(node_final_legacy, dim3(N / 4), dim3(128), 0, stream,
                       h, coord, vel, Wn1, bn1, Wn2, bn2, agg, cnt,
                       aggn, velfac, hout, cout);
  }
}

// Round 12
// 556.160 us; speedup vs baseline: 1.2185x; 1.1670x over previous
//
#include <hip/hip_runtime.h>

#define RELU(x) fmaxf((x), 0.0f)

typedef __attribute__((ext_vector_type(2))) float f32x2;
typedef __attribute__((ext_vector_type(4))) short short4v;
typedef __attribute__((ext_vector_type(8))) short short8v;
typedef __attribute__((ext_vector_type(16))) float f32x16;

__device__ __forceinline__ float bf2f(unsigned short u) {
  unsigned v = ((unsigned)u) << 16;
  float f; __builtin_memcpy(&f, &v, 4); return f;
}
__device__ __forceinline__ unsigned short f2bf(float f) {
  unsigned u; __builtin_memcpy(&u, &f, 4);
  unsigned r = (u + 0x7FFFu + ((u >> 16) & 1u)) >> 16;
  return (unsigned short)r;
}
// HW packed convert: dst = {lo: bf16(a), hi: bf16(b)} (RNE).
__device__ __forceinline__ unsigned cvtpk(float a, float b) {
  unsigned r;
  asm("v_cvt_pk_bf16_f32 %0, %1, %2" : "=v"(r) : "v"(a), "v"(b));
  return r;
}
// packed f32 add: one instruction, two adds.
__device__ __forceinline__ f32x2 pk_add(f32x2 a, f32x2 b) {
  f32x2 d;
  asm("v_pk_add_f32 %0, %1, %2" : "=v"(d) : "v"(a), "v"(b));
  return d;
}
// unpack uint (2 bf16) -> f32 pair: lo = u<<16, hi = u & 0xFFFF0000.
__device__ __forceinline__ f32x2 unpk(unsigned u) {
  unsigned lo = u << 16, hi = u & 0xFFFF0000u;
  float fx, fy;
  __builtin_memcpy(&fx, &lo, 4);
  __builtin_memcpy(&fy, &hi, 4);
  f32x2 r = {fx, fy};
  return r;
}

// ---------------------------------------------------------------------------
// Fused: deg histogram + wprep8.
// ---------------------------------------------------------------------------
__global__ __launch_bounds__(256) void deg_wprep_kernel(
    const int* __restrict__ row, int* __restrict__ deg, int E, int degB,
    const float* __restrict__ We1, const float* __restrict__ Wv1,
    const float* __restrict__ We2, const float* __restrict__ Wc1,
    const float* __restrict__ Wn1, const float* __restrict__ Wn2,
    unsigned short* __restrict__ WF)
{
  if ((int)blockIdx.x < degB) {
    int e = blockIdx.x * 256 + threadIdx.x;
    if (e < E) atomicAdd(&deg[row[e]], 1);
    return;
  }
  const int bid = blockIdx.x - degB;
  const int g = bid >> 6;
  const int idx = (bid & 63) * 256 + threadIdx.x;
  const float* W;
  switch (g) {
    case 0: W = We1; break;
    case 1: W = We1 + 16384; break;
    case 2: W = Wv1; break;
    case 3: W = We2; break;
    case 4: W = Wc1; break;
    case 5: W = Wn1; break;
    case 6: W = Wn1 + 16384; break;
    default: W = Wn2; break;
  }
  int j = idx & 7, l = (idx >> 3) & 63, s = (idx >> 9) & 7, n = idx >> 12;
  int k = s * 16 + ((l >> 5) << 3) + j;
  int c = n * 32 + (l & 31);
  WF[g * 16384 + idx] = f2bf(W[k * 128 + c]);
}

// ---------------------------------------------------------------------------
// Parallel scan: 3 small kernels (partial sums -> block offsets -> write).
// ---------------------------------------------------------------------------
__global__ __launch_bounds__(1024) void scan_sum_kernel(
    const int* __restrict__ deg, int* __restrict__ bsum, int N)
{
  __shared__ int s[1024];
  const int t = threadIdx.x;
  const int i = blockIdx.x * 1024 + t;
  s[t] = (i < N) ? deg[i] : 0;
  __syncthreads();
  for (int off = 512; off >= 1; off >>= 1) {
    if (t < off) s[t] += s[t + off];
    __syncthreads();
  }
  if (t == 0) bsum[blockIdx.x] = s[0];
}

__global__ __launch_bounds__(1024) void scan_off_kernel(
    const int* __restrict__ bsum, int* __restrict__ boff, int nb)
{
  __shared__ int s[2][1024];
  const int t = threadIdx.x;
  s[0][t] = (t < nb) ? bsum[t] : 0;
  __syncthreads();
  int src = 0;
  for (int off = 1; off < 1024; off <<= 1) {
    int v = s[src][t];
    if (t >= off) v += s[src][t - off];
    s[src ^ 1][t] = v;
    __syncthreads();
    src ^= 1;
  }
  if (t < nb) boff[t] = t ? s[src][t - 1] : 0;
}

__global__ __launch_bounds__(1024) void scan_write_kernel(
    const int* __restrict__ deg, const int* __restrict__ boff,
    int* __restrict__ ptr, int* __restrict__ wptr, int N, int E)
{
  __shared__ int s[2][1024];
  const int t = threadIdx.x;
  const int i = blockIdx.x * 1024 + t;
  s[0][t] = (i < N) ? deg[i] : 0;
  __syncthreads();
  int src = 0;
  for (int off = 1; off < 1024; off <<= 1) {
    int v = s[src][t];
    if (t >= off) v += s[src][t - off];
    s[src ^ 1][t] = v;
    __syncthreads();
    src ^= 1;
  }
  if (i < N) {
    int ex = boff[blockIdx.x] + (t ? s[src][t - 1] : 0);
    ptr[i] = ex;
    wptr[i] = ex;
  }
  if (blockIdx.x == 0 && t == 0) ptr[N] = E;
}

// ---------------------------------------------------------------------------
// Fused: scatter (writes SORTED int2 (row,col) pairs) + node_pre MFMA.
// ---------------------------------------------------------------------------
__global__ __launch_bounds__(256) void scatter_nodepre_kernel(
    const int* __restrict__ row, const int* __restrict__ col,
    int* __restrict__ wptr, int2* __restrict__ ecS, int E, int scatB,
    const float* __restrict__ h,
    const unsigned short* __restrict__ WFe1r,
    const unsigned short* __restrict__ WFe1c,
    const unsigned short* __restrict__ WFv1,
    const float* __restrict__ be1, const float* __restrict__ bv1,
    const float* __restrict__ Wv2, const float* __restrict__ bv2,
    float* __restrict__ Hr, float* __restrict__ Hc, float* __restrict__ velfac,
    int N)
{
  __shared__ __align__(16) unsigned short Ah[4096];
  __shared__ float Wv2s[128];
  __shared__ float vpart[32][4];

  if ((int)blockIdx.x < scatB) {
    int e = blockIdx.x * 256 + threadIdx.x;
    if (e < E) {
      int r = row[e];
      int pos = atomicAdd(&wptr[r], 1);
      ecS[pos] = make_int2(r, col[e]);
    }
    return;
  }
  const int t = threadIdx.x, wv = t >> 6, lane = t & 63;
  const int n0 = (blockIdx.x - scatB) * 32;

  if (t < 128) Wv2s[t] = Wv2[t];
  {
    const int e = t >> 3, kc = (t & 7) << 4;
    const int n = n0 + e;
    unsigned pk[8];
    if (n < N) {
      const float* hp = h + (size_t)n * 128 + kc;
      #pragma unroll
      for (int qc = 0; qc < 4; ++qc) {
        float4 v = *(const float4*)(hp + qc * 4);
        pk[qc * 2] = cvtpk(v.x, v.y); pk[qc * 2 + 1] = cvtpk(v.z, v.w);
      }
    } else {
      #pragma unroll
      for (int q = 0; q < 8; ++q) pk[q] = 0u;
    }
    const int sw = e << 2, rb = e << 7;
    #pragma unroll
    for (int q = 0; q < 4; ++q)
      *(uint2*)&Ah[rb + ((kc + 4 * q) ^ sw)] = make_uint2(pk[2 * q], pk[2 * q + 1]);
  }
  __syncthreads();

  const int eA = lane & 31, khalf = (lane >> 5) << 3, swA = eA << 2;
  const int baseA = eA << 7;
  f32x16 aR = {0.f}, aC = {0.f}, aV = {0.f};
  const unsigned short* b1 = WFe1r + ((wv << 12) | (lane << 3));
  const unsigned short* b2 = WFe1c + ((wv << 12) | (lane << 3));
  const unsigned short* b3 = WFv1 + ((wv << 12) | (lane << 3));
  #pragma unroll
  for (int s = 0; s < 8; ++s) {
    const int k1 = s * 16 + khalf;
    short4v a0 = *(const short4v*)&Ah[baseA + (k1 ^ swA)];
    short4v a1 = *(const short4v*)&Ah[baseA + ((k1 + 4) ^ swA)];
    short8v z = __builtin_shufflevector(a0, a1, 0, 1, 2, 3, 4, 5, 6, 7);
    aR = __builtin_amdgcn_mfma_f32_32x32x16_bf16(z, *(const short8v*)(b1 + (s << 9)), aR, 0, 0, 0);
    aC = __builtin_amdgcn_mfma_f32_32x32x16_bf16(z, *(const short8v*)(b2 + (s << 9)), aC, 0, 0, 0);
    aV = __builtin_amdgcn_mfma_f32_32x32x16_bf16(z, *(const short8v*)(b3 + (s << 9)), aV, 0, 0, 0);
  }
  const int colb = (wv << 5) | (lane & 31);
  const float be1j = be1[colb], bv1j = bv1[colb], wv2j = Wv2s[colb];
  const int ebase = (lane >> 5) << 2;
  #pragma unroll
  for (int r = 0; r < 16; ++r) {
    const int e = (r & 3) + 8 * (r >> 2) + ebase;
    const int n = n0 + e;
    if (n < N) {
      Hr[(size_t)n * 128 + colb] = aR[r] + be1j;
      Hc[(size_t)n * 128 + colb] = aC[r];
    }
    float v = RELU(aV[r] + bv1j) * wv2j;
    v += __shfl_xor(v, 1); v += __shfl_xor(v, 2); v += __shfl_xor(v, 4);
    v += __shfl_xor(v, 8); v += __shfl_xor(v, 16);
    if ((lane & 31) == 0) vpart[e][wv] = v;
  }
  __syncthreads();
  if (t < 32) {
    const int n = n0 + t;
    if (n < N)
      velfac[n] = vpart[t][0] + vpart[t][1] + vpart[t][2] + vpart[t][3] + bv2[0];
  }
}

// ---------------------------------------------------------------------------
// Edge kernel (MFMA) — R11 structure; int2 meta reads.
// ---------------------------------------------------------------------------
#define ET 32

__global__ __launch_bounds__(256) void edge_mfma_kernel(
    const int2* __restrict__ ecS,
    const float* __restrict__ Hr, const float* __restrict__ Hc,
    const float* __restrict__ coord, const float* __restrict__ vel,
    const float* __restrict__ We1,
    const unsigned short* __restrict__ WFe2,
    const unsigned short* __restrict__ WFc1,
    const float* __restrict__ be2, const float* __restrict__ bc1,
    const float* __restrict__ Wc2,
    unsigned short* __restrict__ efbuf, float* __restrict__ transbuf,
    int lo, int hi)
{
  const int t    = threadIdx.x;
  const int wv   = t >> 6;
  const int lane = t & 63;
  const int iblk = lo + blockIdx.x * ET;

  __shared__ __align__(16) unsigned short Z4[4 * 4096];
  __shared__ __align__(16) float Wc2s[256];
  __shared__ float ped[11][32];
  __shared__ int rs[32], cs[32];
  __shared__ float cmE[32][2];

  if (t < ET) {
    int i = iblk + t;
    int r = 0, c = 0;
    if (i < hi) { int2 rc = ecS[i]; r = rc.x; c = rc.y; }
    rs[t] = r; cs[t] = c;
    float crx = coord[2 * r], cry = coord[2 * r + 1];
    float ccx = coord[2 * c], ccy = coord[2 * c + 1];
    ped[0][t] = crx; ped[1][t] = cry; ped[2][t] = ccx; ped[3][t] = ccy;
    ped[4][t] = vel[2 * r]; ped[5][t] = vel[2 * r + 1];
    ped[6][t] = vel[2 * c]; ped[7][t] = vel[2 * c + 1];
    float dx = crx - ccx, dy = cry - ccy;
    ped[8][t] = dx; ped[9][t] = dy; ped[10][t] = dx * dx + dy * dy;
  }
  Wc2s[t] = Wc2[t];
  __syncthreads();

  // ---- Z-compute: 4 k's (kq) x 4 edges (eg) per thread ----
  {
    const int kq = t & 31;
    const int eg = t >> 5;
    const int kc = kq << 2;
    float4 w0 = *(const float4*)&We1[(size_t)(256 + 0) * 128 + kc];
    float4 w1 = *(const float4*)&We1[(size_t)(256 + 1) * 128 + kc];
    float4 w2 = *(const float4*)&We1[(size_t)(256 + 2) * 128 + kc];
    float4 w3 = *(const float4*)&We1[(size_t)(256 + 3) * 128 + kc];
    float4 w4 = *(const float4*)&We1[(size_t)(256 + 4) * 128 + kc];
    float4 w5 = *(const float4*)&We1[(size_t)(256 + 5) * 128 + kc];
    float4 w6 = *(const float4*)&We1[(size_t)(256 + 6) * 128 + kc];
    float4 w7 = *(const float4*)&We1[(size_t)(256 + 7) * 128 + kc];
    float4 w8 = *(const float4*)&We1[(size_t)(256 + 8) * 128 + kc];
    float wa0[4] = {w0.x, w0.y, w0.z, w0.w};
    float wa1[4] = {w1.x, w1.y, w1.z, w1.w};
    float wa2[4] = {w2.x, w2.y, w2.z, w2.w};
    float wa3[4] = {w3.x, w3.y, w3.z, w3.w};
    float wa4[4] = {w4.x, w4.y, w4.z, w4.w};
    float wa5[4] = {w5.x, w5.y, w5.z, w5.w};
    float wa6[4] = {w6.x, w6.y, w6.z, w6.w};
    float wa7[4] = {w7.x, w7.y, w7.z, w7.w};
    float wa8[4] = {w8.x, w8.y, w8.z, w8.w};
    #pragma unroll
    for (int ee = 0; ee < 4; ++ee) {
      const int e = (eg << 2) + ee;
      const int r = rs[e], c = cs[e];
      float4 h4 = *(const float4*)(Hr + (size_t)r * 128 + kc);
      float4 c4 = *(const float4*)(Hc + (size_t)c * 128 + kc);
      float hb[4] = {h4.x, h4.y, h4.z, h4.w};
      float cb[4] = {c4.x, c4.y, c4.z, c4.w};
      const float xr = ped[0][e], yr = ped[1][e], xc = ped[2][e], yc = ped[3][e];
      const float vrx = ped[4][e], vry = ped[5][e], vcx = ped[6][e], vcy = ped[7][e];
      const float d2 = ped[10][e];
      float z0[4], z1[4], z2[4], z3[4];
      #pragma unroll
      for (int m = 0; m < 4; ++m) {
        float base = fmaf(d2, wa4[m], hb[m] + cb[m]);
        float A = fmaf(xr, wa0[m], fmaf(xc, wa2[m], fmaf(vrx, wa5[m], vcx * wa7[m])));
        float B = fmaf(yr, wa1[m], fmaf(yc, wa3[m], fmaf(vry, wa6[m], vcy * wa8[m])));
        float bp = base + A, bm = base - A;
        z0[m] = RELU(bp + B);
        z1[m] = RELU(bm - B);
        z2[m] = RELU(bm + B);
        z3[m] = RELU(bp - B);
      }
      const int ia = (e << 7) + (kc ^ (e << 2));
      *(uint2*)&Z4[ia]         = make_uint2(cvtpk(z0[0], z0[1]), cvtpk(z0[2], z0[3]));
      *(uint2*)&Z4[4096 + ia]  = make_uint2(cvtpk(z1[0], z1[1]), cvtpk(z1[2], z1[3]));
      *(uint2*)&Z4[8192 + ia]  = make_uint2(cvtpk(z2[0], z2[1]), cvtpk(z2[2], z2[3]));
      *(uint2*)&Z4[12288 + ia] = make_uint2(cvtpk(z3[0], z3[1]), cvtpk(z3[2], z3[3]));
    }
  }
  __syncthreads();

  // ---- stage 1: 4 groups x 8 K-steps of 32x32x16 MFMA ----
  const int eA    = lane & 31;
  const int khalf = (lane >> 5) << 3;
  const int swA   = eA << 2;
  const int baseA = eA << 7;
  f32x16 ac0 = {0.f}, ac1 = {0.f}, ac2 = {0.f}, ac3 = {0.f};
  {
    const unsigned short* WFw = WFe2 + ((wv << 12) | (lane << 3));
    #pragma unroll
    for (int s = 0; s < 8; ++s) {
      short8v bw = *(const short8v*)(WFw + (s << 9));
      const int k1 = s * 16 + khalf;
      const int i0 = baseA + (k1 ^ swA);
      const int i1 = baseA + ((k1 + 4) ^ swA);
      short8v z0 = __builtin_shufflevector(*(const short4v*)&Z4[i0],
                                           *(const short4v*)&Z4[i1], 0,1,2,3,4,5,6,7);
      short8v z1 = __builtin_shufflevector(*(const short4v*)&Z4[4096 + i0],
                                           *(const short4v*)&Z4[4096 + i1], 0,1,2,3,4,5,6,7);
      short8v z2 = __builtin_shufflevector(*(const short4v*)&Z4[8192 + i0],
                                           *(const short4v*)&Z4[8192 + i1], 0,1,2,3,4,5,6,7);
      short8v z3 = __builtin_shufflevector(*(const short4v*)&Z4[12288 + i0],
                                           *(const short4v*)&Z4[12288 + i1], 0,1,2,3,4,5,6,7);
      ac0 = __builtin_amdgcn_mfma_f32_32x32x16_bf16(z0, bw, ac0, 0, 0, 0);
      ac1 = __builtin_amdgcn_mfma_f32_32x32x16_bf16(z1, bw, ac1, 0, 0, 0);
      ac2 = __builtin_amdgcn_mfma_f32_32x32x16_bf16(z2, bw, ac2, 0, 0, 0);
      ac3 = __builtin_amdgcn_mfma_f32_32x32x16_bf16(z3, bw, ac3, 0, 0, 0);
    }
  }
  __syncthreads();   // all Z4 reads done; region 0 -> ef, region 1 -> tv

  // ---- ef = 0.25 * sum_g relu(out_g + be2) -> LDS bf16 (cvtpk pairs) ----
  {
    const int j = (wv << 5) | (lane & 31);
    const float be2j = be2[j];
    const int ebase = (lane >> 5) << 2;
    #pragma unroll
    for (int q = 0; q < 8; ++q) {
      const int r0 = 2 * q;
      float v0 = RELU(ac0[r0] + be2j) + RELU(ac1[r0] + be2j) +
                 RELU(ac2[r0] + be2j) + RELU(ac3[r0] + be2j);
      float v1 = RELU(ac0[r0 + 1] + be2j) + RELU(ac1[r0 + 1] + be2j) +
                 RELU(ac2[r0 + 1] + be2j) + RELU(ac3[r0 + 1] + be2j);
      unsigned p = cvtpk(0.25f * v0, 0.25f * v1);
      const int e0_ = (r0 & 3) + 8 * (r0 >> 2) + ebase;
      const int e1_ = e0_ + 1;
      Z4[(e0_ << 7) + (j ^ (e0_ << 2))] = (unsigned short)p;
      Z4[(e1_ << 7) + (j ^ (e1_ << 2))] = (unsigned short)(p >> 16);
    }
  }
  __syncthreads();

  // ---- write efbuf (global, coalesced) ----
  {
    const int e  = t >> 3;
    const int kc = (t & 7) << 4;
    int i = iblk + e;
    if (i < hi) {
      const int sw = e << 2, rb = e << 7;
      uint2 c0 = *(const uint2*)&Z4[rb + ((kc + 0) ^ sw)];
      uint2 c1 = *(const uint2*)&Z4[rb + ((kc + 4) ^ sw)];
      uint2 c2 = *(const uint2*)&Z4[rb + ((kc + 8) ^ sw)];
      uint2 c3 = *(const uint2*)&Z4[rb + ((kc + 12) ^ sw)];
      *(uint4*)&efbuf[(size_t)(i - lo) * 128 + kc]     = make_uint4(c0.x, c0.y, c1.x, c1.y);
      *(uint4*)&efbuf[(size_t)(i - lo) * 128 + kc + 8] = make_uint4(c2.x, c2.y, c3.x, c3.y);
    }
  }

  // ---- stage 2: EF @ Wc1 ----
  f32x16 a2 = {0.f};
  {
    const unsigned short* WFc = WFc1 + ((wv << 12) | (lane << 3));
    #pragma unroll
    for (int s = 0; s < 8; ++s) {
      short8v bw = *(const short8v*)(WFc + (s << 9));
      const int k1 = s * 16 + khalf;
      const int i0 = baseA + (k1 ^ swA);
      const int i1 = baseA + ((k1 + 4) ^ swA);
      short8v af = __builtin_shufflevector(*(const short4v*)&Z4[i0],
                                           *(const short4v*)&Z4[i1], 0,1,2,3,4,5,6,7);
      a2 = __builtin_amdgcn_mfma_f32_32x32x16_bf16(af, bw, a2, 0, 0, 0);
    }
  }
  // ---- tv = relu(a2 + bc1) -> LDS region 1 (cvtpk pairs) ----
  {
    const int j = (wv << 5) | (lane & 31);
    const float bc1j = bc1[j];
    const int ebase = (lane >> 5) << 2;
    #pragma unroll
    for (int q = 0; q < 8; ++q) {
      const int r0 = 2 * q;
      unsigned p = cvtpk(RELU(a2[r0] + bc1j), RELU(a2[r0 + 1] + bc1j));
      const int e0_ = (r0 & 3) + 8 * (r0 >> 2) + ebase;
      const int e1_ = e0_ + 1;
      Z4[4096 + (e0_ << 7) + (j ^ (e0_ << 2))] = (unsigned short)p;
      Z4[4096 + (e1_ << 7) + (j ^ (e1_ << 2))] = (unsigned short)(p >> 16);
    }
  }
  __syncthreads();

  // ---- cm[e] = tv[e][:] @ Wc2 : 8 threads/edge, shfl reduce ----
  {
    const int e  = t >> 3;
    const int jc = (t & 7) << 4;
    const int sw = e << 2, rb = e << 7;
    uint2 d0 = *(const uint2*)&Z4[4096 + rb + ((jc + 0) ^ sw)];
    uint2 d1 = *(const uint2*)&Z4[4096 + rb + ((jc + 4) ^ sw)];
    uint2 d2 = *(const uint2*)&Z4[4096 + rb + ((jc + 8) ^ sw)];
    uint2 d3 = *(const uint2*)&Z4[4096 + rb + ((jc + 12) ^ sw)];
    unsigned uu[8] = {d0.x, d0.y, d1.x, d1.y, d2.x, d2.y, d3.x, d3.y};
    float cx = 0.f, cy = 0.f;
    #pragma unroll
    for (int q = 0; q < 8; ++q) {
      float t0 = bf2f((unsigned short)(uu[q] & 0xFFFFu));
      float t1 = bf2f((unsigned short)(uu[q] >> 16));
      float2 wA = *(const float2*)&Wc2s[2 * (jc + 2 * q)];
      float2 wB = *(const float2*)&Wc2s[2 * (jc + 2 * q + 1)];
      cx = fmaf(t0, wA.x, cx); cy = fmaf(t0, wA.y, cy);
      cx = fmaf(t1, wB.x, cx); cy = fmaf(t1, wB.y, cy);
    }
    cx += __shfl_xor(cx, 1); cy += __shfl_xor(cy, 1);
    cx += __shfl_xor(cx, 2); cy += __shfl_xor(cy, 2);
    cx += __shfl_xor(cx, 4); cy += __shfl_xor(cy, 4);
    if ((t & 7) == 0) { cmE[e][0] = cx; cmE[e][1] = cy; }
  }
  __syncthreads();
  if (t < ET) {
    int i = iblk + t;
    if (i < hi) {
      float tx = fminf(fmaxf(ped[8][t] * cmE[t][0], -100.0f), 100.0f);
      float ty = fminf(fmaxf(ped[9][t] * cmE[t][1], -100.0f), 100.0f);
      transbuf[(size_t)i * 2]     = tx;
      transbuf[(size_t)i * 2 + 1] = ty;
    }
  }
}

// ---------------------------------------------------------------------------
// Fused gather + node_final (nch==1). pk_add accumulation.
// ---------------------------------------------------------------------------
__global__ __launch_bounds__(256) void gather_final_mfma(
    const float* __restrict__ h, const float* __restrict__ coord,
    const float* __restrict__ vel,
    const unsigned short* __restrict__ WFn1a,
    const unsigned short* __restrict__ WFn1b,
    const unsigned short* __restrict__ WFn2,
    const float* __restrict__ bn1, const float* __restrict__ bn2,
    const int* __restrict__ ptr, const unsigned short* __restrict__ efbuf,
    const float* __restrict__ transbuf, const float* __restrict__ velfac,
    float* __restrict__ hout, float* __restrict__ cout, int N)
{
  const int t = threadIdx.x, wv = t >> 6, lane = t & 63;
  const int n0 = blockIdx.x * 32;
  __shared__ __align__(16) unsigned short Ah[4096];
  __shared__ __align__(16) unsigned short Ag[4096];
  __shared__ __align__(16) unsigned short Mid[4096];
  __shared__ float trs[32][2];

  {
    const int e = t >> 3, kc = (t & 7) << 4;
    const int n = n0 + e;
    const int sw = (e & 15) << 3, rb = e << 7;
    unsigned pk[8];
    f32x2 ac2[8];
    #pragma unroll
    for (int q = 0; q < 8; ++q) { f32x2 z = {0.f, 0.f}; ac2[q] = z; }
    float tx = 0.f, ty = 0.f;
    if (n < N) {
      const float* hp = h + (size_t)n * 128 + kc;
      #pragma unroll
      for (int qc = 0; qc < 4; ++qc) {
        float4 v = *(const float4*)(hp + qc * 4);
        pk[qc * 2] = cvtpk(v.x, v.y); pk[qc * 2 + 1] = cvtpk(v.z, v.w);
      }
      const int p0 = ptr[n], p1 = ptr[n + 1];
      for (int i = p0; i < p1; ++i) {
        uint4 a = *(const uint4*)&efbuf[(size_t)i * 128 + kc];
        uint4 b = *(const uint4*)&efbuf[(size_t)i * 128 + kc + 8];
        unsigned uu[8] = {a.x, a.y, a.z, a.w, b.x, b.y, b.z, b.w};
        #pragma unroll
        for (int q = 0; q < 8; ++q) ac2[q] = pk_add(ac2[q], unpk(uu[q]));
      }
      for (int i = p0 + (t & 7); i < p1; i += 8) {
        tx += transbuf[(size_t)i * 2];
        ty += transbuf[(size_t)i * 2 + 1];
      }
    } else {
      #pragma unroll
      for (int q = 0; q < 8; ++q) pk[q] = 0u;
    }
    tx += __shfl_xor(tx, 1); ty += __shfl_xor(ty, 1);
    tx += __shfl_xor(tx, 2); ty += __shfl_xor(ty, 2);
    tx += __shfl_xor(tx, 4); ty += __shfl_xor(ty, 4);
    if ((t & 7) == 0) { trs[e][0] = tx; trs[e][1] = ty; }
    *(uint4*)&Ah[rb + (kc ^ sw)]       = make_uint4(pk[0], pk[1], pk[2], pk[3]);
    *(uint4*)&Ah[rb + ((kc + 8) ^ sw)] = make_uint4(pk[4], pk[5], pk[6], pk[7]);
    unsigned gk[8];
    #pragma unroll
    for (int q = 0; q < 8; ++q) gk[q] = cvtpk(ac2[q].x, ac2[q].y);
    *(uint4*)&Ag[rb + (kc ^ sw)]       = make_uint4(gk[0], gk[1], gk[2], gk[3]);
    *(uint4*)&Ag[rb + ((kc + 8) ^ sw)] = make_uint4(gk[4], gk[5], gk[6], gk[7]);
  }
  __syncthreads();

  const int eA = lane & 31, khalf = (lane >> 5) << 3, swA = (eA & 15) << 3;
  const int baseA = eA << 7;
  f32x16 m = {0.f};
  {
    const unsigned short* p1 = WFn1a + ((wv << 12) | (lane << 3));
    const unsigned short* p2 = WFn1b + ((wv << 12) | (lane << 3));
    #pragma unroll
    for (int s = 0; s < 8; ++s) {
      const int i0 = baseA + ((s * 16 + khalf) ^ swA);
      short8v zh = *(const short8v*)&Ah[i0];
      short8v zg = *(const short8v*)&Ag[i0];
      m = __builtin_amdgcn_mfma_f32_32x32x16_bf16(zh, *(const short8v*)(p1 + (s << 9)), m, 0, 0, 0);
      m = __builtin_amdgcn_mfma_f32_32x32x16_bf16(zg, *(const short8v*)(p2 + (s << 9)), m, 0, 0, 0);
    }
  }
  const int colb = (wv << 5) | (lane & 31);
  const float bn1j = bn1[colb];
  const int ebase = (lane >> 5) << 2;
  #pragma unroll
  for (int r = 0; r < 16; ++r) {
    const int e = (r & 3) + 8 * (r >> 2) + ebase;
    Mid[(e << 7) + (colb ^ ((e & 15) << 3))] = f2bf(RELU(m[r] + bn1j));
  }
  __syncthreads();

  f32x16 o = {0.f};
  {
    const unsigned short* p3 = WFn2 + ((wv << 12) | (lane << 3));
    #pragma unroll
    for (int s = 0; s < 8; ++s) {
      const int i0 = baseA + ((s * 16 + khalf) ^ swA);
      short8v zm = *(const short8v*)&Mid[i0];
      o = __builtin_amdgcn_mfma_f32_32x32x16_bf16(zm, *(const short8v*)(p3 + (s << 9)), o, 0, 0, 0);
    }
  }
  const float bn2j = bn2[colb];
  #pragma unroll
  for (int r = 0; r < 16; ++r) {
    const int e = (r & 3) + 8 * (r >> 2) + ebase;
    const int n = n0 + e;
    if (n < N)
      hout[(size_t)n * 128 + colb] = h[(size_t)n * 128 + colb] + o[r] + bn2j;
  }
  if (t < 32) {
    const int n = n0 + t;
    if (n < N) {
      float c = (float)(ptr[n + 1] - ptr[n]);
      float vf = velfac[n];
      float inv = 1.0f / fmaxf(c, 1.0f);
      cout[(size_t)n * 2]     = coord[(size_t)n * 2]     + trs[t][0] * inv + vf * vel[(size_t)n * 2];
      cout[(size_t)n * 2 + 1] = coord[(size_t)n * 2 + 1] + trs[t][1] * inv + vf * vel[(size_t)n * 2 + 1];
    }
  }
}

// ---------------------------------------------------------------------------
// Chunked fallback (nch>1): gather + node_final.
// ---------------------------------------------------------------------------
__global__ __launch_bounds__(256) void gather_kernel(
    const int* __restrict__ ptr, const unsigned short* __restrict__ efbuf,
    const float* __restrict__ transbuf,
    unsigned short* __restrict__ aggnb, float* __restrict__ agg,
    int N, int lo, int hi, int first)
{
  const int wv = threadIdx.x >> 6, lane = threadIdx.x & 63;
  const int n = blockIdx.x * 4 + wv;
  if (n >= N) return;
  const int p0 = ptr[n], p1 = ptr[n + 1];
  const int a = p0 > lo ? p0 : lo;
  const int b = p1 < hi ? p1 : hi;
  const int sub = lane >> 4, c8 = (lane & 15) << 3;
  f32x2 ac2[4];
  #pragma unroll
  for (int q = 0; q < 4; ++q) { f32x2 z = {0.f, 0.f}; ac2[q] = z; }
  for (int i = a + sub; i < b; i += 4) {
    uint4 v = *(const uint4*)&efbuf[(size_t)(i - lo) * 128 + c8];
    unsigned uu[4] = {v.x, v.y, v.z, v.w};
    #pragma unroll
    for (int q = 0; q < 4; ++q) ac2[q] = pk_add(ac2[q], unpk(uu[q]));
  }
  #pragma unroll
  for (int q = 0; q < 4; ++q) {
    ac2[q].x += __shfl_xor(ac2[q].x, 16);
    ac2[q].y += __shfl_xor(ac2[q].y, 16);
    ac2[q].x += __shfl_xor(ac2[q].x, 32);
    ac2[q].y += __shfl_xor(ac2[q].y, 32);
  }
  if (lane < 16) {
    if (!first) {
      uint4 old = *(const uint4*)&aggnb[(size_t)n * 128 + c8];
      unsigned uo[4] = {old.x, old.y, old.z, old.w};
      #pragma unroll
      for (int q = 0; q < 4; ++q) ac2[q] = pk_add(ac2[q], unpk(uo[q]));
    }
    unsigned pk[4];
    #pragma unroll
    for (int q = 0; q < 4; ++q) pk[q] = cvtpk(ac2[q].x, ac2[q].y);
    *(uint4*)&aggnb[(size_t)n * 128 + c8] = make_uint4(pk[0], pk[1], pk[2], pk[3]);
  }
  if (lane < 2) {
    float tacc = first ? 0.f : agg[(size_t)n * 2 + lane];
    for (int i = a; i < b; ++i) tacc += transbuf[(size_t)i * 2 + lane];
    agg[(size_t)n * 2 + lane] = tacc;
  }
}

__global__ __launch_bounds__(256) void node_final_mfma(
    const float* __restrict__ h, const float* __restrict__ coord,
    const float* __restrict__ vel,
    const unsigned short* __restrict__ WFn1a,
    const unsigned short* __restrict__ WFn1b,
    const unsigned short* __restrict__ WFn2,
    const float* __restrict__ bn1, const float* __restrict__ bn2,
    const float* __restrict__ agg, const int* __restrict__ ptr,
    const unsigned short* __restrict__ aggnb, const float* __restrict__ velfac,
    float* __restrict__ hout, float* __restrict__ cout, int N)
{
  const int t = threadIdx.x, wv = t >> 6, lane = t & 63;
  const int n0 = blockIdx.x * 32;
  __shared__ __align__(16) unsigned short Ah[4096];
  __shared__ __align__(16) unsigned short Ag[4096];
  __shared__ __align__(16) unsigned short Mid[4096];

  {
    const int e = t >> 3, kc = (t & 7) << 4;
    const int n = n0 + e;
    unsigned pk[8], gk[8];
    if (n < N) {
      const float* hp = h + (size_t)n * 128 + kc;
      #pragma unroll
      for (int qc = 0; qc < 4; ++qc) {
        float4 v = *(const float4*)(hp + qc * 4);
        pk[qc * 2] = cvtpk(v.x, v.y); pk[qc * 2 + 1] = cvtpk(v.z, v.w);
      }
      uint4 g0 = *(const uint4*)&aggnb[(size_t)n * 128 + kc];
      uint4 g1 = *(const uint4*)&aggnb[(size_t)n * 128 + kc + 8];
      gk[0] = g0.x; gk[1] = g0.y; gk[2] = g0.z; gk[3] = g0.w;
      gk[4] = g1.x; gk[5] = g1.y; gk[6] = g1.z; gk[7] = g1.w;
    } else {
      #pragma unroll
      for (int q = 0; q < 8; ++q) { pk[q] = 0u; gk[q] = 0u; }
    }
    const int sw = (e & 15) << 3, rb = e << 7;
    *(uint4*)&Ah[rb + (kc ^ sw)]       = make_uint4(pk[0], pk[1], pk[2], pk[3]);
    *(uint4*)&Ah[rb + ((kc + 8) ^ sw)] = make_uint4(pk[4], pk[5], pk[6], pk[7]);
    *(uint4*)&Ag[rb + (kc ^ sw)]       = make_uint4(gk[0], gk[1], gk[2], gk[3]);
    *(uint4*)&Ag[rb + ((kc + 8) ^ sw)] = make_uint4(gk[4], gk[5], gk[6], gk[7]);
  }
  __syncthreads();

  const int eA = lane & 31, khalf = (lane >> 5) << 3, swA = (eA & 15) << 3;
  const int baseA = eA << 7;
  f32x16 m = {0.f};
  {
    const unsigned short* p1 = WFn1a + ((wv << 12) | (lane << 3));
    const unsigned short* p2 = WFn1b + ((wv << 12) | (lane << 3));
    #pragma unroll
    for (int s = 0; s < 8; ++s) {
      const int i0 = baseA + ((s * 16 + khalf) ^ swA);
      short8v zh = *(const short8v*)&Ah[i0];
      short8v zg = *(const short8v*)&Ag[i0];
      m = __builtin_amdgcn_mfma_f32_32x32x16_bf16(zh, *(const short8v*)(p1 + (s << 9)), m, 0, 0, 0);
      m = __builtin_amdgcn_mfma_f32_32x32x16_bf16(zg, *(const short8v*)(p2 + (s << 9)), m, 0, 0, 0);
    }
  }
  const int colb = (wv << 5) | (lane & 31);
  const float bn1j = bn1[colb];
  const int ebase = (lane >> 5) << 2;
  #pragma unroll
  for (int r = 0; r < 16; ++r) {
    const int e = (r & 3) + 8 * (r >> 2) + ebase;
    Mid[(e << 7) + (colb ^ ((e & 15) << 3))] = f2bf(RELU(m[r] + bn1j));
  }
  __syncthreads();

  f32x16 o = {0.f};
  {
    const unsigned short* p3 = WFn2 + ((wv << 12) | (lane << 3));
    #pragma unroll
    for (int s = 0; s < 8; ++s) {
      const int i0 = baseA + ((s * 16 + khalf) ^ swA);
      short8v zm = *(const short8v*)&Mid[i0];
      o = __builtin_amdgcn_mfma_f32_32x32x16_bf16(zm, *(const short8v*)(p3 + (s << 9)), o, 0, 0, 0);
    }
  }
  const float bn2j = bn2[colb];
  #pragma unroll
  for (int r = 0; r < 16; ++r) {
    const int e = (r & 3) + 8 * (r >> 2) + ebase;
    const int n = n0 + e;
    if (n < N)
      hout[(size_t)n * 128 + colb] = h[(size_t)n * 128 + colb] + o[r] + bn2j;
  }
  if (t < 32) {
    const int n = n0 + t;
    if (n < N) {
      float c = (float)(ptr[n + 1] - ptr[n]);
      float vf = velfac[n];
      float inv = 1.0f / fmaxf(c, 1.0f);
      cout[(size_t)n * 2]     = coord[(size_t)n * 2]     + agg[(size_t)n * 2] * inv     + vf * vel[(size_t)n * 2];
      cout[(size_t)n * 2 + 1] = coord[(size_t)n * 2 + 1] + agg[(size_t)n * 2 + 1] * inv + vf * vel[(size_t)n * 2 + 1];
    }
  }
}

// ---------------------------------------------------------------------------
// Legacy fp32 fallback kernels (ws too small for efbuf).
// ---------------------------------------------------------------------------
__global__ __launch_bounds__(256) void edge_kernel_legacy(
    const int* __restrict__ row, const int* __restrict__ col,
    const float* __restrict__ Hr, const float* __restrict__ Hc,
    const float* __restrict__ coord, const float* __restrict__ vel,
    const float* __restrict__ We1, const float* __restrict__ We2,
    const float* __restrict__ be2, const float* __restrict__ Wc1,
    const float* __restrict__ bc1, const float* __restrict__ Wc2,
    float* __restrict__ agg, float* __restrict__ cnt, float* __restrict__ aggn,
    int E)
{
  const int t  = threadIdx.x;
  const int el = t & 31;
  const int jg = t >> 5;
  const int j0 = jg * 16;
  const int e0 = blockIdx.x * ET;

  __shared__ __align__(16) float Wch[32][128];
  __shared__ __align__(16) float Zbuf[4256];
  __shared__ __align__(16) float W9[9][128];
  __shared__ float ped[11][32];
  __shared__ int   rs[32], cs[32], vE[32];
  __shared__ float cmP[8][32][2];

#define Z4L(g, e_, k_) Zbuf[((g) * 32 + (e_)) * 33 + (k_)]
#define EFL(e_, k_)    Zbuf[(e_) * 133 + (k_)]

  if (t < ET) {
    int e = e0 + t;
    int r = 0, c = 0, v = 0;
    if (e < E) { r = row[e]; c = col[e]; v = 1; }
    rs[t] = r; cs[t] = c; vE[t] = v;
    float crx = coord[2 * r], cry = coord[2 * r + 1];
    float ccx = coord[2 * c], ccy = coord[2 * c + 1];
    ped[0][t] = crx; ped[1][t] = cry; ped[2][t] = ccx; ped[3][t] = ccy;
    ped[4][t] = vel[2 * r]; ped[5][t] = vel[2 * r + 1];
    ped[6][t] = vel[2 * c]; ped[7][t] = vel[2 * c + 1];
    float dx = crx - ccx, dy = cry - ccy;
    ped[8][t] = dx; ped[9][t] = dy; ped[10][t] = dx * dx + dy * dy;
  }
  for (int idx = t; idx < 9 * 128; idx += 256)
    W9[idx >> 7][idx & 127] = We1[(size_t)(256 + (idx >> 7)) * 128 + (idx & 127)];

  float outg[4][16];
  #pragma unroll
  for (int g = 0; g < 4; ++g)
    #pragma unroll
    for (int jj = 0; jj < 16; ++jj) outg[g][jj] = 0.0f;

  for (int kc = 0; kc < 4; ++kc) {
    const int kb = kc * 32;
    __syncthreads();
    #pragma unroll
    for (int s = 0; s < 4; ++s) {
      int idx4 = t + s * 256;
      int kl = idx4 >> 5, jc = (idx4 & 31) * 4;
      *(float4*)&Wch[kl][jc] = *(const float4*)&We2[(size_t)(kb + kl) * 128 + jc];
    }
    {
      const int kk = kb + (jg << 2);
      const int kl = jg << 2;
      const int r = rs[el], c = cs[el];
      float4 a4 = *(const float4*)(Hr + (size_t)r * 128 + kk);
      float4 b4 = *(const float4*)(Hc + (size_t)c * 128 + kk);
      float hr[4] = {a4.x, a4.y, a4.z, a4.w};
      float hcv[4] = {b4.x, b4.y, b4.z, b4.w};
      float4 q;
      q = *(const float4*)&W9[0][kk]; float w0[4] = {q.x, q.y, q.z, q.w};
      q = *(const float4*)&W9[1][kk]; float w1[4] = {q.x, q.y, q.z, q.w};
      q = *(const float4*)&W9[2][kk]; float w2[4] = {q.x, q.y, q.z, q.w};
      q = *(const float4*)&W9[3][kk]; float w3[4] = {q.x, q.y, q.z, q.w};
      q = *(const float4*)&W9[4][kk]; float w4[4] = {q.x, q.y, q.z, q.w};
      q = *(const float4*)&W9[5][kk]; float w5[4] = {q.x, q.y, q.z, q.w};
      q = *(const float4*)&W9[6][kk]; float w6[4] = {q.x, q.y, q.z, q.w};
      q = *(const float4*)&W9[7][kk]; float w7[4] = {q.x, q.y, q.z, q.w};
      q = *(const float4*)&W9[8][kk]; float w8[4] = {q.x, q.y, q.z, q.w};
      float xr = ped[0][el], yr = ped[1][el], xc = ped[2][el], yc = ped[3][el];
      float vrx = ped[4][el], vry = ped[5][el], vcx = ped[6][el], vcy = ped[7][el];
      float d2 = ped[10][el];
      #pragma unroll
      for (int i = 0; i < 4; ++i) {
        float base = hr[i] + hcv[i] + d2 * w4[i];
        float A = xr * w0[i] + xc * w2[i] + vrx * w5[i] + vcx * w7[i];
        float B = yr * w1[i] + yc * w3[i] + vry * w6[i] + vcy * w8[i];
        Z4L(0, el, kl + i) = RELU(base + A + B);
        Z4L(1, el, kl + i) = RELU(base - A - B);
        Z4L(2, el, kl + i) = RELU(base - A + B);
        Z4L(3, el, kl + i) = RELU(base + A - B);
      }
    }
    __syncthreads();
    #pragma unroll 2
    for (int k = 0; k < 32; ++k) {
      float4 wa = *(const float4*)&Wch[k][j0];
      float4 wb = *(const float4*)&Wch[k][j0 + 4];
      float4 wc4 = *(const float4*)&Wch[k][j0 + 8];
      float4 wd = *(const float4*)&Wch[k][j0 + 12];
      float w[16] = {wa.x, wa.y, wa.z, wa.w, wb.x, wb.y, wb.z, wb.w,
                     wc4.x, wc4.y, wc4.z, wc4.w, wd.x, wd.y, wd.z, wd.w};
      float z0 = Z4L(0, el, k), z1 = Z4L(1, el, k);
      float z2 = Z4L(2, el, k), z3 = Z4L(3, el, k);
      #pragma unroll
      for (int jj = 0; jj < 16; ++jj) {
        outg[0][jj] = fmaf(z0, w[jj], outg[0][jj]);
        outg[1][jj] = fmaf(z1, w[jj], outg[1][jj]);
        outg[2][jj] = fmaf(z2, w[jj], outg[2][jj]);
        outg[3][jj] = fmaf(z3, w[jj], outg[3][jj]);
      }
    }
  }

  __syncthreads();
  float4 q0 = *(const float4*)(be2 + j0);
  float4 q1 = *(const float4*)(be2 + j0 + 4);
  float4 q2 = *(const float4*)(be2 + j0 + 8);
  float4 q3 = *(const float4*)(be2 + j0 + 12);
  float beA[16] = {q0.x, q0.y, q0.z, q0.w, q1.x, q1.y, q1.z, q1.w,
                   q2.x, q2.y, q2.z, q2.w, q3.x, q3.y, q3.z, q3.w};
  float ef[16];
  #pragma unroll
  for (int jj = 0; jj < 16; ++jj) {
    float s = RELU(outg[0][jj] + beA[jj]) + RELU(outg[1][jj] + beA[jj]) +
              RELU(outg[2][jj] + beA[jj]) + RELU(outg[3][jj] + beA[jj]);
    ef[jj] = 0.25f * s;
  }
  #pragma unroll
  for (int jj = 0; jj < 16; ++jj) EFL(el, j0 + jj) = ef[jj];
  {
    const int r = rs[el];
    if (vE[el]) {
      #pragma unroll
      for (int jj = 0; jj < 16; ++jj)
        unsafeAtomicAdd(&aggn[(size_t)r * 128 + j0 + jj], ef[jj]);
    }
  }

  float acc2[16];
  #pragma unroll
  for (int jj = 0; jj < 16; ++jj) acc2[jj] = 0.0f;
  for (int kc = 0; kc < 4; ++kc) {
    const int kb = kc * 32;
    __syncthreads();
    #pragma unroll
    for (int s = 0; s < 4; ++s) {
      int idx4 = t + s * 256;
      int kl = idx4 >> 5, jc = (idx4 & 31) * 4;
      *(float4*)&Wch[kl][jc] = *(const float4*)&Wc1[(size_t)(kb + kl) * 128 + jc];
    }
    __syncthreads();
    #pragma unroll 4
    for (int k = 0; k < 32; ++k) {
      float4 wa = *(const float4*)&Wch[k][j0];
      float4 wb = *(const float4*)&Wch[k][j0 + 4];
      float4 wc4 = *(const float4*)&Wch[k][j0 + 8];
      float4 wd = *(const float4*)&Wch[k][j0 + 12];
      float w[16] = {wa.x, wa.y, wa.z, wa.w, wb.x, wb.y, wb.z, wb.w,
                     wc4.x, wc4.y, wc4.z, wc4.w, wd.x, wd.y, wd.z, wd.w};
      float efk = EFL(el, kb + k);
      #pragma unroll
      for (int jj = 0; jj < 16; ++jj) acc2[jj] = fmaf(efk, w[jj], acc2[jj]);
    }
  }

  float cm0 = 0.f, cm1 = 0.f;
  #pragma unroll
  for (int jj = 0; jj < 16; ++jj) {
    float tv = RELU(acc2[jj] + bc1[j0 + jj]);
    float2 wp = *(const float2*)(Wc2 + 2 * (j0 + jj));
    cm0 = fmaf(tv, wp.x, cm0);
    cm1 = fmaf(tv, wp.y, cm1);
  }
  cmP[jg][el][0] = cm0; cmP[jg][el][1] = cm1;
  __syncthreads();
  if (t < ET && vE[t]) {
    float c0 = 0.f, c1 = 0.f;
    #pragma unroll
    for (int g = 0; g < 8; ++g) { c0 += cmP[g][t][0]; c1 += cmP[g][t][1]; }
    float dx = ped[8][t], dy = ped[9][t];
    float tx = fminf(fmaxf(dx * c0, -100.0f), 100.0f);
    float ty = fminf(fmaxf(dy * c1, -100.0f), 100.0f);
    const int r = rs[t];
    unsafeAtomicAdd(&agg[(size_t)r * 2], tx);
    unsafeAtomicAdd(&agg[(size_t)r * 2 + 1], ty);
    unsafeAtomicAdd(&cnt[r], 1.0f);
  }
}

__global__ __launch_bounds__(128) void node_pre_legacy(
    const float* __restrict__ h, const float* __restrict__ We1,
    const float* __restrict__ be1,
    const float* __restrict__ Wv1, const float* __restrict__ bv1,
    const float* __restrict__ Wv2, const float* __restrict__ bv2,
    float* __restrict__ Hr, float* __restrict__ Hc, float* __restrict__ velfac)
{
  const int j = threadIdx.x;
  const int n0 = blockIdx.x * 8;
  __shared__ __align__(16) float hl[128][8];
  __shared__ float vp[8][128];

  #pragma unroll
  for (int s = 0; s < 8; ++s) hl[j][s] = h[(size_t)(n0 + s) * 128 + j];
  __syncthreads();

  float aR[8], aC[8], aV[8];
  #pragma unroll
  for (int n = 0; n < 8; ++n) { aR[n] = 0.f; aC[n] = 0.f; aV[n] = 0.f; }

  for (int k = 0; k < 128; ++k) {
    float wr = We1[(size_t)k * 128 + j];
    float wc = We1[(size_t)(128 + k) * 128 + j];
    float wv = Wv1[(size_t)k * 128 + j];
    float4 h0 = *(const float4*)&hl[k][0];
    float4 h1 = *(const float4*)&hl[k][4];
    float hv[8] = {h0.x, h0.y, h0.z, h0.w, h1.x, h1.y, h1.z, h1.w};
    #pragma unroll
    for (int n = 0; n < 8; ++n) {
      aR[n] = fmaf(hv[n], wr, aR[n]);
      aC[n] = fmaf(hv[n], wc, aC[n]);
      aV[n] = fmaf(hv[n], wv, aV[n]);
    }
  }
  float b1 = be1[j], bv = bv1[j], w2 = Wv2[j];
  #pragma unroll
  for (int n = 0; n < 8; ++n) {
    Hr[(size_t)(n0 + n) * 128 + j] = aR[n] + b1;
    Hc[(size_t)(n0 + n) * 128 + j] = aC[n];
    vp[n][j] = RELU(aV[n] + bv) * w2;
  }
  __syncthreads();
  if (j < 8) {
    float s = 0.f;
    for (int k = 0; k < 128; ++k) s += vp[j][k];
    velfac[n0 + j] = s + bv2[0];
  }
}

__global__ __launch_bounds__(128) void node_final_legacy(
    const float* __restrict__ h, const float* __restrict__ coord,
    const float* __restrict__ vel,
    const float* __restrict__ Wn1, const float* __restrict__ bn1,
    const float* __restrict__ Wn2, const float* __restrict__ bn2,
    const float* __restrict__ agg, const float* __restrict__ cntbuf,
    const float* __restrict__ aggn, const float* __restrict__ velfac,
    float* __restrict__ hout, float* __restrict__ cout)
{
  const int j = threadIdx.x;
  const int n0 = blockIdx.x * 4;
  __shared__ __align__(16) float xl[256][4];
  __shared__ __align__(16) float tl[128][4];

  #pragma unroll
  for (int s = 0; s < 8; ++s) {
    int idx = s * 128 + j;
    int n = idx >> 8, k = idx & 255;
    float v = (k < 128) ? h[(size_t)(n0 + n) * 128 + k]
                        : aggn[(size_t)(n0 + n) * 128 + (k - 128)];
    xl[k][n] = v;
  }
  __syncthreads();
  float acc[4] = {0.f, 0.f, 0.f, 0.f};
  for (int k = 0; k < 256; ++k) {
    float w = Wn1[(size_t)k * 128 + j];
    float4 xv = *(const float4*)&xl[k][0];
    acc[0] = fmaf(xv.x, w, acc[0]);
    acc[1] = fmaf(xv.y, w, acc[1]);
    acc[2] = fmaf(xv.z, w, acc[2]);
    acc[3] = fmaf(xv.w, w, acc[3]);
  }
  float b = bn1[j];
  #pragma unroll
  for (int n = 0; n < 4; ++n) tl[j][n] = RELU(acc[n] + b);
  __syncthreads();
  float a2[4] = {0.f, 0.f, 0.f, 0.f};
  for (int k = 0; k < 128; ++k) {
    float w = Wn2[(size_t)k * 128 + j];
    float4 tv = *(const float4*)&tl[k][0];
    a2[0] = fmaf(tv.x, w, a2[0]);
    a2[1] = fmaf(tv.y, w, a2[1]);
    a2[2] = fmaf(tv.z, w, a2[2]);
    a2[3] = fmaf(tv.w, w, a2[3]);
  }
  float b2 = bn2[j];
  #pragma unroll
  for (int n = 0; n < 4; ++n)
    hout[(size_t)(n0 + n) * 128 + j] = h[(size_t)(n0 + n) * 128 + j] + a2[n] + b2;
  if (j < 8) {
    int n = j >> 1, d = j & 1;
    int node = n0 + n;
    float cdel = agg[(size_t)node * 2 + d] / fmaxf(cntbuf[node], 1.0f);
    cout[(size_t)node * 2 + d] =
        coord[(size_t)node * 2 + d] + cdel + velfac[node] * vel[(size_t)node * 2 + d];
  }
}

// ---------------------------------------------------------------------------
extern "C" void kernel_launch(void* const* d_in, const int* in_sizes, int n_in,
                              void* d_out, int out_size, void* d_ws, size_t ws_size,
                              hipStream_t stream)
{
  const float* h     = (const float*)d_in[0];
  const float* coord = (const float*)d_in[1];
  const float* vel   = (const float*)d_in[2];
  const float* We1   = (const float*)d_in[3];
  const float* be1   = (const float*)d_in[4];
  const float* We2   = (const float*)d_in[5];
  const float* be2   = (const float*)d_in[6];
  const float* Wc1   = (const float*)d_in[7];
  const float* bc1   = (const float*)d_in[8];
  const float* Wc2   = (const float*)d_in[9];
  const float* Wn1   = (const float*)d_in[10];
  const float* bn1   = (const float*)d_in[11];
  const float* Wn2   = (const float*)d_in[12];
  const float* bn2   = (const float*)d_in[13];
  const float* Wv1   = (const float*)d_in[14];
  const float* bv1   = (const float*)d_in[15];
  const float* Wv2   = (const float*)d_in[16];
  const float* bv2   = (const float*)d_in[17];
  const int*   ei    = (const int*)d_in[18];

  const int N = in_sizes[0] / 128;
  const int E = in_sizes[18] / 2;
  const int* row = ei;
  const int* col = ei + E;

  char* base = (char*)d_ws;
  size_t off = 0;
  auto alloc = [&](size_t bytes) -> char* {
    char* p = base + off;
    off += (bytes + 255) & ~(size_t)255;
    return p;
  };
  float* Hr     = (float*)alloc((size_t)N * 128 * 4);
  float* Hc     = (float*)alloc((size_t)N * 128 * 4);
  float* velfac = (float*)alloc((size_t)N * 4);
  float* zblk   = (float*)alloc((size_t)132 * N * 4);  // deg|agg|cnt|aggn
  int*   deg    = (int*)zblk;
  float* agg    = zblk + N;
  float* cnt    = agg + (size_t)2 * N;
  float* aggn   = cnt + N;
  unsigned short* aggnb = (unsigned short*)aggn;
  int*   ptr    = (int*)alloc((size_t)(N + 1) * 4);
  int*   wptr   = (int*)alloc((size_t)N * 4);
  int2*  ecS    = (int2*)alloc((size_t)E * 8);
  float* trans  = (float*)alloc((size_t)E * 2 * 4);
  unsigned short* wfall = (unsigned short*)alloc((size_t)8 * 16384 * 2);
  int*   bsum   = (int*)alloc((size_t)1024 * 4);
  int*   boff   = (int*)alloc((size_t)1024 * 4);
  size_t fixed_end = off;
  unsigned short* efbuf = (unsigned short*)(base + fixed_end);

  unsigned short* WFe1r = wfall;
  unsigned short* WFe1c = wfall + 16384;
  unsigned short* WFv1  = wfall + 2 * 16384;
  unsigned short* WFe2  = wfall + 3 * 16384;
  unsigned short* WFc1  = wfall + 4 * 16384;
  unsigned short* WFn1a = wfall + 5 * 16384;
  unsigned short* WFn1b = wfall + 6 * 16384;
  unsigned short* WFn2  = wfall + 7 * 16384;

  const int nbS = (N + 1023) / 1024;
  int use_csr = 0, EC = 0, nch = 1;
  if (ws_size > fixed_end) {
    size_t ec_max = (ws_size - fixed_end) / 256;
    ec_max &= ~(size_t)31;
    if (ec_max >= 32768 && nbS <= 1024) {
      use_csr = 1;
      size_t e_pad = ((size_t)E + 31) & ~(size_t)31;
      EC = (int)((ec_max < e_pad) ? ec_max : e_pad);
      nch = (E + EC - 1) / EC;
    }
  }

  const int nblk32 = (N + 31) / 32;
  float* hout = (float*)d_out;
  float* cout = hout + (size_t)N * 128;

  if (use_csr) {
    const int degB = (E + 255) / 256;
    const int scatB = (E + 255) / 256;
    hipMemsetAsync(deg, 0, (size_t)N * 4, stream);
    hipLaunchKernelGGL(deg_wprep_kernel, dim3(degB + 512), dim3(256), 0, stream,
                       row, deg, E, degB, We1, Wv1, We2, Wc1, Wn1, Wn2, wfall);
    hipLaunchKernelGGL(scan_sum_kernel, dim3(nbS), dim3(1024), 0, stream,
                       deg, bsum, N);
    hipLaunchKernelGGL(scan_off_kernel, dim3(1), dim3(1024), 0, stream,
                       bsum, boff, nbS);
    hipLaunchKernelGGL(scan_write_kernel, dim3(nbS), dim3(1024), 0, stream,
                       deg, boff, ptr, wptr, N, E);
    hipLaunchKernelGGL(scatter_nodepre_kernel, dim3(scatB + nblk32), dim3(256), 0,
                       stream, row, col, wptr, ecS, E, scatB,
                       h, WFe1r, WFe1c, WFv1, be1, bv1, Wv2, bv2,
                       Hr, Hc, velfac, N);
    if (nch == 1) {
      hipLaunchKernelGGL(edge_mfma_kernel, dim3((E + ET - 1) / ET), dim3(256), 0,
                         stream, ecS, Hr, Hc, coord, vel, We1,
                         WFe2, WFc1, be2, bc1, Wc2, efbuf, trans, 0, E);
      hipLaunchKernelGGL(gather_final_mfma, dim3(nblk32), dim3(256), 0, stream,
                         h, coord, vel, WFn1a, WFn1b, WFn2, bn1, bn2,
                         ptr, efbuf, trans, velfac, hout, cout, N);
    } else {
      for (int c = 0; c < nch; ++c) {
        int lo = c * EC;
        int hi = (lo + EC < E) ? lo + EC : E;
        int nb = (hi - lo + ET - 1) / ET;
        hipLaunchKernelGGL(edge_mfma_kernel, dim3(nb), dim3(256), 0, stream,
                           ecS, Hr, Hc, coord, vel, We1,
                           WFe2, WFc1, be2, bc1, Wc2, efbuf, trans, lo, hi);
        hipLaunchKernelGGL(gather_kernel, dim3((N + 3) / 4), dim3(256), 0, stream,
                           ptr, efbuf, trans, aggnb, agg, N, lo, hi, (c == 0) ? 1 : 0);
      }
      hipLaunchKernelGGL(node_final_mfma, dim3(nblk32), dim3(256), 0, stream,
                         h, coord, vel, WFn1a, WFn1b, WFn2, bn1, bn2,
                         agg, ptr, aggnb, velfac, hout, cout, N);
    }
  } else {
    hipMemsetAsync(zblk, 0, (size_t)132 * N * 4, stream);
    hipLaunchKernelGGL(node_pre_legacy, dim3(N / 8), dim3(128), 0, stream,
                       h, We1, be1, Wv1, bv1, Wv2, bv2, Hr, Hc, velfac);
    hipLaunchKernelGGL(edge_kernel_legacy, dim3((E + ET - 1) / ET), dim3(256), 0,
                       stream, row, col, Hr, Hc, coord, vel, We1, We2, be2,
                       Wc1, bc1, Wc2, agg, cnt, aggn, E);
    hipLaunchKernelGGL(node_final_legacy, dim3(N / 4), dim3(128), 0, stream,
                       h, coord, vel, Wn1, bn1, Wn2, bn2, agg, cnt,
                       aggn, velfac, hout, cout);
  }
}

// Round 13
// 528.398 us; speedup vs baseline: 1.2825x; 1.0525x over previous
//
#include <hip/hip_runtime.h>

#define RELU(x) fmaxf((x), 0.0f)

typedef __attribute__((ext_vector_type(2))) float f32x2;
typedef __attribute__((ext_vector_type(4))) short short4v;
typedef __attribute__((ext_vector_type(8))) short short8v;
typedef __attribute__((ext_vector_type(16))) float f32x16;

__device__ __forceinline__ float bf2f(unsigned short u) {
  unsigned v = ((unsigned)u) << 16;
  float f; __builtin_memcpy(&f, &v, 4); return f;
}
__device__ __forceinline__ unsigned short f2bf(float f) {
  unsigned u; __builtin_memcpy(&u, &f, 4);
  unsigned r = (u + 0x7FFFu + ((u >> 16) & 1u)) >> 16;
  return (unsigned short)r;
}
// HW packed convert: dst = {lo: bf16(a), hi: bf16(b)} (RNE).
__device__ __forceinline__ unsigned cvtpk(float a, float b) {
  unsigned r;
  asm("v_cvt_pk_bf16_f32 %0, %1, %2" : "=v"(r) : "v"(a), "v"(b));
  return r;
}
// packed f32 add: one instruction, two adds.
__device__ __forceinline__ f32x2 pk_add(f32x2 a, f32x2 b) {
  f32x2 d;
  asm("v_pk_add_f32 %0, %1, %2" : "=v"(d) : "v"(a), "v"(b));
  return d;
}
// unpack uint (2 bf16) -> f32 pair: lo = u<<16, hi = u & 0xFFFF0000.
__device__ __forceinline__ f32x2 unpk(unsigned u) {
  unsigned lo = u << 16, hi = u & 0xFFFF0000u;
  float fx, fy;
  __builtin_memcpy(&fx, &lo, 4);
  __builtin_memcpy(&fy, &hi, 4);
  f32x2 r = {fx, fy};
  return r;
}

// ---------------------------------------------------------------------------
// Fused: deg histogram (grid-stride, int4 loads) + wprep8.
// ---------------------------------------------------------------------------
#define DEGB 512

__global__ __launch_bounds__(256) void deg_wprep_kernel(
    const int* __restrict__ row, int* __restrict__ deg, int E, int E4,
    const float* __restrict__ We1, const float* __restrict__ Wv1,
    const float* __restrict__ We2, const float* __restrict__ Wc1,
    const float* __restrict__ Wn1, const float* __restrict__ Wn2,
    unsigned short* __restrict__ WF)
{
  if ((int)blockIdx.x < DEGB) {
    const int gs = DEGB * 256;
    const int base = blockIdx.x * 256 + threadIdx.x;
    const int4* row4 = (const int4*)row;
    for (int i = base; i < E4; i += gs) {
      int4 r = row4[i];
      atomicAdd(&deg[r.x], 1); atomicAdd(&deg[r.y], 1);
      atomicAdd(&deg[r.z], 1); atomicAdd(&deg[r.w], 1);
    }
    for (int i = (E4 << 2) + base; i < E; i += gs) atomicAdd(&deg[row[i]], 1);
    return;
  }
  const int bid = blockIdx.x - DEGB;
  const int g = bid >> 6;
  const int idx = (bid & 63) * 256 + threadIdx.x;
  const float* W;
  switch (g) {
    case 0: W = We1; break;
    case 1: W = We1 + 16384; break;
    case 2: W = Wv1; break;
    case 3: W = We2; break;
    case 4: W = Wc1; break;
    case 5: W = Wn1; break;
    case 6: W = Wn1 + 16384; break;
    default: W = Wn2; break;
  }
  int j = idx & 7, l = (idx >> 3) & 63, s = (idx >> 9) & 7, n = idx >> 12;
  int k = s * 16 + ((l >> 5) << 3) + j;
  int c = n * 32 + (l & 31);
  WF[g * 16384 + idx] = f2bf(W[k * 128 + c]);
}

// ---------------------------------------------------------------------------
// Parallel scan: 3 small kernels (partial sums -> block offsets -> write).
// ---------------------------------------------------------------------------
__global__ __launch_bounds__(1024) void scan_sum_kernel(
    const int* __restrict__ deg, int* __restrict__ bsum, int N)
{
  __shared__ int s[1024];
  const int t = threadIdx.x;
  const int i = blockIdx.x * 1024 + t;
  s[t] = (i < N) ? deg[i] : 0;
  __syncthreads();
  for (int off = 512; off >= 1; off >>= 1) {
    if (t < off) s[t] += s[t + off];
    __syncthreads();
  }
  if (t == 0) bsum[blockIdx.x] = s[0];
}

__global__ __launch_bounds__(1024) void scan_off_kernel(
    const int* __restrict__ bsum, int* __restrict__ boff, int nb)
{
  __shared__ int s[2][1024];
  const int t = threadIdx.x;
  s[0][t] = (t < nb) ? bsum[t] : 0;
  __syncthreads();
  int src = 0;
  for (int off = 1; off < 1024; off <<= 1) {
    int v = s[src][t];
    if (t >= off) v += s[src][t - off];
    s[src ^ 1][t] = v;
    __syncthreads();
    src ^= 1;
  }
  if (t < nb) boff[t] = t ? s[src][t - 1] : 0;
}

__global__ __launch_bounds__(1024) void scan_write_kernel(
    const int* __restrict__ deg, const int* __restrict__ boff,
    int* __restrict__ ptr, int* __restrict__ wptr, int N, int E)
{
  __shared__ int s[2][1024];
  const int t = threadIdx.x;
  const int i = blockIdx.x * 1024 + t;
  s[0][t] = (i < N) ? deg[i] : 0;
  __syncthreads();
  int src = 0;
  for (int off = 1; off < 1024; off <<= 1) {
    int v = s[src][t];
    if (t >= off) v += s[src][t - off];
    s[src ^ 1][t] = v;
    __syncthreads();
    src ^= 1;
  }
  if (i < N) {
    int ex = boff[blockIdx.x] + (t ? s[src][t - 1] : 0);
    ptr[i] = ex;
    wptr[i] = ex;
  }
  if (blockIdx.x == 0 && t == 0) ptr[N] = E;
}

// ---------------------------------------------------------------------------
// Fused: scatter (grid-stride int4, writes SORTED int2 pairs) + node_pre MFMA.
// ---------------------------------------------------------------------------
#define SCATB 512

__global__ __launch_bounds__(256) void scatter_nodepre_kernel(
    const int* __restrict__ row, const int* __restrict__ col,
    int* __restrict__ wptr, int2* __restrict__ ecS, int E, int E4,
    const float* __restrict__ h,
    const unsigned short* __restrict__ WFe1r,
    const unsigned short* __restrict__ WFe1c,
    const unsigned short* __restrict__ WFv1,
    const float* __restrict__ be1, const float* __restrict__ bv1,
    const float* __restrict__ Wv2, const float* __restrict__ bv2,
    float* __restrict__ Hr, float* __restrict__ Hc, float* __restrict__ velfac,
    int N)
{
  __shared__ __align__(16) unsigned short Ah[4096];
  __shared__ float Wv2s[128];
  __shared__ float vpart[32][4];

  if ((int)blockIdx.x < SCATB) {
    const int gs = SCATB * 256;
    const int base = blockIdx.x * 256 + threadIdx.x;
    const int4* row4 = (const int4*)row;
    const int4* col4 = (const int4*)col;
    for (int i = base; i < E4; i += gs) {
      int4 r = row4[i];
      int4 c = col4[i];
      int p0 = atomicAdd(&wptr[r.x], 1); ecS[p0] = make_int2(r.x, c.x);
      int p1 = atomicAdd(&wptr[r.y], 1); ecS[p1] = make_int2(r.y, c.y);
      int p2 = atomicAdd(&wptr[r.z], 1); ecS[p2] = make_int2(r.z, c.z);
      int p3 = atomicAdd(&wptr[r.w], 1); ecS[p3] = make_int2(r.w, c.w);
    }
    for (int i = (E4 << 2) + base; i < E; i += gs) {
      int r = row[i];
      int p = atomicAdd(&wptr[r], 1);
      ecS[p] = make_int2(r, col[i]);
    }
    return;
  }
  const int t = threadIdx.x, wv = t >> 6, lane = t & 63;
  const int n0 = (blockIdx.x - SCATB) * 32;

  if (t < 128) Wv2s[t] = Wv2[t];
  {
    const int e = t >> 3, kc = (t & 7) << 4;
    const int n = n0 + e;
    unsigned pk[8];
    if (n < N) {
      const float* hp = h + (size_t)n * 128 + kc;
      #pragma unroll
      for (int qc = 0; qc < 4; ++qc) {
        float4 v = *(const float4*)(hp + qc * 4);
        pk[qc * 2] = cvtpk(v.x, v.y); pk[qc * 2 + 1] = cvtpk(v.z, v.w);
      }
    } else {
      #pragma unroll
      for (int q = 0; q < 8; ++q) pk[q] = 0u;
    }
    const int sw = e << 2, rb = e << 7;
    #pragma unroll
    for (int q = 0; q < 4; ++q)
      *(uint2*)&Ah[rb + ((kc + 4 * q) ^ sw)] = make_uint2(pk[2 * q], pk[2 * q + 1]);
  }
  __syncthreads();

  const int eA = lane & 31, khalf = (lane >> 5) << 3, swA = eA << 2;
  const int baseA = eA << 7;
  f32x16 aR = {0.f}, aC = {0.f}, aV = {0.f};
  const unsigned short* b1 = WFe1r + ((wv << 12) | (lane << 3));
  const unsigned short* b2 = WFe1c + ((wv << 12) | (lane << 3));
  const unsigned short* b3 = WFv1 + ((wv << 12) | (lane << 3));
  #pragma unroll
  for (int s = 0; s < 8; ++s) {
    const int k1 = s * 16 + khalf;
    short4v a0 = *(const short4v*)&Ah[baseA + (k1 ^ swA)];
    short4v a1 = *(const short4v*)&Ah[baseA + ((k1 + 4) ^ swA)];
    short8v z = __builtin_shufflevector(a0, a1, 0, 1, 2, 3, 4, 5, 6, 7);
    aR = __builtin_amdgcn_mfma_f32_32x32x16_bf16(z, *(const short8v*)(b1 + (s << 9)), aR, 0, 0, 0);
    aC = __builtin_amdgcn_mfma_f32_32x32x16_bf16(z, *(const short8v*)(b2 + (s << 9)), aC, 0, 0, 0);
    aV = __builtin_amdgcn_mfma_f32_32x32x16_bf16(z, *(const short8v*)(b3 + (s << 9)), aV, 0, 0, 0);
  }
  const int colb = (wv << 5) | (lane & 31);
  const float be1j = be1[colb], bv1j = bv1[colb], wv2j = Wv2s[colb];
  const int ebase = (lane >> 5) << 2;
  #pragma unroll
  for (int r = 0; r < 16; ++r) {
    const int e = (r & 3) + 8 * (r >> 2) + ebase;
    const int n = n0 + e;
    if (n < N) {
      Hr[(size_t)n * 128 + colb] = aR[r] + be1j;
      Hc[(size_t)n * 128 + colb] = aC[r];
    }
    float v = RELU(aV[r] + bv1j) * wv2j;
    v += __shfl_xor(v, 1); v += __shfl_xor(v, 2); v += __shfl_xor(v, 4);
    v += __shfl_xor(v, 8); v += __shfl_xor(v, 16);
    if ((lane & 31) == 0) vpart[e][wv] = v;
  }
  __syncthreads();
  if (t < 32) {
    const int n = n0 + t;
    if (n < N)
      velfac[n] = vpart[t][0] + vpart[t][1] + vpart[t][2] + vpart[t][3] + bv2[0];
  }
}

// ---------------------------------------------------------------------------
// Edge kernel (MFMA) — R11/R12 structure verbatim; int2 meta reads.
// ---------------------------------------------------------------------------
#define ET 32

__global__ __launch_bounds__(256) void edge_mfma_kernel(
    const int2* __restrict__ ecS,
    const float* __restrict__ Hr, const float* __restrict__ Hc,
    const float* __restrict__ coord, const float* __restrict__ vel,
    const float* __restrict__ We1,
    const unsigned short* __restrict__ WFe2,
    const unsigned short* __restrict__ WFc1,
    const float* __restrict__ be2, const float* __restrict__ bc1,
    const float* __restrict__ Wc2,
    unsigned short* __restrict__ efbuf, float* __restrict__ transbuf,
    int lo, int hi)
{
  const int t    = threadIdx.x;
  const int wv   = t >> 6;
  const int lane = t & 63;
  const int iblk = lo + blockIdx.x * ET;

  __shared__ __align__(16) unsigned short Z4[4 * 4096];
  __shared__ __align__(16) float Wc2s[256];
  __shared__ float ped[11][32];
  __shared__ int rs[32], cs[32];
  __shared__ float cmE[32][2];

  if (t < ET) {
    int i = iblk + t;
    int r = 0, c = 0;
    if (i < hi) { int2 rc = ecS[i]; r = rc.x; c = rc.y; }
    rs[t] = r; cs[t] = c;
    float crx = coord[2 * r], cry = coord[2 * r + 1];
    float ccx = coord[2 * c], ccy = coord[2 * c + 1];
    ped[0][t] = crx; ped[1][t] = cry; ped[2][t] = ccx; ped[3][t] = ccy;
    ped[4][t] = vel[2 * r]; ped[5][t] = vel[2 * r + 1];
    ped[6][t] = vel[2 * c]; ped[7][t] = vel[2 * c + 1];
    float dx = crx - ccx, dy = cry - ccy;
    ped[8][t] = dx; ped[9][t] = dy; ped[10][t] = dx * dx + dy * dy;
  }
  Wc2s[t] = Wc2[t];
  __syncthreads();

  // ---- Z-compute: 4 k's (kq) x 4 edges (eg) per thread ----
  {
    const int kq = t & 31;
    const int eg = t >> 5;
    const int kc = kq << 2;
    float4 w0 = *(const float4*)&We1[(size_t)(256 + 0) * 128 + kc];
    float4 w1 = *(const float4*)&We1[(size_t)(256 + 1) * 128 + kc];
    float4 w2 = *(const float4*)&We1[(size_t)(256 + 2) * 128 + kc];
    float4 w3 = *(const float4*)&We1[(size_t)(256 + 3) * 128 + kc];
    float4 w4 = *(const float4*)&We1[(size_t)(256 + 4) * 128 + kc];
    float4 w5 = *(const float4*)&We1[(size_t)(256 + 5) * 128 + kc];
    float4 w6 = *(const float4*)&We1[(size_t)(256 + 6) * 128 + kc];
    float4 w7 = *(const float4*)&We1[(size_t)(256 + 7) * 128 + kc];
    float4 w8 = *(const float4*)&We1[(size_t)(256 + 8) * 128 + kc];
    float wa0[4] = {w0.x, w0.y, w0.z, w0.w};
    float wa1[4] = {w1.x, w1.y, w1.z, w1.w};
    float wa2[4] = {w2.x, w2.y, w2.z, w2.w};
    float wa3[4] = {w3.x, w3.y, w3.z, w3.w};
    float wa4[4] = {w4.x, w4.y, w4.z, w4.w};
    float wa5[4] = {w5.x, w5.y, w5.z, w5.w};
    float wa6[4] = {w6.x, w6.y, w6.z, w6.w};
    float wa7[4] = {w7.x, w7.y, w7.z, w7.w};
    float wa8[4] = {w8.x, w8.y, w8.z, w8.w};
    #pragma unroll
    for (int ee = 0; ee < 4; ++ee) {
      const int e = (eg << 2) + ee;
      const int r = rs[e], c = cs[e];
      float4 h4 = *(const float4*)(Hr + (size_t)r * 128 + kc);
      float4 c4 = *(const float4*)(Hc + (size_t)c * 128 + kc);
      float hb[4] = {h4.x, h4.y, h4.z, h4.w};
      float cb[4] = {c4.x, c4.y, c4.z, c4.w};
      const float xr = ped[0][e], yr = ped[1][e], xc = ped[2][e], yc = ped[3][e];
      const float vrx = ped[4][e], vry = ped[5][e], vcx = ped[6][e], vcy = ped[7][e];
      const float d2 = ped[10][e];
      float z0[4], z1[4], z2[4], z3[4];
      #pragma unroll
      for (int m = 0; m < 4; ++m) {
        float base = fmaf(d2, wa4[m], hb[m] + cb[m]);
        float A = fmaf(xr, wa0[m], fmaf(xc, wa2[m], fmaf(vrx, wa5[m], vcx * wa7[m])));
        float B = fmaf(yr, wa1[m], fmaf(yc, wa3[m], fmaf(vry, wa6[m], vcy * wa8[m])));
        float bp = base + A, bm = base - A;
        z0[m] = RELU(bp + B);
        z1[m] = RELU(bm - B);
        z2[m] = RELU(bm + B);
        z3[m] = RELU(bp - B);
      }
      const int ia = (e << 7) + (kc ^ (e << 2));
      *(uint2*)&Z4[ia]         = make_uint2(cvtpk(z0[0], z0[1]), cvtpk(z0[2], z0[3]));
      *(uint2*)&Z4[4096 + ia]  = make_uint2(cvtpk(z1[0], z1[1]), cvtpk(z1[2], z1[3]));
      *(uint2*)&Z4[8192 + ia]  = make_uint2(cvtpk(z2[0], z2[1]), cvtpk(z2[2], z2[3]));
      *(uint2*)&Z4[12288 + ia] = make_uint2(cvtpk(z3[0], z3[1]), cvtpk(z3[2], z3[3]));
    }
  }
  __syncthreads();

  // ---- stage 1: 4 groups x 8 K-steps of 32x32x16 MFMA ----
  const int eA    = lane & 31;
  const int khalf = (lane >> 5) << 3;
  const int swA   = eA << 2;
  const int baseA = eA << 7;
  f32x16 ac0 = {0.f}, ac1 = {0.f}, ac2 = {0.f}, ac3 = {0.f};
  {
    const unsigned short* WFw = WFe2 + ((wv << 12) | (lane << 3));
    #pragma unroll
    for (int s = 0; s < 8; ++s) {
      short8v bw = *(const short8v*)(WFw + (s << 9));
      const int k1 = s * 16 + khalf;
      const int i0 = baseA + (k1 ^ swA);
      const int i1 = baseA + ((k1 + 4) ^ swA);
      short8v z0 = __builtin_shufflevector(*(const short4v*)&Z4[i0],
                                           *(const short4v*)&Z4[i1], 0,1,2,3,4,5,6,7);
      short8v z1 = __builtin_shufflevector(*(const short4v*)&Z4[4096 + i0],
                                           *(const short4v*)&Z4[4096 + i1], 0,1,2,3,4,5,6,7);
      short8v z2 = __builtin_shufflevector(*(const short4v*)&Z4[8192 + i0],
                                           *(const short4v*)&Z4[8192 + i1], 0,1,2,3,4,5,6,7);
      short8v z3 = __builtin_shufflevector(*(const short4v*)&Z4[12288 + i0],
                                           *(const short4v*)&Z4[12288 + i1], 0,1,2,3,4,5,6,7);
      ac0 = __builtin_amdgcn_mfma_f32_32x32x16_bf16(z0, bw, ac0, 0, 0, 0);
      ac1 = __builtin_amdgcn_mfma_f32_32x32x16_bf16(z1, bw, ac1, 0, 0, 0);
      ac2 = __builtin_amdgcn_mfma_f32_32x32x16_bf16(z2, bw, ac2, 0, 0, 0);
      ac3 = __builtin_amdgcn_mfma_f32_32x32x16_bf16(z3, bw, ac3, 0, 0, 0);
    }
  }
  __syncthreads();   // all Z4 reads done; region 0 -> ef, region 1 -> tv

  // ---- ef = 0.25 * sum_g relu(out_g + be2) -> LDS bf16 (cvtpk pairs) ----
  {
    const int j = (wv << 5) | (lane & 31);
    const float be2j = be2[j];
    const int ebase = (lane >> 5) << 2;
    #pragma unroll
    for (int q = 0; q < 8; ++q) {
      const int r0 = 2 * q;
      float v0 = RELU(ac0[r0] + be2j) + RELU(ac1[r0] + be2j) +
                 RELU(ac2[r0] + be2j) + RELU(ac3[r0] + be2j);
      float v1 = RELU(ac0[r0 + 1] + be2j) + RELU(ac1[r0 + 1] + be2j) +
                 RELU(ac2[r0 + 1] + be2j) + RELU(ac3[r0 + 1] + be2j);
      unsigned p = cvtpk(0.25f * v0, 0.25f * v1);
      const int e0_ = (r0 & 3) + 8 * (r0 >> 2) + ebase;
      const int e1_ = e0_ + 1;
      Z4[(e0_ << 7) + (j ^ (e0_ << 2))] = (unsigned short)p;
      Z4[(e1_ << 7) + (j ^ (e1_ << 2))] = (unsigned short)(p >> 16);
    }
  }
  __syncthreads();

  // ---- write efbuf (global, coalesced) ----
  {
    const int e  = t >> 3;
    const int kc = (t & 7) << 4;
    int i = iblk + e;
    if (i < hi) {
      const int sw = e << 2, rb = e << 7;
      uint2 c0 = *(const uint2*)&Z4[rb + ((kc + 0) ^ sw)];
      uint2 c1 = *(const uint2*)&Z4[rb + ((kc + 4) ^ sw)];
      uint2 c2 = *(const uint2*)&Z4[rb + ((kc + 8) ^ sw)];
      uint2 c3 = *(const uint2*)&Z4[rb + ((kc + 12) ^ sw)];
      *(uint4*)&efbuf[(size_t)(i - lo) * 128 + kc]     = make_uint4(c0.x, c0.y, c1.x, c1.y);
      *(uint4*)&efbuf[(size_t)(i - lo) * 128 + kc + 8] = make_uint4(c2.x, c2.y, c3.x, c3.y);
    }
  }

  // ---- stage 2: EF @ Wc1 ----
  f32x16 a2 = {0.f};
  {
    const unsigned short* WFc = WFc1 + ((wv << 12) | (lane << 3));
    #pragma unroll
    for (int s = 0; s < 8; ++s) {
      short8v bw = *(const short8v*)(WFc + (s << 9));
      const int k1 = s * 16 + khalf;
      const int i0 = baseA + (k1 ^ swA);
      const int i1 = baseA + ((k1 + 4) ^ swA);
      short8v af = __builtin_shufflevector(*(const short4v*)&Z4[i0],
                                           *(const short4v*)&Z4[i1], 0,1,2,3,4,5,6,7);
      a2 = __builtin_amdgcn_mfma_f32_32x32x16_bf16(af, bw, a2, 0, 0, 0);
    }
  }
  // ---- tv = relu(a2 + bc1) -> LDS region 1 (cvtpk pairs) ----
  {
    const int j = (wv << 5) | (lane & 31);
    const float bc1j = bc1[j];
    const int ebase = (lane >> 5) << 2;
    #pragma unroll
    for (int q = 0; q < 8; ++q) {
      const int r0 = 2 * q;
      unsigned p = cvtpk(RELU(a2[r0] + bc1j), RELU(a2[r0 + 1] + bc1j));
      const int e0_ = (r0 & 3) + 8 * (r0 >> 2) + ebase;
      const int e1_ = e0_ + 1;
      Z4[4096 + (e0_ << 7) + (j ^ (e0_ << 2))] = (unsigned short)p;
      Z4[4096 + (e1_ << 7) + (j ^ (e1_ << 2))] = (unsigned short)(p >> 16);
    }
  }
  __syncthreads();

  // ---- cm[e] = tv[e][:] @ Wc2 : 8 threads/edge, shfl reduce ----
  {
    const int e  = t >> 3;
    const int jc = (t & 7) << 4;
    const int sw = e << 2, rb = e << 7;
    uint2 d0 = *(const uint2*)&Z4[4096 + rb + ((jc + 0) ^ sw)];
    uint2 d1 = *(const uint2*)&Z4[4096 + rb + ((jc + 4) ^ sw)];
    uint2 d2 = *(const uint2*)&Z4[4096 + rb + ((jc + 8) ^ sw)];
    uint2 d3 = *(const uint2*)&Z4[4096 + rb + ((jc + 12) ^ sw)];
    unsigned uu[8] = {d0.x, d0.y, d1.x, d1.y, d2.x, d2.y, d3.x, d3.y};
    float cx = 0.f, cy = 0.f;
    #pragma unroll
    for (int q = 0; q < 8; ++q) {
      float t0 = bf2f((unsigned short)(uu[q] & 0xFFFFu));
      float t1 = bf2f((unsigned short)(uu[q] >> 16));
      float2 wA = *(const float2*)&Wc2s[2 * (jc + 2 * q)];
      float2 wB = *(const float2*)&Wc2s[2 * (jc + 2 * q + 1)];
      cx = fmaf(t0, wA.x, cx); cy = fmaf(t0, wA.y, cy);
      cx = fmaf(t1, wB.x, cx); cy = fmaf(t1, wB.y, cy);
    }
    cx += __shfl_xor(cx, 1); cy += __shfl_xor(cy, 1);
    cx += __shfl_xor(cx, 2); cy += __shfl_xor(cy, 2);
    cx += __shfl_xor(cx, 4); cy += __shfl_xor(cy, 4);
    if ((t & 7) == 0) { cmE[e][0] = cx; cmE[e][1] = cy; }
  }
  __syncthreads();
  if (t < ET) {
    int i = iblk + t;
    if (i < hi) {
      float tx = fminf(fmaxf(ped[8][t] * cmE[t][0], -100.0f), 100.0f);
      float ty = fminf(fmaxf(ped[9][t] * cmE[t][1], -100.0f), 100.0f);
      transbuf[(size_t)i * 2]     = tx;
      transbuf[(size_t)i * 2 + 1] = ty;
    }
  }
}

// ---------------------------------------------------------------------------
// Fused gather + node_final (nch==1). pk_add accumulation.
// ---------------------------------------------------------------------------
__global__ __launch_bounds__(256) void gather_final_mfma(
    const float* __restrict__ h, const float* __restrict__ coord,
    const float* __restrict__ vel,
    const unsigned short* __restrict__ WFn1a,
    const unsigned short* __restrict__ WFn1b,
    const unsigned short* __restrict__ WFn2,
    const float* __restrict__ bn1, const float* __restrict__ bn2,
    const int* __restrict__ ptr, const unsigned short* __restrict__ efbuf,
    const float* __restrict__ transbuf, const float* __restrict__ velfac,
    float* __restrict__ hout, float* __restrict__ cout, int N)
{
  const int t = threadIdx.x, wv = t >> 6, lane = t & 63;
  const int n0 = blockIdx.x * 32;
  __shared__ __align__(16) unsigned short Ah[4096];
  __shared__ __align__(16) unsigned short Ag[4096];
  __shared__ __align__(16) unsigned short Mid[4096];
  __shared__ float trs[32][2];

  {
    const int e = t >> 3, kc = (t & 7) << 4;
    const int n = n0 + e;
    const int sw = (e & 15) << 3, rb = e << 7;
    unsigned pk[8];
    f32x2 ac2[8];
    #pragma unroll
    for (int q = 0; q < 8; ++q) { f32x2 z = {0.f, 0.f}; ac2[q] = z; }
    float tx = 0.f, ty = 0.f;
    if (n < N) {
      const float* hp = h + (size_t)n * 128 + kc;
      #pragma unroll
      for (int qc = 0; qc < 4; ++qc) {
        float4 v = *(const float4*)(hp + qc * 4);
        pk[qc * 2] = cvtpk(v.x, v.y); pk[qc * 2 + 1] = cvtpk(v.z, v.w);
      }
      const int p0 = ptr[n], p1 = ptr[n + 1];
      for (int i = p0; i < p1; ++i) {
        uint4 a = *(const uint4*)&efbuf[(size_t)i * 128 + kc];
        uint4 b = *(const uint4*)&efbuf[(size_t)i * 128 + kc + 8];
        unsigned uu[8] = {a.x, a.y, a.z, a.w, b.x, b.y, b.z, b.w};
        #pragma unroll
        for (int q = 0; q < 8; ++q) ac2[q] = pk_add(ac2[q], unpk(uu[q]));
      }
      for (int i = p0 + (t & 7); i < p1; i += 8) {
        tx += transbuf[(size_t)i * 2];
        ty += transbuf[(size_t)i * 2 + 1];
      }
    } else {
      #pragma unroll
      for (int q = 0; q < 8; ++q) pk[q] = 0u;
    }
    tx += __shfl_xor(tx, 1); ty += __shfl_xor(ty, 1);
    tx += __shfl_xor(tx, 2); ty += __shfl_xor(ty, 2);
    tx += __shfl_xor(tx, 4); ty += __shfl_xor(ty, 4);
    if ((t & 7) == 0) { trs[e][0] = tx; trs[e][1] = ty; }
    *(uint4*)&Ah[rb + (kc ^ sw)]       = make_uint4(pk[0], pk[1], pk[2], pk[3]);
    *(uint4*)&Ah[rb + ((kc + 8) ^ sw)] = make_uint4(pk[4], pk[5], pk[6], pk[7]);
    unsigned gk[8];
    #pragma unroll
    for (int q = 0; q < 8; ++q) gk[q] = cvtpk(ac2[q].x, ac2[q].y);
    *(uint4*)&Ag[rb + (kc ^ sw)]       = make_uint4(gk[0], gk[1], gk[2], gk[3]);
    *(uint4*)&Ag[rb + ((kc + 8) ^ sw)] = make_uint4(gk[4], gk[5], gk[6], gk[7]);
  }
  __syncthreads();

  const int eA = lane & 31, khalf = (lane >> 5) << 3, swA = (eA & 15) << 3;
  const int baseA = eA << 7;
  f32x16 m = {0.f};
  {
    const unsigned short* p1 = WFn1a + ((wv << 12) | (lane << 3));
    const unsigned short* p2 = WFn1b + ((wv << 12) | (lane << 3));
    #pragma unroll
    for (int s = 0; s < 8; ++s) {
      const int i0 = baseA + ((s * 16 + khalf) ^ swA);
      short8v zh = *(const short8v*)&Ah[i0];
      short8v zg = *(const short8v*)&Ag[i0];
      m = __builtin_amdgcn_mfma_f32_32x32x16_bf16(zh, *(const short8v*)(p1 + (s << 9)), m, 0, 0, 0);
      m = __builtin_amdgcn_mfma_f32_32x32x16_bf16(zg, *(const short8v*)(p2 + (s << 9)), m, 0, 0, 0);
    }
  }
  const int colb = (wv << 5) | (lane & 31);
  const float bn1j = bn1[colb];
  const int ebase = (lane >> 5) << 2;
  #pragma unroll
  for (int r = 0; r < 16; ++r) {
    const int e = (r & 3) + 8 * (r >> 2) + ebase;
    Mid[(e << 7) + (colb ^ ((e & 15) << 3))] = f2bf(RELU(m[r] + bn1j));
  }
  __syncthreads();

  f32x16 o = {0.f};
  {
    const unsigned short* p3 = WFn2 + ((wv << 12) | (lane << 3));
    #pragma unroll
    for (int s = 0; s < 8; ++s) {
      const int i0 = baseA + ((s * 16 + khalf) ^ swA);
      short8v zm = *(const short8v*)&Mid[i0];
      o = __builtin_amdgcn_mfma_f32_32x32x16_bf16(zm, *(const short8v*)(p3 + (s << 9)), o, 0, 0, 0);
    }
  }
  const float bn2j = bn2[colb];
  #pragma unroll
  for (int r = 0; r < 16; ++r) {
    const int e = (r & 3) + 8 * (r >> 2) + ebase;
    const int n = n0 + e;
    if (n < N)
      hout[(size_t)n * 128 + colb] = h[(size_t)n * 128 + colb] + o[r] + bn2j;
  }
  if (t < 32) {
    const int n = n0 + t;
    if (n < N) {
      float c = (float)(ptr[n + 1] - ptr[n]);
      float vf = velfac[n];
      float inv = 1.0f / fmaxf(c, 1.0f);
      cout[(size_t)n * 2]     = coord[(size_t)n * 2]     + trs[t][0] * inv + vf * vel[(size_t)n * 2];
      cout[(size_t)n * 2 + 1] = coord[(size_t)n * 2 + 1] + trs[t][1] * inv + vf * vel[(size_t)n * 2 + 1];
    }
  }
}

// ---------------------------------------------------------------------------
// Chunked fallback (nch>1): gather + node_final.
// ---------------------------------------------------------------------------
__global__ __launch_bounds__(256) void gather_kernel(
    const int* __restrict__ ptr, const unsigned short* __restrict__ efbuf,
    const float* __restrict__ transbuf,
    unsigned short* __restrict__ aggnb, float* __restrict__ agg,
    int N, int lo, int hi, int first)
{
  const int wv = threadIdx.x >> 6, lane = threadIdx.x & 63;
  const int n = blockIdx.x * 4 + wv;
  if (n >= N) return;
  const int p0 = ptr[n], p1 = ptr[n + 1];
  const int a = p0 > lo ? p0 : lo;
  const int b = p1 < hi ? p1 : hi;
  const int sub = lane >> 4, c8 = (lane & 15) << 3;
  f32x2 ac2[4];
  #pragma unroll
  for (int q = 0; q < 4; ++q) { f32x2 z = {0.f, 0.f}; ac2[q] = z; }
  for (int i = a + sub; i < b; i += 4) {
    uint4 v = *(const uint4*)&efbuf[(size_t)(i - lo) * 128 + c8];
    unsigned uu[4] = {v.x, v.y, v.z, v.w};
    #pragma unroll
    for (int q = 0; q < 4; ++q) ac2[q] = pk_add(ac2[q], unpk(uu[q]));
  }
  #pragma unroll
  for (int q = 0; q < 4; ++q) {
    ac2[q].x += __shfl_xor(ac2[q].x, 16);
    ac2[q].y += __shfl_xor(ac2[q].y, 16);
    ac2[q].x += __shfl_xor(ac2[q].x, 32);
    ac2[q].y += __shfl_xor(ac2[q].y, 32);
  }
  if (lane < 16) {
    if (!first) {
      uint4 old = *(const uint4*)&aggnb[(size_t)n * 128 + c8];
      unsigned uo[4] = {old.x, old.y, old.z, old.w};
      #pragma unroll
      for (int q = 0; q < 4; ++q) ac2[q] = pk_add(ac2[q], unpk(uo[q]));
    }
    unsigned pk[4];
    #pragma unroll
    for (int q = 0; q < 4; ++q) pk[q] = cvtpk(ac2[q].x, ac2[q].y);
    *(uint4*)&aggnb[(size_t)n * 128 + c8] = make_uint4(pk[0], pk[1], pk[2], pk[3]);
  }
  if (lane < 2) {
    float tacc = first ? 0.f : agg[(size_t)n * 2 + lane];
    for (int i = a; i < b; ++i) tacc += transbuf[(size_t)i * 2 + lane];
    agg[(size_t)n * 2 + lane] = tacc;
  }
}

__global__ __launch_bounds__(256) void node_final_mfma(
    const float* __restrict__ h, const float* __restrict__ coord,
    const float* __restrict__ vel,
    const unsigned short* __restrict__ WFn1a,
    const unsigned short* __restrict__ WFn1b,
    const unsigned short* __restrict__ WFn2,
    const float* __restrict__ bn1, const float* __restrict__ bn2,
    const float* __restrict__ agg, const int* __restrict__ ptr,
    const unsigned short* __restrict__ aggnb, const float* __restrict__ velfac,
    float* __restrict__ hout, float* __restrict__ cout, int N)
{
  const int t = threadIdx.x, wv = t >> 6, lane = t & 63;
  const int n0 = blockIdx.x * 32;
  __shared__ __align__(16) unsigned short Ah[4096];
  __shared__ __align__(16) unsigned short Ag[4096];
  __shared__ __align__(16) unsigned short Mid[4096];

  {
    const int e = t >> 3, kc = (t & 7) << 4;
    const int n = n0 + e;
    unsigned pk[8], gk[8];
    if (n < N) {
      const float* hp = h + (size_t)n * 128 + kc;
      #pragma unroll
      for (int qc = 0; qc < 4; ++qc) {
        float4 v = *(const float4*)(hp + qc * 4);
        pk[qc * 2] = cvtpk(v.x, v.y); pk[qc * 2 + 1] = cvtpk(v.z, v.w);
      }
      uint4 g0 = *(const uint4*)&aggnb[(size_t)n * 128 + kc];
      uint4 g1 = *(const uint4*)&aggnb[(size_t)n * 128 + kc + 8];
      gk[0] = g0.x; gk[1] = g0.y; gk[2] = g0.z; gk[3] = g0.w;
      gk[4] = g1.x; gk[5] = g1.y; gk[6] = g1.z; gk[7] = g1.w;
    } else {
      #pragma unroll
      for (int q = 0; q < 8; ++q) { pk[q] = 0u; gk[q] = 0u; }
    }
    const int sw = (e & 15) << 3, rb = e << 7;
    *(uint4*)&Ah[rb + (kc ^ sw)]       = make_uint4(pk[0], pk[1], pk[2], pk[3]);
    *(uint4*)&Ah[rb + ((kc + 8) ^ sw)] = make_uint4(pk[4], pk[5], pk[6], pk[7]);
    *(uint4*)&Ag[rb + (kc ^ sw)]       = make_uint4(gk[0], gk[1], gk[2], gk[3]);
    *(uint4*)&Ag[rb + ((kc + 8) ^ sw)] = make_uint4(gk[4], gk[5], gk[6], gk[7]);
  }
  __syncthreads();

  const int eA = lane & 31, khalf = (lane >> 5) << 3, swA = (eA & 15) << 3;
  const int baseA = eA << 7;
  f32x16 m = {0.f};
  {
    const unsigned short* p1 = WFn1a + ((wv << 12) | (lane << 3));
    const unsigned short* p2 = WFn1b + ((wv << 12) | (lane << 3));
    #pragma unroll
    for (int s = 0; s < 8; ++s) {
      const int i0 = baseA + ((s * 16 + khalf) ^ swA);
      short8v zh = *(const short8v*)&Ah[i0];
      short8v zg = *(const short8v*)&Ag[i0];
      m = __builtin_amdgcn_mfma_f32_32x32x16_bf16(zh, *(const short8v*)(p1 + (s << 9)), m, 0, 0, 0);
      m = __builtin_amdgcn_mfma_f32_32x32x16_bf16(zg, *(const short8v*)(p2 + (s << 9)), m, 0, 0, 0);
    }
  }
  const int colb = (wv << 5) | (lane & 31);
  const float bn1j = bn1[colb];
  const int ebase = (lane >> 5) << 2;
  #pragma unroll
  for (int r = 0; r < 16; ++r) {
    const int e = (r & 3) + 8 * (r >> 2) + ebase;
    Mid[(e << 7) + (colb ^ ((e & 15) << 3))] = f2bf(RELU(m[r] + bn1j));
  }
  __syncthreads();

  f32x16 o = {0.f};
  {
    const unsigned short* p3 = WFn2 + ((wv << 12) | (lane << 3));
    #pragma unroll
    for (int s = 0; s < 8; ++s) {
      const int i0 = baseA + ((s * 16 + khalf) ^ swA);
      short8v zm = *(const short8v*)&Mid[i0];
      o = __builtin_amdgcn_mfma_f32_32x32x16_bf16(zm, *(const short8v*)(p3 + (s << 9)), o, 0, 0, 0);
    }
  }
  const float bn2j = bn2[colb];
  #pragma unroll
  for (int r = 0; r < 16; ++r) {
    const int e = (r & 3) + 8 * (r >> 2) + ebase;
    const int n = n0 + e;
    if (n < N)
      hout[(size_t)n * 128 + colb] = h[(size_t)n * 128 + colb] + o[r] + bn2j;
  }
  if (t < 32) {
    const int n = n0 + t;
    if (n < N) {
      float c = (float)(ptr[n + 1] - ptr[n]);
      float vf = velfac[n];
      float inv = 1.0f / fmaxf(c, 1.0f);
      cout[(size_t)n * 2]     = coord[(size_t)n * 2]     + agg[(size_t)n * 2] * inv     + vf * vel[(size_t)n * 2];
      cout[(size_t)n * 2 + 1] = coord[(size_t)n * 2 + 1] + agg[(size_t)n * 2 + 1] * inv + vf * vel[(size_t)n * 2 + 1];
    }
  }
}

// ---------------------------------------------------------------------------
// Legacy fp32 fallback kernels (ws too small for efbuf).
// ---------------------------------------------------------------------------
__global__ __launch_bounds__(256) void edge_kernel_legacy(
    const int* __restrict__ row, const int* __restrict__ col,
    const float* __restrict__ Hr, const float* __restrict__ Hc,
    const float* __restrict__ coord, const float* __restrict__ vel,
    const float* __restrict__ We1, const float* __restrict__ We2,
    const float* __restrict__ be2, const float* __restrict__ Wc1,
    const float* __restrict__ bc1, const float* __restrict__ Wc2,
    float* __restrict__ agg, float* __restrict__ cnt, float* __restrict__ aggn,
    int E)
{
  const int t  = threadIdx.x;
  const int el = t & 31;
  const int jg = t >> 5;
  const int j0 = jg * 16;
  const int e0 = blockIdx.x * ET;

  __shared__ __align__(16) float Wch[32][128];
  __shared__ __align__(16) float Zbuf[4256];
  __shared__ __align__(16) float W9[9][128];
  __shared__ float ped[11][32];
  __shared__ int   rs[32], cs[32], vE[32];
  __shared__ float cmP[8][32][2];

#define Z4L(g, e_, k_) Zbuf[((g) * 32 + (e_)) * 33 + (k_)]
#define EFL(e_, k_)    Zbuf[(e_) * 133 + (k_)]

  if (t < ET) {
    int e = e0 + t;
    int r = 0, c = 0, v = 0;
    if (e < E) { r = row[e]; c = col[e]; v = 1; }
    rs[t] = r; cs[t] = c; vE[t] = v;
    float crx = coord[2 * r], cry = coord[2 * r + 1];
    float ccx = coord[2 * c], ccy = coord[2 * c + 1];
    ped[0][t] = crx; ped[1][t] = cry; ped[2][t] = ccx; ped[3][t] = ccy;
    ped[4][t] = vel[2 * r]; ped[5][t] = vel[2 * r + 1];
    ped[6][t] = vel[2 * c]; ped[7][t] = vel[2 * c + 1];
    float dx = crx - ccx, dy = cry - ccy;
    ped[8][t] = dx; ped[9][t] = dy; ped[10][t] = dx * dx + dy * dy;
  }
  for (int idx = t; idx < 9 * 128; idx += 256)
    W9[idx >> 7][idx & 127] = We1[(size_t)(256 + (idx >> 7)) * 128 + (idx & 127)];

  float outg[4][16];
  #pragma unroll
  for (int g = 0; g < 4; ++g)
    #pragma unroll
    for (int jj = 0; jj < 16; ++jj) outg[g][jj] = 0.0f;

  for (int kc = 0; kc < 4; ++kc) {
    const int kb = kc * 32;
    __syncthreads();
    #pragma unroll
    for (int s = 0; s < 4; ++s) {
      int idx4 = t + s * 256;
      int kl = idx4 >> 5, jc = (idx4 & 31) * 4;
      *(float4*)&Wch[kl][jc] = *(const float4*)&We2[(size_t)(kb + kl) * 128 + jc];
    }
    {
      const int kk = kb + (jg << 2);
      const int kl = jg << 2;
      const int r = rs[el], c = cs[el];
      float4 a4 = *(const float4*)(Hr + (size_t)r * 128 + kk);
      float4 b4 = *(const float4*)(Hc + (size_t)c * 128 + kk);
      float hr[4] = {a4.x, a4.y, a4.z, a4.w};
      float hcv[4] = {b4.x, b4.y, b4.z, b4.w};
      float4 q;
      q = *(const float4*)&W9[0][kk]; float w0[4] = {q.x, q.y, q.z, q.w};
      q = *(const float4*)&W9[1][kk]; float w1[4] = {q.x, q.y, q.z, q.w};
      q = *(const float4*)&W9[2][kk]; float w2[4] = {q.x, q.y, q.z, q.w};
      q = *(const float4*)&W9[3][kk]; float w3[4] = {q.x, q.y, q.z, q.w};
      q = *(const float4*)&W9[4][kk]; float w4[4] = {q.x, q.y, q.z, q.w};
      q = *(const float4*)&W9[5][kk]; float w5[4] = {q.x, q.y, q.z, q.w};
      q = *(const float4*)&W9[6][kk]; float w6[4] = {q.x, q.y, q.z, q.w};
      q = *(const float4*)&W9[7][kk]; float w7[4] = {q.x, q.y, q.z, q.w};
      q = *(const float4*)&W9[8][kk]; float w8[4] = {q.x, q.y, q.z, q.w};
      float xr = ped[0][el], yr = ped[1][el], xc = ped[2][el], yc = ped[3][el];
      float vrx = ped[4][el], vry = ped[5][el], vcx = ped[6][el], vcy = ped[7][el];
      float d2 = ped[10][el];
      #pragma unroll
      for (int i = 0; i < 4; ++i) {
        float base = hr[i] + hcv[i] + d2 * w4[i];
        float A = xr * w0[i] + xc * w2[i] + vrx * w5[i] + vcx * w7[i];
        float B = yr * w1[i] + yc * w3[i] + vry * w6[i] + vcy * w8[i];
        Z4L(0, el, kl + i) = RELU(base + A + B);
        Z4L(1, el, kl + i) = RELU(base - A - B);
        Z4L(2, el, kl + i) = RELU(base - A + B);
        Z4L(3, el, kl + i) = RELU(base + A - B);
      }
    }
    __syncthreads();
    #pragma unroll 2
    for (int k = 0; k < 32; ++k) {
      float4 wa = *(const float4*)&Wch[k][j0];
      float4 wb = *(const float4*)&Wch[k][j0 + 4];
      float4 wc4 = *(const float4*)&Wch[k][j0 + 8];
      float4 wd = *(const float4*)&Wch[k][j0 + 12];
      float w[16] = {wa.x, wa.y, wa.z, wa.w, wb.x, wb.y, wb.z, wb.w,
                     wc4.x, wc4.y, wc4.z, wc4.w, wd.x, wd.y, wd.z, wd.w};
      float z0 = Z4L(0, el, k), z1 = Z4L(1, el, k);
      float z2 = Z4L(2, el, k), z3 = Z4L(3, el, k);
      #pragma unroll
      for (int jj = 0; jj < 16; ++jj) {
        outg[0][jj] = fmaf(z0, w[jj], outg[0][jj]);
        outg[1][jj] = fmaf(z1, w[jj], outg[1][jj]);
        outg[2][jj] = fmaf(z2, w[jj], outg[2][jj]);
        outg[3][jj] = fmaf(z3, w[jj], outg[3][jj]);
      }
    }
  }

  __syncthreads();
  float4 q0 = *(const float4*)(be2 + j0);
  float4 q1 = *(const float4*)(be2 + j0 + 4);
  float4 q2 = *(const float4*)(be2 + j0 + 8);
  float4 q3 = *(const float4*)(be2 + j0 + 12);
  float beA[16] = {q0.x, q0.y, q0.z, q0.w, q1.x, q1.y, q1.z, q1.w,
                   q2.x, q2.y, q2.z, q2.w, q3.x, q3.y, q3.z, q3.w};
  float ef[16];
  #pragma unroll
  for (int jj = 0; jj < 16; ++jj) {
    float s = RELU(outg[0][jj] + beA[jj]) + RELU(outg[1][jj] + beA[jj]) +
              RELU(outg[2][jj] + beA[jj]) + RELU(outg[3][jj] + beA[jj]);
    ef[jj] = 0.25f * s;
  }
  #pragma unroll
  for (int jj = 0; jj < 16; ++jj) EFL(el, j0 + jj) = ef[jj];
  {
    const int r = rs[el];
    if (vE[el]) {
      #pragma unroll
      for (int jj = 0; jj < 16; ++jj)
        unsafeAtomicAdd(&aggn[(size_t)r * 128 + j0 + jj], ef[jj]);
    }
  }

  float acc2[16];
  #pragma unroll
  for (int jj = 0; jj < 16; ++jj) acc2[jj] = 0.0f;
  for (int kc = 0; kc < 4; ++kc) {
    const int kb = kc * 32;
    __syncthreads();
    #pragma unroll
    for (int s = 0; s < 4; ++s) {
      int idx4 = t + s * 256;
      int kl = idx4 >> 5, jc = (idx4 & 31) * 4;
      *(float4*)&Wch[kl][jc] = *(const float4*)&Wc1[(size_t)(kb + kl) * 128 + jc];
    }
    __syncthreads();
    #pragma unroll 4
    for (int k = 0; k < 32; ++k) {
      float4 wa = *(const float4*)&Wch[k][j0];
      float4 wb = *(const float4*)&Wch[k][j0 + 4];
      float4 wc4 = *(const float4*)&Wch[k][j0 + 8];
      float4 wd = *(const float4*)&Wch[k][j0 + 12];
      float w[16] = {wa.x, wa.y, wa.z, wa.w, wb.x, wb.y, wb.z, wb.w,
                     wc4.x, wc4.y, wc4.z, wc4.w, wd.x, wd.y, wd.z, wd.w};
      float efk = EFL(el, kb + k);
      #pragma unroll
      for (int jj = 0; jj < 16; ++jj) acc2[jj] = fmaf(efk, w[jj], acc2[jj]);
    }
  }

  float cm0 = 0.f, cm1 = 0.f;
  #pragma unroll
  for (int jj = 0; jj < 16; ++jj) {
    float tv = RELU(acc2[jj] + bc1[j0 + jj]);
    float2 wp = *(const float2*)(Wc2 + 2 * (j0 + jj));
    cm0 = fmaf(tv, wp.x, cm0);
    cm1 = fmaf(tv, wp.y, cm1);
  }
  cmP[jg][el][0] = cm0; cmP[jg][el][1] = cm1;
  __syncthreads();
  if (t < ET && vE[t]) {
    float c0 = 0.f, c1 = 0.f;
    #pragma unroll
    for (int g = 0; g < 8; ++g) { c0 += cmP[g][t][0]; c1 += cmP[g][t][1]; }
    float dx = ped[8][t], dy = ped[9][t];
    float tx = fminf(fmaxf(dx * c0, -100.0f), 100.0f);
    float ty = fminf(fmaxf(dy * c1, -100.0f), 100.0f);
    const int r = rs[t];
    unsafeAtomicAdd(&agg[(size_t)r * 2], tx);
    unsafeAtomicAdd(&agg[(size_t)r * 2 + 1], ty);
    unsafeAtomicAdd(&cnt[r], 1.0f);
  }
}

__global__ __launch_bounds__(128) void node_pre_legacy(
    const float* __restrict__ h, const float* __restrict__ We1,
    const float* __restrict__ be1,
    const float* __restrict__ Wv1, const float* __restrict__ bv1,
    const float* __restrict__ Wv2, const float* __restrict__ bv2,
    float* __restrict__ Hr, float* __restrict__ Hc, float* __restrict__ velfac)
{
  const int j = threadIdx.x;
  const int n0 = blockIdx.x * 8;
  __shared__ __align__(16) float hl[128][8];
  __shared__ float vp[8][128];

  #pragma unroll
  for (int s = 0; s < 8; ++s) hl[j][s] = h[(size_t)(n0 + s) * 128 + j];
  __syncthreads();

  float aR[8], aC[8], aV[8];
  #pragma unroll
  for (int n = 0; n < 8; ++n) { aR[n] = 0.f; aC[n] = 0.f; aV[n] = 0.f; }

  for (int k = 0; k < 128; ++k) {
    float wr = We1[(size_t)k * 128 + j];
    float wc = We1[(size_t)(128 + k) * 128 + j];
    float wv = Wv1[(size_t)k * 128 + j];
    float4 h0 = *(const float4*)&hl[k][0];
    float4 h1 = *(const float4*)&hl[k][4];
    float hv[8] = {h0.x, h0.y, h0.z, h0.w, h1.x, h1.y, h1.z, h1.w};
    #pragma unroll
    for (int n = 0; n < 8; ++n) {
      aR[n] = fmaf(hv[n], wr, aR[n]);
      aC[n] = fmaf(hv[n], wc, aC[n]);
      aV[n] = fmaf(hv[n], wv, aV[n]);
    }
  }
  float b1 = be1[j], bv = bv1[j], w2 = Wv2[j];
  #pragma unroll
  for (int n = 0; n < 8; ++n) {
    Hr[(size_t)(n0 + n) * 128 + j] = aR[n] + b1;
    Hc[(size_t)(n0 + n) * 128 + j] = aC[n];
    vp[n][j] = RELU(aV[n] + bv) * w2;
  }
  __syncthreads();
  if (j < 8) {
    float s = 0.f;
    for (int k = 0; k < 128; ++k) s += vp[j][k];
    velfac[n0 + j] = s + bv2[0];
  }
}

__global__ __launch_bounds__(128) void node_final_legacy(
    const float* __restrict__ h, const float* __restrict__ coord,
    const float* __restrict__ vel,
    const float* __restrict__ Wn1, const float* __restrict__ bn1,
    const float* __restrict__ Wn2, const float* __restrict__ bn2,
    const float* __restrict__ agg, const float* __restrict__ cntbuf,
    const float* __restrict__ aggn, const float* __restrict__ velfac,
    float* __restrict__ hout, float* __restrict__ cout)
{
  const int j = threadIdx.x;
  const int n0 = blockIdx.x * 4;
  __shared__ __align__(16) float xl[256][4];
  __shared__ __align__(16) float tl[128][4];

  #pragma unroll
  for (int s = 0; s < 8; ++s) {
    int idx = s * 128 + j;
    int n = idx >> 8, k = idx & 255;
    float v = (k < 128) ? h[(size_t)(n0 + n) * 128 + k]
                        : aggn[(size_t)(n0 + n) * 128 + (k - 128)];
    xl[k][n] = v;
  }
  __syncthreads();
  float acc[4] = {0.f, 0.f, 0.f, 0.f};
  for (int k = 0; k < 256; ++k) {
    float w = Wn1[(size_t)k * 128 + j];
    float4 xv = *(const float4*)&xl[k][0];
    acc[0] = fmaf(xv.x, w, acc[0]);
    acc[1] = fmaf(xv.y, w, acc[1]);
    acc[2] = fmaf(xv.z, w, acc[2]);
    acc[3] = fmaf(xv.w, w, acc[3]);
  }
  float b = bn1[j];
  #pragma unroll
  for (int n = 0; n < 4; ++n) tl[j][n] = RELU(acc[n] + b);
  __syncthreads();
  float a2[4] = {0.f, 0.f, 0.f, 0.f};
  for (int k = 0; k < 128; ++k) {
    float w = Wn2[(size_t)k * 128 + j];
    float4 tv = *(const float4*)&tl[k][0];
    a2[0] = fmaf(tv.x, w, a2[0]);
    a2[1] = fmaf(tv.y, w, a2[1]);
    a2[2] = fmaf(tv.z, w, a2[2]);
    a2[3] = fmaf(tv.w, w, a2[3]);
  }
  float b2 = bn2[j];
  #pragma unroll
  for (int n = 0; n < 4; ++n)
    hout[(size_t)(n0 + n) * 128 + j] = h[(size_t)(n0 + n) * 128 + j] + a2[n] + b2;
  if (j < 8) {
    int n = j >> 1, d = j & 1;
    int node = n0 + n;
    float cdel = agg[(size_t)node * 2 + d] / fmaxf(cntbuf[node], 1.0f);
    cout[(size_t)node * 2 + d] =
        coord[(size_t)node * 2 + d] + cdel + velfac[node] * vel[(size_t)node * 2 + d];
  }
}

// ---------------------------------------------------------------------------
extern "C" void kernel_launch(void* const* d_in, const int* in_sizes, int n_in,
                              void* d_out, int out_size, void* d_ws, size_t ws_size,
                              hipStream_t stream)
{
  const float* h     = (const float*)d_in[0];
  const float* coord = (const float*)d_in[1];
  const float* vel   = (const float*)d_in[2];
  const float* We1   = (const float*)d_in[3];
  const float* be1   = (const float*)d_in[4];
  const float* We2   = (const float*)d_in[5];
  const float* be2   = (const float*)d_in[6];
  const float* Wc1   = (const float*)d_in[7];
  const float* bc1   = (const float*)d_in[8];
  const float* Wc2   = (const float*)d_in[9];
  const float* Wn1   = (const float*)d_in[10];
  const float* bn1   = (const float*)d_in[11];
  const float* Wn2   = (const float*)d_in[12];
  const float* bn2   = (const float*)d_in[13];
  const float* Wv1   = (const float*)d_in[14];
  const float* bv1   = (const float*)d_in[15];
  const float* Wv2   = (const float*)d_in[16];
  const float* bv2   = (const float*)d_in[17];
  const int*   ei    = (const int*)d_in[18];

  const int N = in_sizes[0] / 128;
  const int E = in_sizes[18] / 2;
  const int* row = ei;
  const int* col = ei + E;
  // int4-vectorizable iff E is a multiple of 4 (keeps row/col 16B-aligned views)
  const int E4 = ((E & 3) == 0) ? (E >> 2) : 0;

  char* base = (char*)d_ws;
  size_t off = 0;
  auto alloc = [&](size_t bytes) -> char* {
    char* p = base + off;
    off += (bytes + 255) & ~(size_t)255;
    return p;
  };
  float* Hr     = (float*)alloc((size_t)N * 128 * 4);
  float* Hc     = (float*)alloc((size_t)N * 128 * 4);
  float* velfac = (float*)alloc((size_t)N * 4);
  float* zblk   = (float*)alloc((size_t)132 * N * 4);  // deg|agg|cnt|aggn
  int*   deg    = (int*)zblk;
  float* agg    = zblk + N;
  float* cnt    = agg + (size_t)2 * N;
  float* aggn   = cnt + N;
  unsigned short* aggnb = (unsigned short*)aggn;
  int*   ptr    = (int*)alloc((size_t)(N + 1) * 4);
  int*   wptr   = (int*)alloc((size_t)N * 4);
  int2*  ecS    = (int2*)alloc((size_t)E * 8);
  float* trans  = (float*)alloc((size_t)E * 2 * 4);
  unsigned short* wfall = (unsigned short*)alloc((size_t)8 * 16384 * 2);
  int*   bsum   = (int*)alloc((size_t)1024 * 4);
  int*   boff   = (int*)alloc((size_t)1024 * 4);
  size_t fixed_end = off;
  unsigned short* efbuf = (unsigned short*)(base + fixed_end);

  unsigned short* WFe1r = wfall;
  unsigned short* WFe1c = wfall + 16384;
  unsigned short* WFv1  = wfall + 2 * 16384;
  unsigned short* WFe2  = wfall + 3 * 16384;
  unsigned short* WFc1  = wfall + 4 * 16384;
  unsigned short* WFn1a = wfall + 5 * 16384;
  unsigned short* WFn1b = wfall + 6 * 16384;
  unsigned short* WFn2  = wfall + 7 * 16384;

  const int nbS = (N + 1023) / 1024;
  int use_csr = 0, EC = 0, nch = 1;
  if (ws_size > fixed_end) {
    size_t ec_max = (ws_size - fixed_end) / 256;
    ec_max &= ~(size_t)31;
    if (ec_max >= 32768 && nbS <= 1024) {
      use_csr = 1;
      size_t e_pad = ((size_t)E + 31) & ~(size_t)31;
      EC = (int)((ec_max < e_pad) ? ec_max : e_pad);
      nch = (E + EC - 1) / EC;
    }
  }

  const int nblk32 = (N + 31) / 32;
  float* hout = (float*)d_out;
  float* cout = hout + (size_t)N * 128;

  if (use_csr) {
    hipMemsetAsync(deg, 0, (size_t)N * 4, stream);
    hipLaunchKernelGGL(deg_wprep_kernel, dim3(DEGB + 512), dim3(256), 0, stream,
                       row, deg, E, E4, We1, Wv1, We2, Wc1, Wn1, Wn2, wfall);
    hipLaunchKernelGGL(scan_sum_kernel, dim3(nbS), dim3(1024), 0, stream,
                       deg, bsum, N);
    hipLaunchKernelGGL(scan_off_kernel, dim3(1), dim3(1024), 0, stream,
                       bsum, boff, nbS);
    hipLaunchKernelGGL(scan_write_kernel, dim3(nbS), dim3(1024), 0, stream,
                       deg, boff, ptr, wptr, N, E);
    hipLaunchKernelGGL(scatter_nodepre_kernel, dim3(SCATB + nblk32), dim3(256), 0,
                       stream, row, col, wptr, ecS, E, E4,
                       h, WFe1r, WFe1c, WFv1, be1, bv1, Wv2, bv2,
                       Hr, Hc, velfac, N);
    if (nch == 1) {
      hipLaunchKernelGGL(edge_mfma_kernel, dim3((E + ET - 1) / ET), dim3(256), 0,
                         stream, ecS, Hr, Hc, coord, vel, We1,
                         WFe2, WFc1, be2, bc1, Wc2, efbuf, trans, 0, E);
      hipLaunchKernelGGL(gather_final_mfma, dim3(nblk32), dim3(256), 0, stream,
                         h, coord, vel, WFn1a, WFn1b, WFn2, bn1, bn2,
                         ptr, efbuf, trans, velfac, hout, cout, N);
    } else {
      for (int c = 0; c < nch; ++c) {
        int lo = c * EC;
        int hi = (lo + EC < E) ? lo + EC : E;
        int nb = (hi - lo + ET - 1) / ET;
        hipLaunchKernelGGL(edge_mfma_kernel, dim3(nb), dim3(256), 0, stream,
                           ecS, Hr, Hc, coord, vel, We1,
                           WFe2, WFc1, be2, bc1, Wc2, efbuf, trans, lo, hi);
        hipLaunchKernelGGL(gather_kernel, dim3((N + 3) / 4), dim3(256), 0, stream,
                           ptr, efbuf, trans, aggnb, agg, N, lo, hi, (c == 0) ? 1 : 0);
      }
      hipLaunchKernelGGL(node_final_mfma, dim3(nblk32), dim3(256), 0, stream,
                         h, coord, vel, WFn1a, WFn1b, WFn2, bn1, bn2,
                         agg, ptr, aggnb, velfac, hout, cout, N);
    }
  } else {
    hipMemsetAsync(zblk, 0, (size_t)132 * N * 4, stream);
    hipLaunchKernelGGL(node_pre_legacy, dim3(N / 8), dim3(128), 0, stream,
                       h, We1, be1, Wv1, bv1, Wv2, bv2, Hr, Hc, velfac);
    hipLaunchKernelGGL(edge_kernel_legacy, dim3((E + ET - 1) / ET), dim3(256), 0,
                       stream, row, col, Hr, Hc, coord, vel, We1, We2, be2,
                       Wc1, bc1, Wc2, agg, cnt, aggn, E);
    hipLaunchKernelGGL(node_final_legacy, dim3(N / 4), dim3(128), 0, stream,
                       h, coord, vel, Wn1, bn1, Wn2, bn2, agg, cnt,
                       aggn, velfac, hout, cout);
  }
}

// Round 14
// 480.963 us; speedup vs baseline: 1.4090x; 1.0986x over previous
//
#include <hip/hip_runtime.h>

#define RELU(x) fmaxf((x), 0.0f)

typedef __attribute__((ext_vector_type(2))) float f32x2;
typedef __attribute__((ext_vector_type(4))) short short4v;
typedef __attribute__((ext_vector_type(8))) short short8v;
typedef __attribute__((ext_vector_type(16))) float f32x16;

__device__ __forceinline__ float bf2f(unsigned short u) {
  unsigned v = ((unsigned)u) << 16;
  float f; __builtin_memcpy(&f, &v, 4); return f;
}
__device__ __forceinline__ unsigned short f2bf(float f) {
  unsigned u; __builtin_memcpy(&u, &f, 4);
  unsigned r = (u + 0x7FFFu + ((u >> 16) & 1u)) >> 16;
  return (unsigned short)r;
}
// HW packed convert: dst = {lo: bf16(a), hi: bf16(b)} (RNE).
__device__ __forceinline__ unsigned cvtpk(float a, float b) {
  unsigned r;
  asm("v_cvt_pk_bf16_f32 %0, %1, %2" : "=v"(r) : "v"(a), "v"(b));
  return r;
}
// packed f32 add: one instruction, two adds.
__device__ __forceinline__ f32x2 pk_add(f32x2 a, f32x2 b) {
  f32x2 d;
  asm("v_pk_add_f32 %0, %1, %2" : "=v"(d) : "v"(a), "v"(b));
  return d;
}
// unpack uint (2 bf16) -> f32 pair: lo = u<<16, hi = u & 0xFFFF0000.
__device__ __forceinline__ f32x2 unpk(unsigned u) {
  unsigned lo = u << 16, hi = u & 0xFFFF0000u;
  float fx, fy;
  __builtin_memcpy(&fx, &lo, 4);
  __builtin_memcpy(&fy, &hi, 4);
  f32x2 r = {fx, fy};
  return r;
}

// ---------------------------------------------------------------------------
// Fused: deg histogram (grid-stride, int4 loads) + wprep8.
// ---------------------------------------------------------------------------
#define DEGB 512

__global__ __launch_bounds__(256) void deg_wprep_kernel(
    const int* __restrict__ row, int* __restrict__ deg, int E, int E4,
    const float* __restrict__ We1, const float* __restrict__ Wv1,
    const float* __restrict__ We2, const float* __restrict__ Wc1,
    const float* __restrict__ Wn1, const float* __restrict__ Wn2,
    unsigned short* __restrict__ WF)
{
  if ((int)blockIdx.x < DEGB) {
    const int gs = DEGB * 256;
    const int base = blockIdx.x * 256 + threadIdx.x;
    const int4* row4 = (const int4*)row;
    for (int i = base; i < E4; i += gs) {
      int4 r = row4[i];
      atomicAdd(&deg[r.x], 1); atomicAdd(&deg[r.y], 1);
      atomicAdd(&deg[r.z], 1); atomicAdd(&deg[r.w], 1);
    }
    for (int i = (E4 << 2) + base; i < E; i += gs) atomicAdd(&deg[row[i]], 1);
    return;
  }
  const int bid = blockIdx.x - DEGB;
  const int g = bid >> 6;
  const int idx = (bid & 63) * 256 + threadIdx.x;
  const float* W;
  switch (g) {
    case 0: W = We1; break;
    case 1: W = We1 + 16384; break;
    case 2: W = Wv1; break;
    case 3: W = We2; break;
    case 4: W = Wc1; break;
    case 5: W = Wn1; break;
    case 6: W = Wn1 + 16384; break;
    default: W = Wn2; break;
  }
  int j = idx & 7, l = (idx >> 3) & 63, s = (idx >> 9) & 7, n = idx >> 12;
  int k = s * 16 + ((l >> 5) << 3) + j;
  int c = n * 32 + (l & 31);
  WF[g * 16384 + idx] = f2bf(W[k * 128 + c]);
}

// ---------------------------------------------------------------------------
// Parallel scan: 3 small kernels (partial sums -> block offsets -> write).
// ---------------------------------------------------------------------------
__global__ __launch_bounds__(1024) void scan_sum_kernel(
    const int* __restrict__ deg, int* __restrict__ bsum, int N)
{
  __shared__ int s[1024];
  const int t = threadIdx.x;
  const int i = blockIdx.x * 1024 + t;
  s[t] = (i < N) ? deg[i] : 0;
  __syncthreads();
  for (int off = 512; off >= 1; off >>= 1) {
    if (t < off) s[t] += s[t + off];
    __syncthreads();
  }
  if (t == 0) bsum[blockIdx.x] = s[0];
}

__global__ __launch_bounds__(1024) void scan_off_kernel(
    const int* __restrict__ bsum, int* __restrict__ boff, int nb)
{
  __shared__ int s[2][1024];
  const int t = threadIdx.x;
  s[0][t] = (t < nb) ? bsum[t] : 0;
  __syncthreads();
  int src = 0;
  for (int off = 1; off < 1024; off <<= 1) {
    int v = s[src][t];
    if (t >= off) v += s[src][t - off];
    s[src ^ 1][t] = v;
    __syncthreads();
    src ^= 1;
  }
  if (t < nb) boff[t] = t ? s[src][t - 1] : 0;
}

__global__ __launch_bounds__(1024) void scan_write_kernel(
    const int* __restrict__ deg, const int* __restrict__ boff,
    int* __restrict__ ptr, int* __restrict__ wptr, int N, int E)
{
  __shared__ int s[2][1024];
  const int t = threadIdx.x;
  const int i = blockIdx.x * 1024 + t;
  s[0][t] = (i < N) ? deg[i] : 0;
  __syncthreads();
  int src = 0;
  for (int off = 1; off < 1024; off <<= 1) {
    int v = s[src][t];
    if (t >= off) v += s[src][t - off];
    s[src ^ 1][t] = v;
    __syncthreads();
    src ^= 1;
  }
  if (i < N) {
    int ex = boff[blockIdx.x] + (t ? s[src][t - 1] : 0);
    ptr[i] = ex;
    wptr[i] = ex;
  }
  if (blockIdx.x == 0 && t == 0) ptr[N] = E;
}

// ---------------------------------------------------------------------------
// Fused: scatter (grid-stride int4, writes SORTED int2 pairs) + node_pre MFMA.
// ---------------------------------------------------------------------------
#define SCATB 512

__global__ __launch_bounds__(256) void scatter_nodepre_kernel(
    const int* __restrict__ row, const int* __restrict__ col,
    int* __restrict__ wptr, int2* __restrict__ ecS, int E, int E4,
    const float* __restrict__ h,
    const unsigned short* __restrict__ WFe1r,
    const unsigned short* __restrict__ WFe1c,
    const unsigned short* __restrict__ WFv1,
    const float* __restrict__ be1, const float* __restrict__ bv1,
    const float* __restrict__ Wv2, const float* __restrict__ bv2,
    float* __restrict__ Hr, float* __restrict__ Hc, float* __restrict__ velfac,
    int N)
{
  __shared__ __align__(16) unsigned short Ah[4096];
  __shared__ float Wv2s[128];
  __shared__ float vpart[32][4];

  if ((int)blockIdx.x < SCATB) {
    const int gs = SCATB * 256;
    const int base = blockIdx.x * 256 + threadIdx.x;
    const int4* row4 = (const int4*)row;
    const int4* col4 = (const int4*)col;
    for (int i = base; i < E4; i += gs) {
      int4 r = row4[i];
      int4 c = col4[i];
      int p0 = atomicAdd(&wptr[r.x], 1); ecS[p0] = make_int2(r.x, c.x);
      int p1 = atomicAdd(&wptr[r.y], 1); ecS[p1] = make_int2(r.y, c.y);
      int p2 = atomicAdd(&wptr[r.z], 1); ecS[p2] = make_int2(r.z, c.z);
      int p3 = atomicAdd(&wptr[r.w], 1); ecS[p3] = make_int2(r.w, c.w);
    }
    for (int i = (E4 << 2) + base; i < E; i += gs) {
      int r = row[i];
      int p = atomicAdd(&wptr[r], 1);
      ecS[p] = make_int2(r, col[i]);
    }
    return;
  }
  const int t = threadIdx.x, wv = t >> 6, lane = t & 63;
  const int n0 = (blockIdx.x - SCATB) * 32;

  if (t < 128) Wv2s[t] = Wv2[t];
  {
    const int e = t >> 3, kc = (t & 7) << 4;
    const int n = n0 + e;
    unsigned pk[8];
    if (n < N) {
      const float* hp = h + (size_t)n * 128 + kc;
      #pragma unroll
      for (int qc = 0; qc < 4; ++qc) {
        float4 v = *(const float4*)(hp + qc * 4);
        pk[qc * 2] = cvtpk(v.x, v.y); pk[qc * 2 + 1] = cvtpk(v.z, v.w);
      }
    } else {
      #pragma unroll
      for (int q = 0; q < 8; ++q) pk[q] = 0u;
    }
    const int sw = e << 2, rb = e << 7;
    #pragma unroll
    for (int q = 0; q < 4; ++q)
      *(uint2*)&Ah[rb + ((kc + 4 * q) ^ sw)] = make_uint2(pk[2 * q], pk[2 * q + 1]);
  }
  __syncthreads();

  const int eA = lane & 31, khalf = (lane >> 5) << 3, swA = eA << 2;
  const int baseA = eA << 7;
  f32x16 aR = {0.f}, aC = {0.f}, aV = {0.f};
  const unsigned short* b1 = WFe1r + ((wv << 12) | (lane << 3));
  const unsigned short* b2 = WFe1c + ((wv << 12) | (lane << 3));
  const unsigned short* b3 = WFv1 + ((wv << 12) | (lane << 3));
  #pragma unroll
  for (int s = 0; s < 8; ++s) {
    const int k1 = s * 16 + khalf;
    short4v a0 = *(const short4v*)&Ah[baseA + (k1 ^ swA)];
    short4v a1 = *(const short4v*)&Ah[baseA + ((k1 + 4) ^ swA)];
    short8v z = __builtin_shufflevector(a0, a1, 0, 1, 2, 3, 4, 5, 6, 7);
    aR = __builtin_amdgcn_mfma_f32_32x32x16_bf16(z, *(const short8v*)(b1 + (s << 9)), aR, 0, 0, 0);
    aC = __builtin_amdgcn_mfma_f32_32x32x16_bf16(z, *(const short8v*)(b2 + (s << 9)), aC, 0, 0, 0);
    aV = __builtin_amdgcn_mfma_f32_32x32x16_bf16(z, *(const short8v*)(b3 + (s << 9)), aV, 0, 0, 0);
  }
  const int colb = (wv << 5) | (lane & 31);
  const float be1j = be1[colb], bv1j = bv1[colb], wv2j = Wv2s[colb];
  const int ebase = (lane >> 5) << 2;
  #pragma unroll
  for (int r = 0; r < 16; ++r) {
    const int e = (r & 3) + 8 * (r >> 2) + ebase;
    const int n = n0 + e;
    if (n < N) {
      Hr[(size_t)n * 128 + colb] = aR[r] + be1j;
      Hc[(size_t)n * 128 + colb] = aC[r];
    }
    float v = RELU(aV[r] + bv1j) * wv2j;
    v += __shfl_xor(v, 1); v += __shfl_xor(v, 2); v += __shfl_xor(v, 4);
    v += __shfl_xor(v, 8); v += __shfl_xor(v, 16);
    if ((lane & 31) == 0) vpart[e][wv] = v;
  }
  __syncthreads();
  if (t < 32) {
    const int n = n0 + t;
    if (n < N)
      velfac[n] = vpart[t][0] + vpart[t][1] + vpart[t][2] + vpart[t][3] + bv2[0];
  }
}

// ---------------------------------------------------------------------------
// Edge kernel (MFMA) — R13 structure; __launch_bounds__(256,4) occupancy hint;
// float2 meta loads.
// ---------------------------------------------------------------------------
#define ET 32

__global__ __launch_bounds__(256, 4) void edge_mfma_kernel(
    const int2* __restrict__ ecS,
    const float* __restrict__ Hr, const float* __restrict__ Hc,
    const float* __restrict__ coord, const float* __restrict__ vel,
    const float* __restrict__ We1,
    const unsigned short* __restrict__ WFe2,
    const unsigned short* __restrict__ WFc1,
    const float* __restrict__ be2, const float* __restrict__ bc1,
    const float* __restrict__ Wc2,
    unsigned short* __restrict__ efbuf, float* __restrict__ transbuf,
    int lo, int hi)
{
  const int t    = threadIdx.x;
  const int wv   = t >> 6;
  const int lane = t & 63;
  const int iblk = lo + blockIdx.x * ET;

  __shared__ __align__(16) unsigned short Z4[4 * 4096];
  __shared__ __align__(16) float Wc2s[256];
  __shared__ float ped[11][32];
  __shared__ int rs[32], cs[32];
  __shared__ float cmE[32][2];

  if (t < ET) {
    int i = iblk + t;
    int r = 0, c = 0;
    if (i < hi) { int2 rc = ecS[i]; r = rc.x; c = rc.y; }
    rs[t] = r; cs[t] = c;
    float2 cr = *(const float2*)&coord[2 * r];
    float2 cc = *(const float2*)&coord[2 * c];
    float2 vr = *(const float2*)&vel[2 * r];
    float2 vc = *(const float2*)&vel[2 * c];
    ped[0][t] = cr.x; ped[1][t] = cr.y; ped[2][t] = cc.x; ped[3][t] = cc.y;
    ped[4][t] = vr.x; ped[5][t] = vr.y;
    ped[6][t] = vc.x; ped[7][t] = vc.y;
    float dx = cr.x - cc.x, dy = cr.y - cc.y;
    ped[8][t] = dx; ped[9][t] = dy; ped[10][t] = dx * dx + dy * dy;
  }
  Wc2s[t] = Wc2[t];
  __syncthreads();

  // ---- Z-compute: 4 k's (kq) x 4 edges (eg) per thread ----
  {
    const int kq = t & 31;
    const int eg = t >> 5;
    const int kc = kq << 2;
    float4 w0 = *(const float4*)&We1[(size_t)(256 + 0) * 128 + kc];
    float4 w1 = *(const float4*)&We1[(size_t)(256 + 1) * 128 + kc];
    float4 w2 = *(const float4*)&We1[(size_t)(256 + 2) * 128 + kc];
    float4 w3 = *(const float4*)&We1[(size_t)(256 + 3) * 128 + kc];
    float4 w4 = *(const float4*)&We1[(size_t)(256 + 4) * 128 + kc];
    float4 w5 = *(const float4*)&We1[(size_t)(256 + 5) * 128 + kc];
    float4 w6 = *(const float4*)&We1[(size_t)(256 + 6) * 128 + kc];
    float4 w7 = *(const float4*)&We1[(size_t)(256 + 7) * 128 + kc];
    float4 w8 = *(const float4*)&We1[(size_t)(256 + 8) * 128 + kc];
    float wa0[4] = {w0.x, w0.y, w0.z, w0.w};
    float wa1[4] = {w1.x, w1.y, w1.z, w1.w};
    float wa2[4] = {w2.x, w2.y, w2.z, w2.w};
    float wa3[4] = {w3.x, w3.y, w3.z, w3.w};
    float wa4[4] = {w4.x, w4.y, w4.z, w4.w};
    float wa5[4] = {w5.x, w5.y, w5.z, w5.w};
    float wa6[4] = {w6.x, w6.y, w6.z, w6.w};
    float wa7[4] = {w7.x, w7.y, w7.z, w7.w};
    float wa8[4] = {w8.x, w8.y, w8.z, w8.w};
    #pragma unroll
    for (int ee = 0; ee < 4; ++ee) {
      const int e = (eg << 2) + ee;
      const int r = rs[e], c = cs[e];
      float4 h4 = *(const float4*)(Hr + (size_t)r * 128 + kc);
      float4 c4 = *(const float4*)(Hc + (size_t)c * 128 + kc);
      float hb[4] = {h4.x, h4.y, h4.z, h4.w};
      float cb[4] = {c4.x, c4.y, c4.z, c4.w};
      const float xr = ped[0][e], yr = ped[1][e], xc = ped[2][e], yc = ped[3][e];
      const float vrx = ped[4][e], vry = ped[5][e], vcx = ped[6][e], vcy = ped[7][e];
      const float d2 = ped[10][e];
      float z0[4], z1[4], z2[4], z3[4];
      #pragma unroll
      for (int m = 0; m < 4; ++m) {
        float base = fmaf(d2, wa4[m], hb[m] + cb[m]);
        float A = fmaf(xr, wa0[m], fmaf(xc, wa2[m], fmaf(vrx, wa5[m], vcx * wa7[m])));
        float B = fmaf(yr, wa1[m], fmaf(yc, wa3[m], fmaf(vry, wa6[m], vcy * wa8[m])));
        float bp = base + A, bm = base - A;
        z0[m] = RELU(bp + B);
        z1[m] = RELU(bm - B);
        z2[m] = RELU(bm + B);
        z3[m] = RELU(bp - B);
      }
      const int ia = (e << 7) + (kc ^ (e << 2));
      *(uint2*)&Z4[ia]         = make_uint2(cvtpk(z0[0], z0[1]), cvtpk(z0[2], z0[3]));
      *(uint2*)&Z4[4096 + ia]  = make_uint2(cvtpk(z1[0], z1[1]), cvtpk(z1[2], z1[3]));
      *(uint2*)&Z4[8192 + ia]  = make_uint2(cvtpk(z2[0], z2[1]), cvtpk(z2[2], z2[3]));
      *(uint2*)&Z4[12288 + ia] = make_uint2(cvtpk(z3[0], z3[1]), cvtpk(z3[2], z3[3]));
    }
  }
  __syncthreads();

  // ---- stage 1: 4 groups x 8 K-steps of 32x32x16 MFMA ----
  const int eA    = lane & 31;
  const int khalf = (lane >> 5) << 3;
  const int swA   = eA << 2;
  const int baseA = eA << 7;
  f32x16 ac0 = {0.f}, ac1 = {0.f}, ac2 = {0.f}, ac3 = {0.f};
  {
    const unsigned short* WFw = WFe2 + ((wv << 12) | (lane << 3));
    #pragma unroll
    for (int s = 0; s < 8; ++s) {
      short8v bw = *(const short8v*)(WFw + (s << 9));
      const int k1 = s * 16 + khalf;
      const int i0 = baseA + (k1 ^ swA);
      const int i1 = baseA + ((k1 + 4) ^ swA);
      short8v z0 = __builtin_shufflevector(*(const short4v*)&Z4[i0],
                                           *(const short4v*)&Z4[i1], 0,1,2,3,4,5,6,7);
      short8v z1 = __builtin_shufflevector(*(const short4v*)&Z4[4096 + i0],
                                           *(const short4v*)&Z4[4096 + i1], 0,1,2,3,4,5,6,7);
      short8v z2 = __builtin_shufflevector(*(const short4v*)&Z4[8192 + i0],
                                           *(const short4v*)&Z4[8192 + i1], 0,1,2,3,4,5,6,7);
      short8v z3 = __builtin_shufflevector(*(const short4v*)&Z4[12288 + i0],
                                           *(const short4v*)&Z4[12288 + i1], 0,1,2,3,4,5,6,7);
      ac0 = __builtin_amdgcn_mfma_f32_32x32x16_bf16(z0, bw, ac0, 0, 0, 0);
      ac1 = __builtin_amdgcn_mfma_f32_32x32x16_bf16(z1, bw, ac1, 0, 0, 0);
      ac2 = __builtin_amdgcn_mfma_f32_32x32x16_bf16(z2, bw, ac2, 0, 0, 0);
      ac3 = __builtin_amdgcn_mfma_f32_32x32x16_bf16(z3, bw, ac3, 0, 0, 0);
    }
  }
  __syncthreads();   // all Z4 reads done; region 0 -> ef, region 1 -> tv

  // ---- ef = 0.25 * sum_g relu(out_g + be2) -> LDS bf16 (cvtpk pairs) ----
  {
    const int j = (wv << 5) | (lane & 31);
    const float be2j = be2[j];
    const int ebase = (lane >> 5) << 2;
    #pragma unroll
    for (int q = 0; q < 8; ++q) {
      const int r0 = 2 * q;
      float v0 = RELU(ac0[r0] + be2j) + RELU(ac1[r0] + be2j) +
                 RELU(ac2[r0] + be2j) + RELU(ac3[r0] + be2j);
      float v1 = RELU(ac0[r0 + 1] + be2j) + RELU(ac1[r0 + 1] + be2j) +
                 RELU(ac2[r0 + 1] + be2j) + RELU(ac3[r0 + 1] + be2j);
      unsigned p = cvtpk(0.25f * v0, 0.25f * v1);
      const int e0_ = (r0 & 3) + 8 * (r0 >> 2) + ebase;
      const int e1_ = e0_ + 1;
      Z4[(e0_ << 7) + (j ^ (e0_ << 2))] = (unsigned short)p;
      Z4[(e1_ << 7) + (j ^ (e1_ << 2))] = (unsigned short)(p >> 16);
    }
  }
  __syncthreads();

  // ---- write efbuf (global, coalesced) ----
  {
    const int e  = t >> 3;
    const int kc = (t & 7) << 4;
    int i = iblk + e;
    if (i < hi) {
      const int sw = e << 2, rb = e << 7;
      uint2 c0 = *(const uint2*)&Z4[rb + ((kc + 0) ^ sw)];
      uint2 c1 = *(const uint2*)&Z4[rb + ((kc + 4) ^ sw)];
      uint2 c2 = *(const uint2*)&Z4[rb + ((kc + 8) ^ sw)];
      uint2 c3 = *(const uint2*)&Z4[rb + ((kc + 12) ^ sw)];
      *(uint4*)&efbuf[(size_t)(i - lo) * 128 + kc]     = make_uint4(c0.x, c0.y, c1.x, c1.y);
      *(uint4*)&efbuf[(size_t)(i - lo) * 128 + kc + 8] = make_uint4(c2.x, c2.y, c3.x, c3.y);
    }
  }

  // ---- stage 2: EF @ Wc1 ----
  f32x16 a2 = {0.f};
  {
    const unsigned short* WFc = WFc1 + ((wv << 12) | (lane << 3));
    #pragma unroll
    for (int s = 0; s < 8; ++s) {
      short8v bw = *(const short8v*)(WFc + (s << 9));
      const int k1 = s * 16 + khalf;
      const int i0 = baseA + (k1 ^ swA);
      const int i1 = baseA + ((k1 + 4) ^ swA);
      short8v af = __builtin_shufflevector(*(const short4v*)&Z4[i0],
                                           *(const short4v*)&Z4[i1], 0,1,2,3,4,5,6,7);
      a2 = __builtin_amdgcn_mfma_f32_32x32x16_bf16(af, bw, a2, 0, 0, 0);
    }
  }
  // ---- tv = relu(a2 + bc1) -> LDS region 1 (cvtpk pairs) ----
  {
    const int j = (wv << 5) | (lane & 31);
    const float bc1j = bc1[j];
    const int ebase = (lane >> 5) << 2;
    #pragma unroll
    for (int q = 0; q < 8; ++q) {
      const int r0 = 2 * q;
      unsigned p = cvtpk(RELU(a2[r0] + bc1j), RELU(a2[r0 + 1] + bc1j));
      const int e0_ = (r0 & 3) + 8 * (r0 >> 2) + ebase;
      const int e1_ = e0_ + 1;
      Z4[4096 + (e0_ << 7) + (j ^ (e0_ << 2))] = (unsigned short)p;
      Z4[4096 + (e1_ << 7) + (j ^ (e1_ << 2))] = (unsigned short)(p >> 16);
    }
  }
  __syncthreads();

  // ---- cm[e] = tv[e][:] @ Wc2 : 8 threads/edge, shfl reduce ----
  {
    const int e  = t >> 3;
    const int jc = (t & 7) << 4;
    const int sw = e << 2, rb = e << 7;
    uint2 d0 = *(const uint2*)&Z4[4096 + rb + ((jc + 0) ^ sw)];
    uint2 d1 = *(const uint2*)&Z4[4096 + rb + ((jc + 4) ^ sw)];
    uint2 d2 = *(const uint2*)&Z4[4096 + rb + ((jc + 8) ^ sw)];
    uint2 d3 = *(const uint2*)&Z4[4096 + rb + ((jc + 12) ^ sw)];
    unsigned uu[8] = {d0.x, d0.y, d1.x, d1.y, d2.x, d2.y, d3.x, d3.y};
    float cx = 0.f, cy = 0.f;
    #pragma unroll
    for (int q = 0; q < 8; ++q) {
      float t0 = bf2f((unsigned short)(uu[q] & 0xFFFFu));
      float t1 = bf2f((unsigned short)(uu[q] >> 16));
      float2 wA = *(const float2*)&Wc2s[2 * (jc + 2 * q)];
      float2 wB = *(const float2*)&Wc2s[2 * (jc + 2 * q + 1)];
      cx = fmaf(t0, wA.x, cx); cy = fmaf(t0, wA.y, cy);
      cx = fmaf(t1, wB.x, cx); cy = fmaf(t1, wB.y, cy);
    }
    cx += __shfl_xor(cx, 1); cy += __shfl_xor(cy, 1);
    cx += __shfl_xor(cx, 2); cy += __shfl_xor(cy, 2);
    cx += __shfl_xor(cx, 4); cy += __shfl_xor(cy, 4);
    if ((t & 7) == 0) { cmE[e][0] = cx; cmE[e][1] = cy; }
  }
  __syncthreads();
  if (t < ET) {
    int i = iblk + t;
    if (i < hi) {
      float tx = fminf(fmaxf(ped[8][t] * cmE[t][0], -100.0f), 100.0f);
      float ty = fminf(fmaxf(ped[9][t] * cmE[t][1], -100.0f), 100.0f);
      transbuf[(size_t)i * 2]     = tx;
      transbuf[(size_t)i * 2 + 1] = ty;
    }
  }
}

// ---------------------------------------------------------------------------
// Fused gather + node_final (nch==1). pk_add accumulation.
// ---------------------------------------------------------------------------
__global__ __launch_bounds__(256) void gather_final_mfma(
    const float* __restrict__ h, const float* __restrict__ coord,
    const float* __restrict__ vel,
    const unsigned short* __restrict__ WFn1a,
    const unsigned short* __restrict__ WFn1b,
    const unsigned short* __restrict__ WFn2,
    const float* __restrict__ bn1, const float* __restrict__ bn2,
    const int* __restrict__ ptr, const unsigned short* __restrict__ efbuf,
    const float* __restrict__ transbuf, const float* __restrict__ velfac,
    float* __restrict__ hout, float* __restrict__ cout, int N)
{
  const int t = threadIdx.x, wv = t >> 6, lane = t & 63;
  const int n0 = blockIdx.x * 32;
  __shared__ __align__(16) unsigned short Ah[4096];
  __shared__ __align__(16) unsigned short Ag[4096];
  __shared__ __align__(16) unsigned short Mid[4096];
  __shared__ float trs[32][2];

  {
    const int e = t >> 3, kc = (t & 7) << 4;
    const int n = n0 + e;
    const int sw = (e & 15) << 3, rb = e << 7;
    unsigned pk[8];
    f32x2 ac2[8];
    #pragma unroll
    for (int q = 0; q < 8; ++q) { f32x2 z = {0.f, 0.f}; ac2[q] = z; }
    float tx = 0.f, ty = 0.f;
    if (n < N) {
      const float* hp = h + (size_t)n * 128 + kc;
      #pragma unroll
      for (int qc = 0; qc < 4; ++qc) {
        float4 v = *(const float4*)(hp + qc * 4);
        pk[qc * 2] = cvtpk(v.x, v.y); pk[qc * 2 + 1] = cvtpk(v.z, v.w);
      }
      const int p0 = ptr[n], p1 = ptr[n + 1];
      for (int i = p0; i < p1; ++i) {
        uint4 a = *(const uint4*)&efbuf[(size_t)i * 128 + kc];
        uint4 b = *(const uint4*)&efbuf[(size_t)i * 128 + kc + 8];
        unsigned uu[8] = {a.x, a.y, a.z, a.w, b.x, b.y, b.z, b.w};
        #pragma unroll
        for (int q = 0; q < 8; ++q) ac2[q] = pk_add(ac2[q], unpk(uu[q]));
      }
      for (int i = p0 + (t & 7); i < p1; i += 8) {
        tx += transbuf[(size_t)i * 2];
        ty += transbuf[(size_t)i * 2 + 1];
      }
    } else {
      #pragma unroll
      for (int q = 0; q < 8; ++q) pk[q] = 0u;
    }
    tx += __shfl_xor(tx, 1); ty += __shfl_xor(ty, 1);
    tx += __shfl_xor(tx, 2); ty += __shfl_xor(ty, 2);
    tx += __shfl_xor(tx, 4); ty += __shfl_xor(ty, 4);
    if ((t & 7) == 0) { trs[e][0] = tx; trs[e][1] = ty; }
    *(uint4*)&Ah[rb + (kc ^ sw)]       = make_uint4(pk[0], pk[1], pk[2], pk[3]);
    *(uint4*)&Ah[rb + ((kc + 8) ^ sw)] = make_uint4(pk[4], pk[5], pk[6], pk[7]);
    unsigned gk[8];
    #pragma unroll
    for (int q = 0; q < 8; ++q) gk[q] = cvtpk(ac2[q].x, ac2[q].y);
    *(uint4*)&Ag[rb + (kc ^ sw)]       = make_uint4(gk[0], gk[1], gk[2], gk[3]);
    *(uint4*)&Ag[rb + ((kc + 8) ^ sw)] = make_uint4(gk[4], gk[5], gk[6], gk[7]);
  }
  __syncthreads();

  const int eA = lane & 31, khalf = (lane >> 5) << 3, swA = (eA & 15) << 3;
  const int baseA = eA << 7;
  f32x16 m = {0.f};
  {
    const unsigned short* p1 = WFn1a + ((wv << 12) | (lane << 3));
    const unsigned short* p2 = WFn1b + ((wv << 12) | (lane << 3));
    #pragma unroll
    for (int s = 0; s < 8; ++s) {
      const int i0 = baseA + ((s * 16 + khalf) ^ swA);
      short8v zh = *(const short8v*)&Ah[i0];
      short8v zg = *(const short8v*)&Ag[i0];
      m = __builtin_amdgcn_mfma_f32_32x32x16_bf16(zh, *(const short8v*)(p1 + (s << 9)), m, 0, 0, 0);
      m = __builtin_amdgcn_mfma_f32_32x32x16_bf16(zg, *(const short8v*)(p2 + (s << 9)), m, 0, 0, 0);
    }
  }
  const int colb = (wv << 5) | (lane & 31);
  const float bn1j = bn1[colb];
  const int ebase = (lane >> 5) << 2;
  #pragma unroll
  for (int r = 0; r < 16; ++r) {
    const int e = (r & 3) + 8 * (r >> 2) + ebase;
    Mid[(e << 7) + (colb ^ ((e & 15) << 3))] = f2bf(RELU(m[r] + bn1j));
  }
  __syncthreads();

  f32x16 o = {0.f};
  {
    const unsigned short* p3 = WFn2 + ((wv << 12) | (lane << 3));
    #pragma unroll
    for (int s = 0; s < 8; ++s) {
      const int i0 = baseA + ((s * 16 + khalf) ^ swA);
      short8v zm = *(const short8v*)&Mid[i0];
      o = __builtin_amdgcn_mfma_f32_32x32x16_bf16(zm, *(const short8v*)(p3 + (s << 9)), o, 0, 0, 0);
    }
  }
  const float bn2j = bn2[colb];
  #pragma unroll
  for (int r = 0; r < 16; ++r) {
    const int e = (r & 3) + 8 * (r >> 2) + ebase;
    const int n = n0 + e;
    if (n < N)
      hout[(size_t)n * 128 + colb] = h[(size_t)n * 128 + colb] + o[r] + bn2j;
  }
  if (t < 32) {
    const int n = n0 + t;
    if (n < N) {
      float c = (float)(ptr[n + 1] - ptr[n]);
      float vf = velfac[n];
      float inv = 1.0f / fmaxf(c, 1.0f);
      cout[(size_t)n * 2]     = coord[(size_t)n * 2]     + trs[t][0] * inv + vf * vel[(size_t)n * 2];
      cout[(size_t)n * 2 + 1] = coord[(size_t)n * 2 + 1] + trs[t][1] * inv + vf * vel[(size_t)n * 2 + 1];
    }
  }
}

// ---------------------------------------------------------------------------
// Chunked fallback (nch>1): gather + node_final.
// ---------------------------------------------------------------------------
__global__ __launch_bounds__(256) void gather_kernel(
    const int* __restrict__ ptr, const unsigned short* __restrict__ efbuf,
    const float* __restrict__ transbuf,
    unsigned short* __restrict__ aggnb, float* __restrict__ agg,
    int N, int lo, int hi, int first)
{
  const int wv = threadIdx.x >> 6, lane = threadIdx.x & 63;
  const int n = blockIdx.x * 4 + wv;
  if (n >= N) return;
  const int p0 = ptr[n], p1 = ptr[n + 1];
  const int a = p0 > lo ? p0 : lo;
  const int b = p1 < hi ? p1 : hi;
  const int sub = lane >> 4, c8 = (lane & 15) << 3;
  f32x2 ac2[4];
  #pragma unroll
  for (int q = 0; q < 4; ++q) { f32x2 z = {0.f, 0.f}; ac2[q] = z; }
  for (int i = a + sub; i < b; i += 4) {
    uint4 v = *(const uint4*)&efbuf[(size_t)(i - lo) * 128 + c8];
    unsigned uu[4] = {v.x, v.y, v.z, v.w};
    #pragma unroll
    for (int q = 0; q < 4; ++q) ac2[q] = pk_add(ac2[q], unpk(uu[q]));
  }
  #pragma unroll
  for (int q = 0; q < 4; ++q) {
    ac2[q].x += __shfl_xor(ac2[q].x, 16);
    ac2[q].y += __shfl_xor(ac2[q].y, 16);
    ac2[q].x += __shfl_xor(ac2[q].x, 32);
    ac2[q].y += __shfl_xor(ac2[q].y, 32);
  }
  if (lane < 16) {
    if (!first) {
      uint4 old = *(const uint4*)&aggnb[(size_t)n * 128 + c8];
      unsigned uo[4] = {old.x, old.y, old.z, old.w};
      #pragma unroll
      for (int q = 0; q < 4; ++q) ac2[q] = pk_add(ac2[q], unpk(uo[q]));
    }
    unsigned pk[4];
    #pragma unroll
    for (int q = 0; q < 4; ++q) pk[q] = cvtpk(ac2[q].x, ac2[q].y);
    *(uint4*)&aggnb[(size_t)n * 128 + c8] = make_uint4(pk[0], pk[1], pk[2], pk[3]);
  }
  if (lane < 2) {
    float tacc = first ? 0.f : agg[(size_t)n * 2 + lane];
    for (int i = a; i < b; ++i) tacc += transbuf[(size_t)i * 2 + lane];
    agg[(size_t)n * 2 + lane] = tacc;
  }
}

__global__ __launch_bounds__(256) void node_final_mfma(
    const float* __restrict__ h, const float* __restrict__ coord,
    const float* __restrict__ vel,
    const unsigned short* __restrict__ WFn1a,
    const unsigned short* __restrict__ WFn1b,
    const unsigned short* __restrict__ WFn2,
    const float* __restrict__ bn1, const float* __restrict__ bn2,
    const float* __restrict__ agg, const int* __restrict__ ptr,
    const unsigned short* __restrict__ aggnb, const float* __restrict__ velfac,
    float* __restrict__ hout, float* __restrict__ cout, int N)
{
  const int t = threadIdx.x, wv = t >> 6, lane = t & 63;
  const int n0 = blockIdx.x * 32;
  __shared__ __align__(16) unsigned short Ah[4096];
  __shared__ __align__(16) unsigned short Ag[4096];
  __shared__ __align__(16) unsigned short Mid[4096];

  {
    const int e = t >> 3, kc = (t & 7) << 4;
    const int n = n0 + e;
    unsigned pk[8], gk[8];
    if (n < N) {
      const float* hp = h + (size_t)n * 128 + kc;
      #pragma unroll
      for (int qc = 0; qc < 4; ++qc) {
        float4 v = *(const float4*)(hp + qc * 4);
        pk[qc * 2] = cvtpk(v.x, v.y); pk[qc * 2 + 1] = cvtpk(v.z, v.w);
      }
      uint4 g0 = *(const uint4*)&aggnb[(size_t)n * 128 + kc];
      uint4 g1 = *(const uint4*)&aggnb[(size_t)n * 128 + kc + 8];
      gk[0] = g0.x; gk[1] = g0.y; gk[2] = g0.z; gk[3] = g0.w;
      gk[4] = g1.x; gk[5] = g1.y; gk[6] = g1.z; gk[7] = g1.w;
    } else {
      #pragma unroll
      for (int q = 0; q < 8; ++q) { pk[q] = 0u; gk[q] = 0u; }
    }
    const int sw = (e & 15) << 3, rb = e << 7;
    *(uint4*)&Ah[rb + (kc ^ sw)]       = make_uint4(pk[0], pk[1], pk[2], pk[3]);
    *(uint4*)&Ah[rb + ((kc + 8) ^ sw)] = make_uint4(pk[4], pk[5], pk[6], pk[7]);
    *(uint4*)&Ag[rb + (kc ^ sw)]       = make_uint4(gk[0], gk[1], gk[2], gk[3]);
    *(uint4*)&Ag[rb + ((kc + 8) ^ sw)] = make_uint4(gk[4], gk[5], gk[6], gk[7]);
  }
  __syncthreads();

  const int eA = lane & 31, khalf = (lane >> 5) << 3, swA = (eA & 15) << 3;
  const int baseA = eA << 7;
  f32x16 m = {0.f};
  {
    const unsigned short* p1 = WFn1a + ((wv << 12) | (lane << 3));
    const unsigned short* p2 = WFn1b + ((wv << 12) | (lane << 3));
    #pragma unroll
    for (int s = 0; s < 8; ++s) {
      const int i0 = baseA + ((s * 16 + khalf) ^ swA);
      short8v zh = *(const short8v*)&Ah[i0];
      short8v zg = *(const short8v*)&Ag[i0];
      m = __builtin_amdgcn_mfma_f32_32x32x16_bf16(zh, *(const short8v*)(p1 + (s << 9)), m, 0, 0, 0);
      m = __builtin_amdgcn_mfma_f32_32x32x16_bf16(zg, *(const short8v*)(p2 + (s << 9)), m, 0, 0, 0);
    }
  }
  const int colb = (wv << 5) | (lane & 31);
  const float bn1j = bn1[colb];
  const int ebase = (lane >> 5) << 2;
  #pragma unroll
  for (int r = 0; r < 16; ++r) {
    const int e = (r & 3) + 8 * (r >> 2) + ebase;
    Mid[(e << 7) + (colb ^ ((e & 15) << 3))] = f2bf(RELU(m[r] + bn1j));
  }
  __syncthreads();

  f32x16 o = {0.f};
  {
    const unsigned short* p3 = WFn2 + ((wv << 12) | (lane << 3));
    #pragma unroll
    for (int s = 0; s < 8; ++s) {
      const int i0 = baseA + ((s * 16 + khalf) ^ swA);
      short8v zm = *(const short8v*)&Mid[i0];
      o = __builtin_amdgcn_mfma_f32_32x32x16_bf16(zm, *(const short8v*)(p3 + (s << 9)), o, 0, 0, 0);
    }
  }
  const float bn2j = bn2[colb];
  #pragma unroll
  for (int r = 0; r < 16; ++r) {
    const int e = (r & 3) + 8 * (r >> 2) + ebase;
    const int n = n0 + e;
    if (n < N)
      hout[(size_t)n * 128 + colb] = h[(size_t)n * 128 + colb] + o[r] + bn2j;
  }
  if (t < 32) {
    const int n = n0 + t;
    if (n < N) {
      float c = (float)(ptr[n + 1] - ptr[n]);
      float vf = velfac[n];
      float inv = 1.0f / fmaxf(c, 1.0f);
      cout[(size_t)n * 2]     = coord[(size_t)n * 2]     + agg[(size_t)n * 2] * inv     + vf * vel[(size_t)n * 2];
      cout[(size_t)n * 2 + 1] = coord[(size_t)n * 2 + 1] + agg[(size_t)n * 2 + 1] * inv + vf * vel[(size_t)n * 2 + 1];
    }
  }
}

// ---------------------------------------------------------------------------
// Legacy fp32 fallback kernels (ws too small for efbuf).
// ---------------------------------------------------------------------------
__global__ __launch_bounds__(256) void edge_kernel_legacy(
    const int* __restrict__ row, const int* __restrict__ col,
    const float* __restrict__ Hr, const float* __restrict__ Hc,
    const float* __restrict__ coord, const float* __restrict__ vel,
    const float* __restrict__ We1, const float* __restrict__ We2,
    const float* __restrict__ be2, const float* __restrict__ Wc1,
    const float* __restrict__ bc1, const float* __restrict__ Wc2,
    float* __restrict__ agg, float* __restrict__ cnt, float* __restrict__ aggn,
    int E)
{
  const int t  = threadIdx.x;
  const int el = t & 31;
  const int jg = t >> 5;
  const int j0 = jg * 16;
  const int e0 = blockIdx.x * ET;

  __shared__ __align__(16) float Wch[32][128];
  __shared__ __align__(16) float Zbuf[4256];
  __shared__ __align__(16) float W9[9][128];
  __shared__ float ped[11][32];
  __shared__ int   rs[32], cs[32], vE[32];
  __shared__ float cmP[8][32][2];

#define Z4L(g, e_, k_) Zbuf[((g) * 32 + (e_)) * 33 + (k_)]
#define EFL(e_, k_)    Zbuf[(e_) * 133 + (k_)]

  if (t < ET) {
    int e = e0 + t;
    int r = 0, c = 0, v = 0;
    if (e < E) { r = row[e]; c = col[e]; v = 1; }
    rs[t] = r; cs[t] = c; vE[t] = v;
    float crx = coord[2 * r], cry = coord[2 * r + 1];
    float ccx = coord[2 * c], ccy = coord[2 * c + 1];
    ped[0][t] = crx; ped[1][t] = cry; ped[2][t] = ccx; ped[3][t] = ccy;
    ped[4][t] = vel[2 * r]; ped[5][t] = vel[2 * r + 1];
    ped[6][t] = vel[2 * c]; ped[7][t] = vel[2 * c + 1];
    float dx = crx - ccx, dy = cry - ccy;
    ped[8][t] = dx; ped[9][t] = dy; ped[10][t] = dx * dx + dy * dy;
  }
  for (int idx = t; idx < 9 * 128; idx += 256)
    W9[idx >> 7][idx & 127] = We1[(size_t)(256 + (idx >> 7)) * 128 + (idx & 127)];

  float outg[4][16];
  #pragma unroll
  for (int g = 0; g < 4; ++g)
    #pragma unroll
    for (int jj = 0; jj < 16; ++jj) outg[g][jj] = 0.0f;

  for (int kc = 0; kc < 4; ++kc) {
    const int kb = kc * 32;
    __syncthreads();
    #pragma unroll
    for (int s = 0; s < 4; ++s) {
      int idx4 = t + s * 256;
      int kl = idx4 >> 5, jc = (idx4 & 31) * 4;
      *(float4*)&Wch[kl][jc] = *(const float4*)&We2[(size_t)(kb + kl) * 128 + jc];
    }
    {
      const int kk = kb + (jg << 2);
      const int kl = jg << 2;
      const int r = rs[el], c = cs[el];
      float4 a4 = *(const float4*)(Hr + (size_t)r * 128 + kk);
      float4 b4 = *(const float4*)(Hc + (size_t)c * 128 + kk);
      float hr[4] = {a4.x, a4.y, a4.z, a4.w};
      float hcv[4] = {b4.x, b4.y, b4.z, b4.w};
      float4 q;
      q = *(const float4*)&W9[0][kk]; float w0[4] = {q.x, q.y, q.z, q.w};
      q = *(const float4*)&W9[1][kk]; float w1[4] = {q.x, q.y, q.z, q.w};
      q = *(const float4*)&W9[2][kk]; float w2[4] = {q.x, q.y, q.z, q.w};
      q = *(const float4*)&W9[3][kk]; float w3[4] = {q.x, q.y, q.z, q.w};
      q = *(const float4*)&W9[4][kk]; float w4[4] = {q.x, q.y, q.z, q.w};
      q = *(const float4*)&W9[5][kk]; float w5[4] = {q.x, q.y, q.z, q.w};
      q = *(const float4*)&W9[6][kk]; float w6[4] = {q.x, q.y, q.z, q.w};
      q = *(const float4*)&W9[7][kk]; float w7[4] = {q.x, q.y, q.z, q.w};
      q = *(const float4*)&W9[8][kk]; float w8[4] = {q.x, q.y, q.z, q.w};
      float xr = ped[0][el], yr = ped[1][el], xc = ped[2][el], yc = ped[3][el];
      float vrx = ped[4][el], vry = ped[5][el], vcx = ped[6][el], vcy = ped[7][el];
      float d2 = ped[10][el];
      #pragma unroll
      for (int i = 0; i < 4; ++i) {
        float base = hr[i] + hcv[i] + d2 * w4[i];
        float A = xr * w0[i] + xc * w2[i] + vrx * w5[i] + vcx * w7[i];
        float B = yr * w1[i] + yc * w3[i] + vry * w6[i] + vcy * w8[i];
        Z4L(0, el, kl + i) = RELU(base + A + B);
        Z4L(1, el, kl + i) = RELU(base - A - B);
        Z4L(2, el, kl + i) = RELU(base - A + B);
        Z4L(3, el, kl + i) = RELU(base + A - B);
      }
    }
    __syncthreads();
    #pragma unroll 2
    for (int k = 0; k < 32; ++k) {
      float4 wa = *(const float4*)&Wch[k][j0];
      float4 wb = *(const float4*)&Wch[k][j0 + 4];
      float4 wc4 = *(const float4*)&Wch[k][j0 + 8];
      float4 wd = *(const float4*)&Wch[k][j0 + 12];
      float w[16] = {wa.x, wa.y, wa.z, wa.w, wb.x, wb.y, wb.z, wb.w,
                     wc4.x, wc4.y, wc4.z, wc4.w, wd.x, wd.y, wd.z, wd.w};
      float z0 = Z4L(0, el, k), z1 = Z4L(1, el, k);
      float z2 = Z4L(2, el, k), z3 = Z4L(3, el, k);
      #pragma unroll
      for (int jj = 0; jj < 16; ++jj) {
        outg[0][jj] = fmaf(z0, w[jj], outg[0][jj]);
        outg[1][jj] = fmaf(z1, w[jj], outg[1][jj]);
        outg[2][jj] = fmaf(z2, w[jj], outg[2][jj]);
        outg[3][jj] = fmaf(z3, w[jj], outg[3][jj]);
      }
    }
  }

  __syncthreads();
  float4 q0 = *(const float4*)(be2 + j0);
  float4 q1 = *(const float4*)(be2 + j0 + 4);
  float4 q2 = *(const float4*)(be2 + j0 + 8);
  float4 q3 = *(const float4*)(be2 + j0 + 12);
  float beA[16] = {q0.x, q0.y, q0.z, q0.w, q1.x, q1.y, q1.z, q1.w,
                   q2.x, q2.y, q2.z, q2.w, q3.x, q3.y, q3.z, q3.w};
  float ef[16];
  #pragma unroll
  for (int jj = 0; jj < 16; ++jj) {
    float s = RELU(outg[0][jj] + beA[jj]) + RELU(outg[1][jj] + beA[jj]) +
              RELU(outg[2][jj] + beA[jj]) + RELU(outg[3][jj] + beA[jj]);
    ef[jj] = 0.25f * s;
  }
  #pragma unroll
  for (int jj = 0; jj < 16; ++jj) EFL(el, j0 + jj) = ef[jj];
  {
    const int r = rs[el];
    if (vE[el]) {
      #pragma unroll
      for (int jj = 0; jj < 16; ++jj)
        unsafeAtomicAdd(&aggn[(size_t)r * 128 + j0 + jj], ef[jj]);
    }
  }

  float acc2[16];
  #pragma unroll
  for (int jj = 0; jj < 16; ++jj) acc2[jj] = 0.0f;
  for (int kc = 0; kc < 4; ++kc) {
    const int kb = kc * 32;
    __syncthreads();
    #pragma unroll
    for (int s = 0; s < 4; ++s) {
      int idx4 = t + s * 256;
      int kl = idx4 >> 5, jc = (idx4 & 31) * 4;
      *(float4*)&Wch[kl][jc] = *(const float4*)&Wc1[(size_t)(kb + kl) * 128 + jc];
    }
    __syncthreads();
    #pragma unroll 4
    for (int k = 0; k < 32; ++k) {
      float4 wa = *(const float4*)&Wch[k][j0];
      float4 wb = *(const float4*)&Wch[k][j0 + 4];
      float4 wc4 = *(const float4*)&Wch[k][j0 + 8];
      float4 wd = *(const float4*)&Wch[k][j0 + 12];
      float w[16] = {wa.x, wa.y, wa.z, wa.w, wb.x, wb.y, wb.z, wb.w,
                     wc4.x, wc4.y, wc4.z, wc4.w, wd.x, wd.y, wd.z, wd.w};
      float efk = EFL(el, kb + k);
      #pragma unroll
      for (int jj = 0; jj < 16; ++jj) acc2[jj] = fmaf(efk, w[jj], acc2[jj]);
    }
  }

  float cm0 = 0.f, cm1 = 0.f;
  #pragma unroll
  for (int jj = 0; jj < 16; ++jj) {
    float tv = RELU(acc2[jj] + bc1[j0 + jj]);
    float2 wp = *(const float2*)(Wc2 + 2 * (j0 + jj));
    cm0 = fmaf(tv, wp.x, cm0);
    cm1 = fmaf(tv, wp.y, cm1);
  }
  cmP[jg][el][0] = cm0; cmP[jg][el][1] = cm1;
  __syncthreads();
  if (t < ET && vE[t]) {
    float c0 = 0.f, c1 = 0.f;
    #pragma unroll
    for (int g = 0; g < 8; ++g) { c0 += cmP[g][t][0]; c1 += cmP[g][t][1]; }
    float dx = ped[8][t], dy = ped[9][t];
    float tx = fminf(fmaxf(dx * c0, -100.0f), 100.0f);
    float ty = fminf(fmaxf(dy * c1, -100.0f), 100.0f);
    const int r = rs[t];
    unsafeAtomicAdd(&agg[(size_t)r * 2], tx);
    unsafeAtomicAdd(&agg[(size_t)r * 2 + 1], ty);
    unsafeAtomicAdd(&cnt[r], 1.0f);
  }
}

__global__ __launch_bounds__(128) void node_pre_legacy(
    const float* __restrict__ h, const float* __restrict__ We1,
    const float* __restrict__ be1,
    const float* __restrict__ Wv1, const float* __restrict__ bv1,
    const float* __restrict__ Wv2, const float* __restrict__ bv2,
    float* __restrict__ Hr, float* __restrict__ Hc, float* __restrict__ velfac)
{
  const int j = threadIdx.x;
  const int n0 = blockIdx.x * 8;
  __shared__ __align__(16) float hl[128][8];
  __shared__ float vp[8][128];

  #pragma unroll
  for (int s = 0; s < 8; ++s) hl[j][s] = h[(size_t)(n0 + s) * 128 + j];
  __syncthreads();

  float aR[8], aC[8], aV[8];
  #pragma unroll
  for (int n = 0; n < 8; ++n) { aR[n] = 0.f; aC[n] = 0.f; aV[n] = 0.f; }

  for (int k = 0; k < 128; ++k) {
    float wr = We1[(size_t)k * 128 + j];
    float wc = We1[(size_t)(128 + k) * 128 + j];
    float wv = Wv1[(size_t)k * 128 + j];
    float4 h0 = *(const float4*)&hl[k][0];
    float4 h1 = *(const float4*)&hl[k][4];
    float hv[8] = {h0.x, h0.y, h0.z, h0.w, h1.x, h1.y, h1.z, h1.w};
    #pragma unroll
    for (int n = 0; n < 8; ++n) {
      aR[n] = fmaf(hv[n], wr, aR[n]);
      aC[n] = fmaf(hv[n], wc, aC[n]);
      aV[n] = fmaf(hv[n], wv, aV[n]);
    }
  }
  float b1 = be1[j], bv = bv1[j], w2 = Wv2[j];
  #pragma unroll
  for (int n = 0; n < 8; ++n) {
    Hr[(size_t)(n0 + n) * 128 + j] = aR[n] + b1;
    Hc[(size_t)(n0 + n) * 128 + j] = aC[n];
    vp[n][j] = RELU(aV[n] + bv) * w2;
  }
  __syncthreads();
  if (j < 8) {
    float s = 0.f;
    for (int k = 0; k < 128; ++k) s += vp[j][k];
    velfac[n0 + j] = s + bv2[0];
  }
}

__global__ __launch_bounds__(128) void node_final_legacy(
    const float* __restrict__ h, const float* __restrict__ coord,
    const float* __restrict__ vel,
    const float* __restrict__ Wn1, const float* __restrict__ bn1,
    const float* __restrict__ Wn2, const float* __restrict__ bn2,
    const float* __restrict__ agg, const float* __restrict__ cntbuf,
    const float* __restrict__ aggn, const float* __restrict__ velfac,
    float* __restrict__ hout, float* __restrict__ cout)
{
  const int j = threadIdx.x;
  const int n0 = blockIdx.x * 4;
  __shared__ __align__(16) float xl[256][4];
  __shared__ __align__(16) float tl[128][4];

  #pragma unroll
  for (int s = 0; s < 8; ++s) {
    int idx = s * 128 + j;
    int n = idx >> 8, k = idx & 255;
    float v = (k < 128) ? h[(size_t)(n0 + n) * 128 + k]
                        : aggn[(size_t)(n0 + n) * 128 + (k - 128)];
    xl[k][n] = v;
  }
  __syncthreads();
  float acc[4] = {0.f, 0.f, 0.f, 0.f};
  for (int k = 0; k < 256; ++k) {
    float w = Wn1[(size_t)k * 128 + j];
    float4 xv = *(const float4*)&xl[k][0];
    acc[0] = fmaf(xv.x, w, acc[0]);
    acc[1] = fmaf(xv.y, w, acc[1]);
    acc[2] = fmaf(xv.z, w, acc[2]);
    acc[3] = fmaf(xv.w, w, acc[3]);
  }
  float b = bn1[j];
  #pragma unroll
  for (int n = 0; n < 4; ++n) tl[j][n] = RELU(acc[n] + b);
  __syncthreads();
  float a2[4] = {0.f, 0.f, 0.f, 0.f};
  for (int k = 0; k < 128; ++k) {
    float w = Wn2[(size_t)k * 128 + j];
    float4 tv = *(const float4*)&tl[k][0];
    a2[0] = fmaf(tv.x, w, a2[0]);
    a2[1] = fmaf(tv.y, w, a2[1]);
    a2[2] = fmaf(tv.z, w, a2[2]);
    a2[3] = fmaf(tv.w, w, a2[3]);
  }
  float b2 = bn2[j];
  #pragma unroll
  for (int n = 0; n < 4; ++n)
    hout[(size_t)(n0 + n) * 128 + j] = h[(size_t)(n0 + n) * 128 + j] + a2[n] + b2;
  if (j < 8) {
    int n = j >> 1, d = j & 1;
    int node = n0 + n;
    float cdel = agg[(size_t)node * 2 + d] / fmaxf(cntbuf[node], 1.0f);
    cout[(size_t)node * 2 + d] =
        coord[(size_t)node * 2 + d] + cdel + velfac[node] * vel[(size_t)node * 2 + d];
  }
}

// ---------------------------------------------------------------------------
extern "C" void kernel_launch(void* const* d_in, const int* in_sizes, int n_in,
                              void* d_out, int out_size, void* d_ws, size_t ws_size,
                              hipStream_t stream)
{
  const float* h     = (const float*)d_in[0];
  const float* coord = (const float*)d_in[1];
  const float* vel   = (const float*)d_in[2];
  const float* We1   = (const float*)d_in[3];
  const float* be1   = (const float*)d_in[4];
  const float* We2   = (const float*)d_in[5];
  const float* be2   = (const float*)d_in[6];
  const float* Wc1   = (const float*)d_in[7];
  const float* bc1   = (const float*)d_in[8];
  const float* Wc2   = (const float*)d_in[9];
  const float* Wn1   = (const float*)d_in[10];
  const float* bn1   = (const float*)d_in[11];
  const float* Wn2   = (const float*)d_in[12];
  const float* bn2   = (const float*)d_in[13];
  const float* Wv1   = (const float*)d_in[14];
  const float* bv1   = (const float*)d_in[15];
  const float* Wv2   = (const float*)d_in[16];
  const float* bv2   = (const float*)d_in[17];
  const int*   ei    = (const int*)d_in[18];

  const int N = in_sizes[0] / 128;
  const int E = in_sizes[18] / 2;
  const int* row = ei;
  const int* col = ei + E;
  // int4-vectorizable iff E is a multiple of 4 (keeps row/col 16B-aligned views)
  const int E4 = ((E & 3) == 0) ? (E >> 2) : 0;

  char* base = (char*)d_ws;
  size_t off = 0;
  auto alloc = [&](size_t bytes) -> char* {
    char* p = base + off;
    off += (bytes + 255) & ~(size_t)255;
    return p;
  };
  float* Hr     = (float*)alloc((size_t)N * 128 * 4);
  float* Hc     = (float*)alloc((size_t)N * 128 * 4);
  float* velfac = (float*)alloc((size_t)N * 4);
  float* zblk   = (float*)alloc((size_t)132 * N * 4);  // deg|agg|cnt|aggn
  int*   deg    = (int*)zblk;
  float* agg    = zblk + N;
  float* cnt    = agg + (size_t)2 * N;
  float* aggn   = cnt + N;
  unsigned short* aggnb = (unsigned short*)aggn;
  int*   ptr    = (int*)alloc((size_t)(N + 1) * 4);
  int*   wptr   = (int*)alloc((size_t)N * 4);
  int2*  ecS    = (int2*)alloc((size_t)E * 8);
  float* trans  = (float*)alloc((size_t)E * 2 * 4);
  unsigned short* wfall = (unsigned short*)alloc((size_t)8 * 16384 * 2);
  int*   bsum   = (int*)alloc((size_t)1024 * 4);
  int*   boff   = (int*)alloc((size_t)1024 * 4);
  size_t fixed_end = off;
  unsigned short* efbuf = (unsigned short*)(base + fixed_end);

  unsigned short* WFe1r = wfall;
  unsigned short* WFe1c = wfall + 16384;
  unsigned short* WFv1  = wfall + 2 * 16384;
  unsigned short* WFe2  = wfall + 3 * 16384;
  unsigned short* WFc1  = wfall + 4 * 16384;
  unsigned short* WFn1a = wfall + 5 * 16384;
  unsigned short* WFn1b = wfall + 6 * 16384;
  unsigned short* WFn2  = wfall + 7 * 16384;

  const int nbS = (N + 1023) / 1024;
  int use_csr = 0, EC = 0, nch = 1;
  if (ws_size > fixed_end) {
    size_t ec_max = (ws_size - fixed_end) / 256;
    ec_max &= ~(size_t)31;
    if (ec_max >= 32768 && nbS <= 1024) {
      use_csr = 1;
      size_t e_pad = ((size_t)E + 31) & ~(size_t)31;
      EC = (int)((ec_max < e_pad) ? ec_max : e_pad);
      nch = (E + EC - 1) / EC;
    }
  }

  const int nblk32 = (N + 31) / 32;
  float* hout = (float*)d_out;
  float* cout = hout + (size_t)N * 128;

  if (use_csr) {
    hipMemsetAsync(deg, 0, (size_t)N * 4, stream);
    hipLaunchKernelGGL(deg_wprep_kernel, dim3(DEGB + 512), dim3(256), 0, stream,
                       row, deg, E, E4, We1, Wv1, We2, Wc1, Wn1, Wn2, wfall);
    hipLaunchKernelGGL(scan_sum_kernel, dim3(nbS), dim3(1024), 0, stream,
                       deg, bsum, N);
    hipLaunchKernelGGL(scan_off_kernel, dim3(1), dim3(1024), 0, stream,
                       bsum, boff, nbS);
    hipLaunchKernelGGL(scan_write_kernel, dim3(nbS), dim3(1024), 0, stream,
                       deg, boff, ptr, wptr, N, E);
    hipLaunchKernelGGL(scatter_nodepre_kernel, dim3(SCATB + nblk32), dim3(256), 0,
                       stream, row, col, wptr, ecS, E, E4,
                       h, WFe1r, WFe1c, WFv1, be1, bv1, Wv2, bv2,
                       Hr, Hc, velfac, N);
    if (nch == 1) {
      hipLaunchKernelGGL(edge_mfma_kernel, dim3((E + ET - 1) / ET), dim3(256), 0,
                         stream, ecS, Hr, Hc, coord, vel, We1,
                         WFe2, WFc1, be2, bc1, Wc2, efbuf, trans, 0, E);
      hipLaunchKernelGGL(gather_final_mfma, dim3(nblk32), dim3(256), 0, stream,
                         h, coord, vel, WFn1a, WFn1b, WFn2, bn1, bn2,
                         ptr, efbuf, trans, velfac, hout, cout, N);
    } else {
      for (int c = 0; c < nch; ++c) {
        int lo = c * EC;
        int hi = (lo + EC < E) ? lo + EC : E;
        int nb = (hi - lo + ET - 1) / ET;
        hipLaunchKernelGGL(edge_mfma_kernel, dim3(nb), dim3(256), 0, stream,
                           ecS, Hr, Hc, coord, vel, We1,
                           WFe2, WFc1, be2, bc1, Wc2, efbuf, trans, lo, hi);
        hipLaunchKernelGGL(gather_kernel, dim3((N + 3) / 4), dim3(256), 0, stream,
                           ptr, efbuf, trans, aggnb, agg, N, lo, hi, (c == 0) ? 1 : 0);
      }
      hipLaunchKernelGGL(node_final_mfma, dim3(nblk32), dim3(256), 0, stream,
                         h, coord, vel, WFn1a, WFn1b, WFn2, bn1, bn2,
                         agg, ptr, aggnb, velfac, hout, cout, N);
    }
  } else {
    hipMemsetAsync(zblk, 0, (size_t)132 * N * 4, stream);
    hipLaunchKernelGGL(node_pre_legacy, dim3(N / 8), dim3(128), 0, stream,
                       h, We1, be1, Wv1, bv1, Wv2, bv2, Hr, Hc, velfac);
    hipLaunchKernelGGL(edge_kernel_legacy, dim3((E + ET - 1) / ET), dim3(256), 0,
                       stream, row, col, Hr, Hc, coord, vel, We1, We2, be2,
                       Wc1, bc1, Wc2, agg, cnt, aggn, E);
    hipLaunchKernelGGL(node_final_legacy, dim3(N / 4), dim3(128), 0, stream,
                       h, coord, vel, Wn1, bn1, Wn2, bn2, agg, cnt,
                       aggn, velfac, hout, cout);
  }
}

// Round 15
// 479.417 us; speedup vs baseline: 1.4136x; 1.0032x over previous
//
#include <hip/hip_runtime.h>

#define RELU(x) fmaxf((x), 0.0f)

typedef __attribute__((ext_vector_type(2))) float f32x2;
typedef __attribute__((ext_vector_type(4))) short short4v;
typedef __attribute__((ext_vector_type(8))) short short8v;
typedef __attribute__((ext_vector_type(16))) float f32x16;

__device__ __forceinline__ float bf2f(unsigned short u) {
  unsigned v = ((unsigned)u) << 16;
  float f; __builtin_memcpy(&f, &v, 4); return f;
}
__device__ __forceinline__ unsigned short f2bf(float f) {
  unsigned u; __builtin_memcpy(&u, &f, 4);
  unsigned r = (u + 0x7FFFu + ((u >> 16) & 1u)) >> 16;
  return (unsigned short)r;
}
// HW packed convert: dst = {lo: bf16(a), hi: bf16(b)} (RNE).
__device__ __forceinline__ unsigned cvtpk(float a, float b) {
  unsigned r;
  asm("v_cvt_pk_bf16_f32 %0, %1, %2" : "=v"(r) : "v"(a), "v"(b));
  return r;
}
// packed f32 add: one instruction, two adds.
__device__ __forceinline__ f32x2 pk_add(f32x2 a, f32x2 b) {
  f32x2 d;
  asm("v_pk_add_f32 %0, %1, %2" : "=v"(d) : "v"(a), "v"(b));
  return d;
}
// unpack uint (2 bf16) -> f32 pair: lo = u<<16, hi = u & 0xFFFF0000.
__device__ __forceinline__ f32x2 unpk(unsigned u) {
  unsigned lo = u << 16, hi = u & 0xFFFF0000u;
  float fx, fy;
  __builtin_memcpy(&fx, &lo, 4);
  __builtin_memcpy(&fy, &hi, 4);
  f32x2 r = {fx, fy};
  return r;
}

// ---------------------------------------------------------------------------
// Fused: deg histogram (grid-stride, int4 loads) + wprep8.
// ---------------------------------------------------------------------------
#define DEGB 512

__global__ __launch_bounds__(256) void deg_wprep_kernel(
    const int* __restrict__ row, int* __restrict__ deg, int E, int E4,
    const float* __restrict__ We1, const float* __restrict__ Wv1,
    const float* __restrict__ We2, const float* __restrict__ Wc1,
    const float* __restrict__ Wn1, const float* __restrict__ Wn2,
    unsigned short* __restrict__ WF)
{
  if ((int)blockIdx.x < DEGB) {
    const int gs = DEGB * 256;
    const int base = blockIdx.x * 256 + threadIdx.x;
    const int4* row4 = (const int4*)row;
    for (int i = base; i < E4; i += gs) {
      int4 r = row4[i];
      atomicAdd(&deg[r.x], 1); atomicAdd(&deg[r.y], 1);
      atomicAdd(&deg[r.z], 1); atomicAdd(&deg[r.w], 1);
    }
    for (int i = (E4 << 2) + base; i < E; i += gs) atomicAdd(&deg[row[i]], 1);
    return;
  }
  const int bid = blockIdx.x - DEGB;
  const int g = bid >> 6;
  const int idx = (bid & 63) * 256 + threadIdx.x;
  const float* W;
  switch (g) {
    case 0: W = We1; break;
    case 1: W = We1 + 16384; break;
    case 2: W = Wv1; break;
    case 3: W = We2; break;
    case 4: W = Wc1; break;
    case 5: W = Wn1; break;
    case 6: W = Wn1 + 16384; break;
    default: W = Wn2; break;
  }
  int j = idx & 7, l = (idx >> 3) & 63, s = (idx >> 9) & 7, n = idx >> 12;
  int k = s * 16 + ((l >> 5) << 3) + j;
  int c = n * 32 + (l & 31);
  WF[g * 16384 + idx] = f2bf(W[k * 128 + c]);
}

// ---------------------------------------------------------------------------
// Parallel scan: 3 small kernels (partial sums -> block offsets -> write).
// ---------------------------------------------------------------------------
__global__ __launch_bounds__(1024) void scan_sum_kernel(
    const int* __restrict__ deg, int* __restrict__ bsum, int N)
{
  __shared__ int s[1024];
  const int t = threadIdx.x;
  const int i = blockIdx.x * 1024 + t;
  s[t] = (i < N) ? deg[i] : 0;
  __syncthreads();
  for (int off = 512; off >= 1; off >>= 1) {
    if (t < off) s[t] += s[t + off];
    __syncthreads();
  }
  if (t == 0) bsum[blockIdx.x] = s[0];
}

__global__ __launch_bounds__(1024) void scan_off_kernel(
    const int* __restrict__ bsum, int* __restrict__ boff, int nb)
{
  __shared__ int s[2][1024];
  const int t = threadIdx.x;
  s[0][t] = (t < nb) ? bsum[t] : 0;
  __syncthreads();
  int src = 0;
  for (int off = 1; off < 1024; off <<= 1) {
    int v = s[src][t];
    if (t >= off) v += s[src][t - off];
    s[src ^ 1][t] = v;
    __syncthreads();
    src ^= 1;
  }
  if (t < nb) boff[t] = t ? s[src][t - 1] : 0;
}

__global__ __launch_bounds__(1024) void scan_write_kernel(
    const int* __restrict__ deg, const int* __restrict__ boff,
    int* __restrict__ ptr, int* __restrict__ wptr, int N, int E)
{
  __shared__ int s[2][1024];
  const int t = threadIdx.x;
  const int i = blockIdx.x * 1024 + t;
  s[0][t] = (i < N) ? deg[i] : 0;
  __syncthreads();
  int src = 0;
  for (int off = 1; off < 1024; off <<= 1) {
    int v = s[src][t];
    if (t >= off) v += s[src][t - off];
    s[src ^ 1][t] = v;
    __syncthreads();
    src ^= 1;
  }
  if (i < N) {
    int ex = boff[blockIdx.x] + (t ? s[src][t - 1] : 0);
    ptr[i] = ex;
    wptr[i] = ex;
  }
  if (blockIdx.x == 0 && t == 0) ptr[N] = E;
}

// ---------------------------------------------------------------------------
// Fused: scatter (grid-stride int4, writes SORTED int2 pairs) + node_pre MFMA.
// ---------------------------------------------------------------------------
#define SCATB 512

__global__ __launch_bounds__(256, 4) void scatter_nodepre_kernel(
    const int* __restrict__ row, const int* __restrict__ col,
    int* __restrict__ wptr, int2* __restrict__ ecS, int E, int E4,
    const float* __restrict__ h,
    const unsigned short* __restrict__ WFe1r,
    const unsigned short* __restrict__ WFe1c,
    const unsigned short* __restrict__ WFv1,
    const float* __restrict__ be1, const float* __restrict__ bv1,
    const float* __restrict__ Wv2, const float* __restrict__ bv2,
    float* __restrict__ Hr, float* __restrict__ Hc, float* __restrict__ velfac,
    int N)
{
  __shared__ __align__(16) unsigned short Ah[4096];
  __shared__ float Wv2s[128];
  __shared__ float vpart[32][4];

  if ((int)blockIdx.x < SCATB) {
    const int gs = SCATB * 256;
    const int base = blockIdx.x * 256 + threadIdx.x;
    const int4* row4 = (const int4*)row;
    const int4* col4 = (const int4*)col;
    for (int i = base; i < E4; i += gs) {
      int4 r = row4[i];
      int4 c = col4[i];
      int p0 = atomicAdd(&wptr[r.x], 1); ecS[p0] = make_int2(r.x, c.x);
      int p1 = atomicAdd(&wptr[r.y], 1); ecS[p1] = make_int2(r.y, c.y);
      int p2 = atomicAdd(&wptr[r.z], 1); ecS[p2] = make_int2(r.z, c.z);
      int p3 = atomicAdd(&wptr[r.w], 1); ecS[p3] = make_int2(r.w, c.w);
    }
    for (int i = (E4 << 2) + base; i < E; i += gs) {
      int r = row[i];
      int p = atomicAdd(&wptr[r], 1);
      ecS[p] = make_int2(r, col[i]);
    }
    return;
  }
  const int t = threadIdx.x, wv = t >> 6, lane = t & 63;
  const int n0 = (blockIdx.x - SCATB) * 32;

  if (t < 128) Wv2s[t] = Wv2[t];
  {
    const int e = t >> 3, kc = (t & 7) << 4;
    const int n = n0 + e;
    unsigned pk[8];
    if (n < N) {
      const float* hp = h + (size_t)n * 128 + kc;
      #pragma unroll
      for (int qc = 0; qc < 4; ++qc) {
        float4 v = *(const float4*)(hp + qc * 4);
        pk[qc * 2] = cvtpk(v.x, v.y); pk[qc * 2 + 1] = cvtpk(v.z, v.w);
      }
    } else {
      #pragma unroll
      for (int q = 0; q < 8; ++q) pk[q] = 0u;
    }
    const int sw = e << 2, rb = e << 7;
    #pragma unroll
    for (int q = 0; q < 4; ++q)
      *(uint2*)&Ah[rb + ((kc + 4 * q) ^ sw)] = make_uint2(pk[2 * q], pk[2 * q + 1]);
  }
  __syncthreads();

  const int eA = lane & 31, khalf = (lane >> 5) << 3, swA = eA << 2;
  const int baseA = eA << 7;
  f32x16 aR = {0.f}, aC = {0.f}, aV = {0.f};
  const unsigned short* b1 = WFe1r + ((wv << 12) | (lane << 3));
  const unsigned short* b2 = WFe1c + ((wv << 12) | (lane << 3));
  const unsigned short* b3 = WFv1 + ((wv << 12) | (lane << 3));
  #pragma unroll
  for (int s = 0; s < 8; ++s) {
    const int k1 = s * 16 + khalf;
    short4v a0 = *(const short4v*)&Ah[baseA + (k1 ^ swA)];
    short4v a1 = *(const short4v*)&Ah[baseA + ((k1 + 4) ^ swA)];
    short8v z = __builtin_shufflevector(a0, a1, 0, 1, 2, 3, 4, 5, 6, 7);
    aR = __builtin_amdgcn_mfma_f32_32x32x16_bf16(z, *(const short8v*)(b1 + (s << 9)), aR, 0, 0, 0);
    aC = __builtin_amdgcn_mfma_f32_32x32x16_bf16(z, *(const short8v*)(b2 + (s << 9)), aC, 0, 0, 0);
    aV = __builtin_amdgcn_mfma_f32_32x32x16_bf16(z, *(const short8v*)(b3 + (s << 9)), aV, 0, 0, 0);
  }
  const int colb = (wv << 5) | (lane & 31);
  const float be1j = be1[colb], bv1j = bv1[colb], wv2j = Wv2s[colb];
  const int ebase = (lane >> 5) << 2;
  #pragma unroll
  for (int r = 0; r < 16; ++r) {
    const int e = (r & 3) + 8 * (r >> 2) + ebase;
    const int n = n0 + e;
    if (n < N) {
      Hr[(size_t)n * 128 + colb] = aR[r] + be1j;
      Hc[(size_t)n * 128 + colb] = aC[r];
    }
    float v = RELU(aV[r] + bv1j) * wv2j;
    v += __shfl_xor(v, 1); v += __shfl_xor(v, 2); v += __shfl_xor(v, 4);
    v += __shfl_xor(v, 8); v += __shfl_xor(v, 16);
    if ((lane & 31) == 0) vpart[e][wv] = v;
  }
  __syncthreads();
  if (t < 32) {
    const int n = n0 + t;
    if (n < N)
      velfac[n] = vpart[t][0] + vpart[t][1] + vpart[t][2] + vpart[t][3] + bv2[0];
  }
}

// ---------------------------------------------------------------------------
// Edge kernel (MFMA) — R14 structure verbatim (234 µs proven).
// ---------------------------------------------------------------------------
#define ET 32

__global__ __launch_bounds__(256, 4) void edge_mfma_kernel(
    const int2* __restrict__ ecS,
    const float* __restrict__ Hr, const float* __restrict__ Hc,
    const float* __restrict__ coord, const float* __restrict__ vel,
    const float* __restrict__ We1,
    const unsigned short* __restrict__ WFe2,
    const unsigned short* __restrict__ WFc1,
    const float* __restrict__ be2, const float* __restrict__ bc1,
    const float* __restrict__ Wc2,
    unsigned short* __restrict__ efbuf, float* __restrict__ transbuf,
    int lo, int hi)
{
  const int t    = threadIdx.x;
  const int wv   = t >> 6;
  const int lane = t & 63;
  const int iblk = lo + blockIdx.x * ET;

  __shared__ __align__(16) unsigned short Z4[4 * 4096];
  __shared__ __align__(16) float Wc2s[256];
  __shared__ float ped[11][32];
  __shared__ int rs[32], cs[32];
  __shared__ float cmE[32][2];

  if (t < ET) {
    int i = iblk + t;
    int r = 0, c = 0;
    if (i < hi) { int2 rc = ecS[i]; r = rc.x; c = rc.y; }
    rs[t] = r; cs[t] = c;
    float2 cr = *(const float2*)&coord[2 * r];
    float2 cc = *(const float2*)&coord[2 * c];
    float2 vr = *(const float2*)&vel[2 * r];
    float2 vc = *(const float2*)&vel[2 * c];
    ped[0][t] = cr.x; ped[1][t] = cr.y; ped[2][t] = cc.x; ped[3][t] = cc.y;
    ped[4][t] = vr.x; ped[5][t] = vr.y;
    ped[6][t] = vc.x; ped[7][t] = vc.y;
    float dx = cr.x - cc.x, dy = cr.y - cc.y;
    ped[8][t] = dx; ped[9][t] = dy; ped[10][t] = dx * dx + dy * dy;
  }
  Wc2s[t] = Wc2[t];
  __syncthreads();

  // ---- Z-compute: 4 k's (kq) x 4 edges (eg) per thread ----
  {
    const int kq = t & 31;
    const int eg = t >> 5;
    const int kc = kq << 2;
    float4 w0 = *(const float4*)&We1[(size_t)(256 + 0) * 128 + kc];
    float4 w1 = *(const float4*)&We1[(size_t)(256 + 1) * 128 + kc];
    float4 w2 = *(const float4*)&We1[(size_t)(256 + 2) * 128 + kc];
    float4 w3 = *(const float4*)&We1[(size_t)(256 + 3) * 128 + kc];
    float4 w4 = *(const float4*)&We1[(size_t)(256 + 4) * 128 + kc];
    float4 w5 = *(const float4*)&We1[(size_t)(256 + 5) * 128 + kc];
    float4 w6 = *(const float4*)&We1[(size_t)(256 + 6) * 128 + kc];
    float4 w7 = *(const float4*)&We1[(size_t)(256 + 7) * 128 + kc];
    float4 w8 = *(const float4*)&We1[(size_t)(256 + 8) * 128 + kc];
    float wa0[4] = {w0.x, w0.y, w0.z, w0.w};
    float wa1[4] = {w1.x, w1.y, w1.z, w1.w};
    float wa2[4] = {w2.x, w2.y, w2.z, w2.w};
    float wa3[4] = {w3.x, w3.y, w3.z, w3.w};
    float wa4[4] = {w4.x, w4.y, w4.z, w4.w};
    float wa5[4] = {w5.x, w5.y, w5.z, w5.w};
    float wa6[4] = {w6.x, w6.y, w6.z, w6.w};
    float wa7[4] = {w7.x, w7.y, w7.z, w7.w};
    float wa8[4] = {w8.x, w8.y, w8.z, w8.w};
    #pragma unroll
    for (int ee = 0; ee < 4; ++ee) {
      const int e = (eg << 2) + ee;
      const int r = rs[e], c = cs[e];
      float4 h4 = *(const float4*)(Hr + (size_t)r * 128 + kc);
      float4 c4 = *(const float4*)(Hc + (size_t)c * 128 + kc);
      float hb[4] = {h4.x, h4.y, h4.z, h4.w};
      float cb[4] = {c4.x, c4.y, c4.z, c4.w};
      const float xr = ped[0][e], yr = ped[1][e], xc = ped[2][e], yc = ped[3][e];
      const float vrx = ped[4][e], vry = ped[5][e], vcx = ped[6][e], vcy = ped[7][e];
      const float d2 = ped[10][e];
      float z0[4], z1[4], z2[4], z3[4];
      #pragma unroll
      for (int m = 0; m < 4; ++m) {
        float base = fmaf(d2, wa4[m], hb[m] + cb[m]);
        float A = fmaf(xr, wa0[m], fmaf(xc, wa2[m], fmaf(vrx, wa5[m], vcx * wa7[m])));
        float B = fmaf(yr, wa1[m], fmaf(yc, wa3[m], fmaf(vry, wa6[m], vcy * wa8[m])));
        float bp = base + A, bm = base - A;
        z0[m] = RELU(bp + B);
        z1[m] = RELU(bm - B);
        z2[m] = RELU(bm + B);
        z3[m] = RELU(bp - B);
      }
      const int ia = (e << 7) + (kc ^ (e << 2));
      *(uint2*)&Z4[ia]         = make_uint2(cvtpk(z0[0], z0[1]), cvtpk(z0[2], z0[3]));
      *(uint2*)&Z4[4096 + ia]  = make_uint2(cvtpk(z1[0], z1[1]), cvtpk(z1[2], z1[3]));
      *(uint2*)&Z4[8192 + ia]  = make_uint2(cvtpk(z2[0], z2[1]), cvtpk(z2[2], z2[3]));
      *(uint2*)&Z4[12288 + ia] = make_uint2(cvtpk(z3[0], z3[1]), cvtpk(z3[2], z3[3]));
    }
  }
  __syncthreads();

  // ---- stage 1: 4 groups x 8 K-steps of 32x32x16 MFMA ----
  const int eA    = lane & 31;
  const int khalf = (lane >> 5) << 3;
  const int swA   = eA << 2;
  const int baseA = eA << 7;
  f32x16 ac0 = {0.f}, ac1 = {0.f}, ac2 = {0.f}, ac3 = {0.f};
  {
    const unsigned short* WFw = WFe2 + ((wv << 12) | (lane << 3));
    #pragma unroll
    for (int s = 0; s < 8; ++s) {
      short8v bw = *(const short8v*)(WFw + (s << 9));
      const int k1 = s * 16 + khalf;
      const int i0 = baseA + (k1 ^ swA);
      const int i1 = baseA + ((k1 + 4) ^ swA);
      short8v z0 = __builtin_shufflevector(*(const short4v*)&Z4[i0],
                                           *(const short4v*)&Z4[i1], 0,1,2,3,4,5,6,7);
      short8v z1 = __builtin_shufflevector(*(const short4v*)&Z4[4096 + i0],
                                           *(const short4v*)&Z4[4096 + i1], 0,1,2,3,4,5,6,7);
      short8v z2 = __builtin_shufflevector(*(const short4v*)&Z4[8192 + i0],
                                           *(const short4v*)&Z4[8192 + i1], 0,1,2,3,4,5,6,7);
      short8v z3 = __builtin_shufflevector(*(const short4v*)&Z4[12288 + i0],
                                           *(const short4v*)&Z4[12288 + i1], 0,1,2,3,4,5,6,7);
      ac0 = __builtin_amdgcn_mfma_f32_32x32x16_bf16(z0, bw, ac0, 0, 0, 0);
      ac1 = __builtin_amdgcn_mfma_f32_32x32x16_bf16(z1, bw, ac1, 0, 0, 0);
      ac2 = __builtin_amdgcn_mfma_f32_32x32x16_bf16(z2, bw, ac2, 0, 0, 0);
      ac3 = __builtin_amdgcn_mfma_f32_32x32x16_bf16(z3, bw, ac3, 0, 0, 0);
    }
  }
  __syncthreads();   // all Z4 reads done; region 0 -> ef, region 1 -> tv

  // ---- ef = 0.25 * sum_g relu(out_g + be2) -> LDS bf16 (cvtpk pairs) ----
  {
    const int j = (wv << 5) | (lane & 31);
    const float be2j = be2[j];
    const int ebase = (lane >> 5) << 2;
    #pragma unroll
    for (int q = 0; q < 8; ++q) {
      const int r0 = 2 * q;
      float v0 = RELU(ac0[r0] + be2j) + RELU(ac1[r0] + be2j) +
                 RELU(ac2[r0] + be2j) + RELU(ac3[r0] + be2j);
      float v1 = RELU(ac0[r0 + 1] + be2j) + RELU(ac1[r0 + 1] + be2j) +
                 RELU(ac2[r0 + 1] + be2j) + RELU(ac3[r0 + 1] + be2j);
      unsigned p = cvtpk(0.25f * v0, 0.25f * v1);
      const int e0_ = (r0 & 3) + 8 * (r0 >> 2) + ebase;
      const int e1_ = e0_ + 1;
      Z4[(e0_ << 7) + (j ^ (e0_ << 2))] = (unsigned short)p;
      Z4[(e1_ << 7) + (j ^ (e1_ << 2))] = (unsigned short)(p >> 16);
    }
  }
  __syncthreads();

  // ---- write efbuf (global, coalesced) ----
  {
    const int e  = t >> 3;
    const int kc = (t & 7) << 4;
    int i = iblk + e;
    if (i < hi) {
      const int sw = e << 2, rb = e << 7;
      uint2 c0 = *(const uint2*)&Z4[rb + ((kc + 0) ^ sw)];
      uint2 c1 = *(const uint2*)&Z4[rb + ((kc + 4) ^ sw)];
      uint2 c2 = *(const uint2*)&Z4[rb + ((kc + 8) ^ sw)];
      uint2 c3 = *(const uint2*)&Z4[rb + ((kc + 12) ^ sw)];
      *(uint4*)&efbuf[(size_t)(i - lo) * 128 + kc]     = make_uint4(c0.x, c0.y, c1.x, c1.y);
      *(uint4*)&efbuf[(size_t)(i - lo) * 128 + kc + 8] = make_uint4(c2.x, c2.y, c3.x, c3.y);
    }
  }

  // ---- stage 2: EF @ Wc1 ----
  f32x16 a2 = {0.f};
  {
    const unsigned short* WFc = WFc1 + ((wv << 12) | (lane << 3));
    #pragma unroll
    for (int s = 0; s < 8; ++s) {
      short8v bw = *(const short8v*)(WFc + (s << 9));
      const int k1 = s * 16 + khalf;
      const int i0 = baseA + (k1 ^ swA);
      const int i1 = baseA + ((k1 + 4) ^ swA);
      short8v af = __builtin_shufflevector(*(const short4v*)&Z4[i0],
                                           *(const short4v*)&Z4[i1], 0,1,2,3,4,5,6,7);
      a2 = __builtin_amdgcn_mfma_f32_32x32x16_bf16(af, bw, a2, 0, 0, 0);
    }
  }
  // ---- tv = relu(a2 + bc1) -> LDS region 1 (cvtpk pairs) ----
  {
    const int j = (wv << 5) | (lane & 31);
    const float bc1j = bc1[j];
    const int ebase = (lane >> 5) << 2;
    #pragma unroll
    for (int q = 0; q < 8; ++q) {
      const int r0 = 2 * q;
      unsigned p = cvtpk(RELU(a2[r0] + bc1j), RELU(a2[r0 + 1] + bc1j));
      const int e0_ = (r0 & 3) + 8 * (r0 >> 2) + ebase;
      const int e1_ = e0_ + 1;
      Z4[4096 + (e0_ << 7) + (j ^ (e0_ << 2))] = (unsigned short)p;
      Z4[4096 + (e1_ << 7) + (j ^ (e1_ << 2))] = (unsigned short)(p >> 16);
    }
  }
  __syncthreads();

  // ---- cm[e] = tv[e][:] @ Wc2 : 8 threads/edge, shfl reduce ----
  {
    const int e  = t >> 3;
    const int jc = (t & 7) << 4;
    const int sw = e << 2, rb = e << 7;
    uint2 d0 = *(const uint2*)&Z4[4096 + rb + ((jc + 0) ^ sw)];
    uint2 d1 = *(const uint2*)&Z4[4096 + rb + ((jc + 4) ^ sw)];
    uint2 d2 = *(const uint2*)&Z4[4096 + rb + ((jc + 8) ^ sw)];
    uint2 d3 = *(const uint2*)&Z4[4096 + rb + ((jc + 12) ^ sw)];
    unsigned uu[8] = {d0.x, d0.y, d1.x, d1.y, d2.x, d2.y, d3.x, d3.y};
    float cx = 0.f, cy = 0.f;
    #pragma unroll
    for (int q = 0; q < 8; ++q) {
      float t0 = bf2f((unsigned short)(uu[q] & 0xFFFFu));
      float t1 = bf2f((unsigned short)(uu[q] >> 16));
      float2 wA = *(const float2*)&Wc2s[2 * (jc + 2 * q)];
      float2 wB = *(const float2*)&Wc2s[2 * (jc + 2 * q + 1)];
      cx = fmaf(t0, wA.x, cx); cy = fmaf(t0, wA.y, cy);
      cx = fmaf(t1, wB.x, cx); cy = fmaf(t1, wB.y, cy);
    }
    cx += __shfl_xor(cx, 1); cy += __shfl_xor(cy, 1);
    cx += __shfl_xor(cx, 2); cy += __shfl_xor(cy, 2);
    cx += __shfl_xor(cx, 4); cy += __shfl_xor(cy, 4);
    if ((t & 7) == 0) { cmE[e][0] = cx; cmE[e][1] = cy; }
  }
  __syncthreads();
  if (t < ET) {
    int i = iblk + t;
    if (i < hi) {
      float tx = fminf(fmaxf(ped[8][t] * cmE[t][0], -100.0f), 100.0f);
      float ty = fminf(fmaxf(ped[9][t] * cmE[t][1], -100.0f), 100.0f);
      transbuf[(size_t)i * 2]     = tx;
      transbuf[(size_t)i * 2 + 1] = ty;
    }
  }
}

// ---------------------------------------------------------------------------
// Fused gather + node_final (nch==1). pk_add accumulation; occupancy hint.
// ---------------------------------------------------------------------------
__global__ __launch_bounds__(256, 4) void gather_final_mfma(
    const float* __restrict__ h, const float* __restrict__ coord,
    const float* __restrict__ vel,
    const unsigned short* __restrict__ WFn1a,
    const unsigned short* __restrict__ WFn1b,
    const unsigned short* __restrict__ WFn2,
    const float* __restrict__ bn1, const float* __restrict__ bn2,
    const int* __restrict__ ptr, const unsigned short* __restrict__ efbuf,
    const float* __restrict__ transbuf, const float* __restrict__ velfac,
    float* __restrict__ hout, float* __restrict__ cout, int N)
{
  const int t = threadIdx.x, wv = t >> 6, lane = t & 63;
  const int n0 = blockIdx.x * 32;
  __shared__ __align__(16) unsigned short Ah[4096];
  __shared__ __align__(16) unsigned short Ag[4096];
  __shared__ __align__(16) unsigned short Mid[4096];
  __shared__ float trs[32][2];

  {
    const int e = t >> 3, kc = (t & 7) << 4;
    const int n = n0 + e;
    const int sw = (e & 15) << 3, rb = e << 7;
    unsigned pk[8];
    f32x2 ac2[8];
    #pragma unroll
    for (int q = 0; q < 8; ++q) { f32x2 z = {0.f, 0.f}; ac2[q] = z; }
    float tx = 0.f, ty = 0.f;
    if (n < N) {
      const float* hp = h + (size_t)n * 128 + kc;
      #pragma unroll
      for (int qc = 0; qc < 4; ++qc) {
        float4 v = *(const float4*)(hp + qc * 4);
        pk[qc * 2] = cvtpk(v.x, v.y); pk[qc * 2 + 1] = cvtpk(v.z, v.w);
      }
      const int p0 = ptr[n], p1 = ptr[n + 1];
      for (int i = p0; i < p1; ++i) {
        uint4 a = *(const uint4*)&efbuf[(size_t)i * 128 + kc];
        uint4 b = *(const uint4*)&efbuf[(size_t)i * 128 + kc + 8];
        unsigned uu[8] = {a.x, a.y, a.z, a.w, b.x, b.y, b.z, b.w};
        #pragma unroll
        for (int q = 0; q < 8; ++q) ac2[q] = pk_add(ac2[q], unpk(uu[q]));
      }
      for (int i = p0 + (t & 7); i < p1; i += 8) {
        tx += transbuf[(size_t)i * 2];
        ty += transbuf[(size_t)i * 2 + 1];
      }
    } else {
      #pragma unroll
      for (int q = 0; q < 8; ++q) pk[q] = 0u;
    }
    tx += __shfl_xor(tx, 1); ty += __shfl_xor(ty, 1);
    tx += __shfl_xor(tx, 2); ty += __shfl_xor(ty, 2);
    tx += __shfl_xor(tx, 4); ty += __shfl_xor(ty, 4);
    if ((t & 7) == 0) { trs[e][0] = tx; trs[e][1] = ty; }
    *(uint4*)&Ah[rb + (kc ^ sw)]       = make_uint4(pk[0], pk[1], pk[2], pk[3]);
    *(uint4*)&Ah[rb + ((kc + 8) ^ sw)] = make_uint4(pk[4], pk[5], pk[6], pk[7]);
    unsigned gk[8];
    #pragma unroll
    for (int q = 0; q < 8; ++q) gk[q] = cvtpk(ac2[q].x, ac2[q].y);
    *(uint4*)&Ag[rb + (kc ^ sw)]       = make_uint4(gk[0], gk[1], gk[2], gk[3]);
    *(uint4*)&Ag[rb + ((kc + 8) ^ sw)] = make_uint4(gk[4], gk[5], gk[6], gk[7]);
  }
  __syncthreads();

  const int eA = lane & 31, khalf = (lane >> 5) << 3, swA = (eA & 15) << 3;
  const int baseA = eA << 7;
  f32x16 m = {0.f};
  {
    const unsigned short* p1 = WFn1a + ((wv << 12) | (lane << 3));
    const unsigned short* p2 = WFn1b + ((wv << 12) | (lane << 3));
    #pragma unroll
    for (int s = 0; s < 8; ++s) {
      const int i0 = baseA + ((s * 16 + khalf) ^ swA);
      short8v zh = *(const short8v*)&Ah[i0];
      short8v zg = *(const short8v*)&Ag[i0];
      m = __builtin_amdgcn_mfma_f32_32x32x16_bf16(zh, *(const short8v*)(p1 + (s << 9)), m, 0, 0, 0);
      m = __builtin_amdgcn_mfma_f32_32x32x16_bf16(zg, *(const short8v*)(p2 + (s << 9)), m, 0, 0, 0);
    }
  }
  const int colb = (wv << 5) | (lane & 31);
  const float bn1j = bn1[colb];
  const int ebase = (lane >> 5) << 2;
  #pragma unroll
  for (int r = 0; r < 16; ++r) {
    const int e = (r & 3) + 8 * (r >> 2) + ebase;
    Mid[(e << 7) + (colb ^ ((e & 15) << 3))] = f2bf(RELU(m[r] + bn1j));
  }
  __syncthreads();

  f32x16 o = {0.f};
  {
    const unsigned short* p3 = WFn2 + ((wv << 12) | (lane << 3));
    #pragma unroll
    for (int s = 0; s < 8; ++s) {
      const int i0 = baseA + ((s * 16 + khalf) ^ swA);
      short8v zm = *(const short8v*)&Mid[i0];
      o = __builtin_amdgcn_mfma_f32_32x32x16_bf16(zm, *(const short8v*)(p3 + (s << 9)), o, 0, 0, 0);
    }
  }
  const float bn2j = bn2[colb];
  #pragma unroll
  for (int r = 0; r < 16; ++r) {
    const int e = (r & 3) + 8 * (r >> 2) + ebase;
    const int n = n0 + e;
    if (n < N)
      hout[(size_t)n * 128 + colb] = h[(size_t)n * 128 + colb] + o[r] + bn2j;
  }
  if (t < 32) {
    const int n = n0 + t;
    if (n < N) {
      float c = (float)(ptr[n + 1] - ptr[n]);
      float vf = velfac[n];
      float inv = 1.0f / fmaxf(c, 1.0f);
      cout[(size_t)n * 2]     = coord[(size_t)n * 2]     + trs[t][0] * inv + vf * vel[(size_t)n * 2];
      cout[(size_t)n * 2 + 1] = coord[(size_t)n * 2 + 1] + trs[t][1] * inv + vf * vel[(size_t)n * 2 + 1];
    }
  }
}

// ---------------------------------------------------------------------------
// Chunked fallback (nch>1): gather + node_final.
// ---------------------------------------------------------------------------
__global__ __launch_bounds__(256) void gather_kernel(
    const int* __restrict__ ptr, const unsigned short* __restrict__ efbuf,
    const float* __restrict__ transbuf,
    unsigned short* __restrict__ aggnb, float* __restrict__ agg,
    int N, int lo, int hi, int first)
{
  const int wv = threadIdx.x >> 6, lane = threadIdx.x & 63;
  const int n = blockIdx.x * 4 + wv;
  if (n >= N) return;
  const int p0 = ptr[n], p1 = ptr[n + 1];
  const int a = p0 > lo ? p0 : lo;
  const int b = p1 < hi ? p1 : hi;
  const int sub = lane >> 4, c8 = (lane & 15) << 3;
  f32x2 ac2[4];
  #pragma unroll
  for (int q = 0; q < 4; ++q) { f32x2 z = {0.f, 0.f}; ac2[q] = z; }
  for (int i = a + sub; i < b; i += 4) {
    uint4 v = *(const uint4*)&efbuf[(size_t)(i - lo) * 128 + c8];
    unsigned uu[4] = {v.x, v.y, v.z, v.w};
    #pragma unroll
    for (int q = 0; q < 4; ++q) ac2[q] = pk_add(ac2[q], unpk(uu[q]));
  }
  #pragma unroll
  for (int q = 0; q < 4; ++q) {
    ac2[q].x += __shfl_xor(ac2[q].x, 16);
    ac2[q].y += __shfl_xor(ac2[q].y, 16);
    ac2[q].x += __shfl_xor(ac2[q].x, 32);
    ac2[q].y += __shfl_xor(ac2[q].y, 32);
  }
  if (lane < 16) {
    if (!first) {
      uint4 old = *(const uint4*)&aggnb[(size_t)n * 128 + c8];
      unsigned uo[4] = {old.x, old.y, old.z, old.w};
      #pragma unroll
      for (int q = 0; q < 4; ++q) ac2[q] = pk_add(ac2[q], unpk(uo[q]));
    }
    unsigned pk[4];
    #pragma unroll
    for (int q = 0; q < 4; ++q) pk[q] = cvtpk(ac2[q].x, ac2[q].y);
    *(uint4*)&aggnb[(size_t)n * 128 + c8] = make_uint4(pk[0], pk[1], pk[2], pk[3]);
  }
  if (lane < 2) {
    float tacc = first ? 0.f : agg[(size_t)n * 2 + lane];
    for (int i = a; i < b; ++i) tacc += transbuf[(size_t)i * 2 + lane];
    agg[(size_t)n * 2 + lane] = tacc;
  }
}

__global__ __launch_bounds__(256) void node_final_mfma(
    const float* __restrict__ h, const float* __restrict__ coord,
    const float* __restrict__ vel,
    const unsigned short* __restrict__ WFn1a,
    const unsigned short* __restrict__ WFn1b,
    const unsigned short* __restrict__ WFn2,
    const float* __restrict__ bn1, const float* __restrict__ bn2,
    const float* __restrict__ agg, const int* __restrict__ ptr,
    const unsigned short* __restrict__ aggnb, const float* __restrict__ velfac,
    float* __restrict__ hout, float* __restrict__ cout, int N)
{
  const int t = threadIdx.x, wv = t >> 6, lane = t & 63;
  const int n0 = blockIdx.x * 32;
  __shared__ __align__(16) unsigned short Ah[4096];
  __shared__ __align__(16) unsigned short Ag[4096];
  __shared__ __align__(16) unsigned short Mid[4096];

  {
    const int e = t >> 3, kc = (t & 7) << 4;
    const int n = n0 + e;
    unsigned pk[8], gk[8];
    if (n < N) {
      const float* hp = h + (size_t)n * 128 + kc;
      #pragma unroll
      for (int qc = 0; qc < 4; ++qc) {
        float4 v = *(const float4*)(hp + qc * 4);
        pk[qc * 2] = cvtpk(v.x, v.y); pk[qc * 2 + 1] = cvtpk(v.z, v.w);
      }
      uint4 g0 = *(const uint4*)&aggnb[(size_t)n * 128 + kc];
      uint4 g1 = *(const uint4*)&aggnb[(size_t)n * 128 + kc + 8];
      gk[0] = g0.x; gk[1] = g0.y; gk[2] = g0.z; gk[3] = g0.w;
      gk[4] = g1.x; gk[5] = g1.y; gk[6] = g1.z; gk[7] = g1.w;
    } else {
      #pragma unroll
      for (int q = 0; q < 8; ++q) { pk[q] = 0u; gk[q] = 0u; }
    }
    const int sw = (e & 15) << 3, rb = e << 7;
    *(uint4*)&Ah[rb + (kc ^ sw)]       = make_uint4(pk[0], pk[1], pk[2], pk[3]);
    *(uint4*)&Ah[rb + ((kc + 8) ^ sw)] = make_uint4(pk[4], pk[5], pk[6], pk[7]);
    *(uint4*)&Ag[rb + (kc ^ sw)]       = make_uint4(gk[0], gk[1], gk[2], gk[3]);
    *(uint4*)&Ag[rb + ((kc + 8) ^ sw)] = make_uint4(gk[4], gk[5], gk[6], gk[7]);
  }
  __syncthreads();

  const int eA = lane & 31, khalf = (lane >> 5) << 3, swA = (eA & 15) << 3;
  const int baseA = eA << 7;
  f32x16 m = {0.f};
  {
    const unsigned short* p1 = WFn1a + ((wv << 12) | (lane << 3));
    const unsigned short* p2 = WFn1b + ((wv << 12) | (lane << 3));
    #pragma unroll
    for (int s = 0; s < 8; ++s) {
      const int i0 = baseA + ((s * 16 + khalf) ^ swA);
      short8v zh = *(const short8v*)&Ah[i0];
      short8v zg = *(const short8v*)&Ag[i0];
      m = __builtin_amdgcn_mfma_f32_32x32x16_bf16(zh, *(const short8v*)(p1 + (s << 9)), m, 0, 0, 0);
      m = __builtin_amdgcn_mfma_f32_32x32x16_bf16(zg, *(const short8v*)(p2 + (s << 9)), m, 0, 0, 0);
    }
  }
  const int colb = (wv << 5) | (lane & 31);
  const float bn1j = bn1[colb];
  const int ebase = (lane >> 5) << 2;
  #pragma unroll
  for (int r = 0; r < 16; ++r) {
    const int e = (r & 3) + 8 * (r >> 2) + ebase;
    Mid[(e << 7) + (colb ^ ((e & 15) << 3))] = f2bf(RELU(m[r] + bn1j));
  }
  __syncthreads();

  f32x16 o = {0.f};
  {
    const unsigned short* p3 = WFn2 + ((wv << 12) | (lane << 3));
    #pragma unroll
    for (int s = 0; s < 8; ++s) {
      const int i0 = baseA + ((s * 16 + khalf) ^ swA);
      short8v zm = *(const short8v*)&Mid[i0];
      o = __builtin_amdgcn_mfma_f32_32x32x16_bf16(zm, *(const short8v*)(p3 + (s << 9)), o, 0, 0, 0);
    }
  }
  const float bn2j = bn2[colb];
  #pragma unroll
  for (int r = 0; r < 16; ++r) {
    const int e = (r & 3) + 8 * (r >> 2) + ebase;
    const int n = n0 + e;
    if (n < N)
      hout[(size_t)n * 128 + colb] = h[(size_t)n * 128 + colb] + o[r] + bn2j;
  }
  if (t < 32) {
    const int n = n0 + t;
    if (n < N) {
      float c = (float)(ptr[n + 1] - ptr[n]);
      float vf = velfac[n];
      float inv = 1.0f / fmaxf(c, 1.0f);
      cout[(size_t)n * 2]     = coord[(size_t)n * 2]     + agg[(size_t)n * 2] * inv     + vf * vel[(size_t)n * 2];
      cout[(size_t)n * 2 + 1] = coord[(size_t)n * 2 + 1] + agg[(size_t)n * 2 + 1] * inv + vf * vel[(size_t)n * 2 + 1];
    }
  }
}

// ---------------------------------------------------------------------------
// Legacy fp32 fallback kernels (ws too small for efbuf).
// ---------------------------------------------------------------------------
__global__ __launch_bounds__(256) void edge_kernel_legacy(
    const int* __restrict__ row, const int* __restrict__ col,
    const float* __restrict__ Hr, const float* __restrict__ Hc,
    const float* __restrict__ coord, const float* __restrict__ vel,
    const float* __restrict__ We1, const float* __restrict__ We2,
    const float* __restrict__ be2, const float* __restrict__ Wc1,
    const float* __restrict__ bc1, const float* __restrict__ Wc2,
    float* __restrict__ agg, float* __restrict__ cnt, float* __restrict__ aggn,
    int E)
{
  const int t  = threadIdx.x;
  const int el = t & 31;
  const int jg = t >> 5;
  const int j0 = jg * 16;
  const int e0 = blockIdx.x * ET;

  __shared__ __align__(16) float Wch[32][128];
  __shared__ __align__(16) float Zbuf[4256];
  __shared__ __align__(16) float W9[9][128];
  __shared__ float ped[11][32];
  __shared__ int   rs[32], cs[32], vE[32];
  __shared__ float cmP[8][32][2];

#define Z4L(g, e_, k_) Zbuf[((g) * 32 + (e_)) * 33 + (k_)]
#define EFL(e_, k_)    Zbuf[(e_) * 133 + (k_)]

  if (t < ET) {
    int e = e0 + t;
    int r = 0, c = 0, v = 0;
    if (e < E) { r = row[e]; c = col[e]; v = 1; }
    rs[t] = r; cs[t] = c; vE[t] = v;
    float crx = coord[2 * r], cry = coord[2 * r + 1];
    float ccx = coord[2 * c], ccy = coord[2 * c + 1];
    ped[0][t] = crx; ped[1][t] = cry; ped[2][t] = ccx; ped[3][t] = ccy;
    ped[4][t] = vel[2 * r]; ped[5][t] = vel[2 * r + 1];
    ped[6][t] = vel[2 * c]; ped[7][t] = vel[2 * c + 1];
    float dx = crx - ccx, dy = cry - ccy;
    ped[8][t] = dx; ped[9][t] = dy; ped[10][t] = dx * dx + dy * dy;
  }
  for (int idx = t; idx < 9 * 128; idx += 256)
    W9[idx >> 7][idx & 127] = We1[(size_t)(256 + (idx >> 7)) * 128 + (idx & 127)];

  float outg[4][16];
  #pragma unroll
  for (int g = 0; g < 4; ++g)
    #pragma unroll
    for (int jj = 0; jj < 16; ++jj) outg[g][jj] = 0.0f;

  for (int kc = 0; kc < 4; ++kc) {
    const int kb = kc * 32;
    __syncthreads();
    #pragma unroll
    for (int s = 0; s < 4; ++s) {
      int idx4 = t + s * 256;
      int kl = idx4 >> 5, jc = (idx4 & 31) * 4;
      *(float4*)&Wch[kl][jc] = *(const float4*)&We2[(size_t)(kb + kl) * 128 + jc];
    }
    {
      const int kk = kb + (jg << 2);
      const int kl = jg << 2;
      const int r = rs[el], c = cs[el];
      float4 a4 = *(const float4*)(Hr + (size_t)r * 128 + kk);
      float4 b4 = *(const float4*)(Hc + (size_t)c * 128 + kk);
      float hr[4] = {a4.x, a4.y, a4.z, a4.w};
      float hcv[4] = {b4.x, b4.y, b4.z, b4.w};
      float4 q;
      q = *(const float4*)&W9[0][kk]; float w0[4] = {q.x, q.y, q.z, q.w};
      q = *(const float4*)&W9[1][kk]; float w1[4] = {q.x, q.y, q.z, q.w};
      q = *(const float4*)&W9[2][kk]; float w2[4] = {q.x, q.y, q.z, q.w};
      q = *(const float4*)&W9[3][kk]; float w3[4] = {q.x, q.y, q.z, q.w};
      q = *(const float4*)&W9[4][kk]; float w4[4] = {q.x, q.y, q.z, q.w};
      q = *(const float4*)&W9[5][kk]; float w5[4] = {q.x, q.y, q.z, q.w};
      q = *(const float4*)&W9[6][kk]; float w6[4] = {q.x, q.y, q.z, q.w};
      q = *(const float4*)&W9[7][kk]; float w7[4] = {q.x, q.y, q.z, q.w};
      q = *(const float4*)&W9[8][kk]; float w8[4] = {q.x, q.y, q.z, q.w};
      float xr = ped[0][el], yr = ped[1][el], xc = ped[2][el], yc = ped[3][el];
      float vrx = ped[4][el], vry = ped[5][el], vcx = ped[6][el], vcy = ped[7][el];
      float d2 = ped[10][el];
      #pragma unroll
      for (int i = 0; i < 4; ++i) {
        float base = hr[i] + hcv[i] + d2 * w4[i];
        float A = xr * w0[i] + xc * w2[i] + vrx * w5[i] + vcx * w7[i];
        float B = yr * w1[i] + yc * w3[i] + vry * w6[i] + vcy * w8[i];
        Z4L(0, el, kl + i) = RELU(base + A + B);
        Z4L(1, el, kl + i) = RELU(base - A - B);
        Z4L(2, el, kl + i) = RELU(base - A + B);
        Z4L(3, el, kl + i) = RELU(base + A - B);
      }
    }
    __syncthreads();
    #pragma unroll 2
    for (int k = 0; k < 32; ++k) {
      float4 wa = *(const float4*)&Wch[k][j0];
      float4 wb = *(const float4*)&Wch[k][j0 + 4];
      float4 wc4 = *(const float4*)&Wch[k][j0 + 8];
      float4 wd = *(const float4*)&Wch[k][j0 + 12];
      float w[16] = {wa.x, wa.y, wa.z, wa.w, wb.x, wb.y, wb.z, wb.w,
                     wc4.x, wc4.y, wc4.z, wc4.w, wd.x, wd.y, wd.z, wd.w};
      float z0 = Z4L(0, el, k), z1 = Z4L(1, el, k);
      float z2 = Z4L(2, el, k), z3 = Z4L(3, el, k);
      #pragma unroll
      for (int jj = 0; jj < 16; ++jj) {
        outg[0][jj] = fmaf(z0, w[jj], outg[0][jj]);
        outg[1][jj] = fmaf(z1, w[jj], outg[1][jj]);
        outg[2][jj] = fmaf(z2, w[jj], outg[2][jj]);
        outg[3][jj] = fmaf(z3, w[jj], outg[3][jj]);
      }
    }
  }

  __syncthreads();
  float4 q0 = *(const float4*)(be2 + j0);
  float4 q1 = *(const float4*)(be2 + j0 + 4);
  float4 q2 = *(const float4*)(be2 + j0 + 8);
  float4 q3 = *(const float4*)(be2 + j0 + 12);
  float beA[16] = {q0.x, q0.y, q0.z, q0.w, q1.x, q1.y, q1.z, q1.w,
                   q2.x, q2.y, q2.z, q2.w, q3.x, q3.y, q3.z, q3.w};
  float ef[16];
  #pragma unroll
  for (int jj = 0; jj < 16; ++jj) {
    float s = RELU(outg[0][jj] + beA[jj]) + RELU(outg[1][jj] + beA[jj]) +
              RELU(outg[2][jj] + beA[jj]) + RELU(outg[3][jj] + beA[jj]);
    ef[jj] = 0.25f * s;
  }
  #pragma unroll
  for (int jj = 0; jj < 16; ++jj) EFL(el, j0 + jj) = ef[jj];
  {
    const int r = rs[el];
    if (vE[el]) {
      #pragma unroll
      for (int jj = 0; jj < 16; ++jj)
        unsafeAtomicAdd(&aggn[(size_t)r * 128 + j0 + jj], ef[jj]);
    }
  }

  float acc2[16];
  #pragma unroll
  for (int jj = 0; jj < 16; ++jj) acc2[jj] = 0.0f;
  for (int kc = 0; kc < 4; ++kc) {
    const int kb = kc * 32;
    __syncthreads();
    #pragma unroll
    for (int s = 0; s < 4; ++s) {
      int idx4 = t + s * 256;
      int kl = idx4 >> 5, jc = (idx4 & 31) * 4;
      *(float4*)&Wch[kl][jc] = *(const float4*)&Wc1[(size_t)(kb + kl) * 128 + jc];
    }
    __syncthreads();
    #pragma unroll 4
    for (int k = 0; k < 32; ++k) {
      float4 wa = *(const float4*)&Wch[k][j0];
      float4 wb = *(const float4*)&Wch[k][j0 + 4];
      float4 wc4 = *(const float4*)&Wch[k][j0 + 8];
      float4 wd = *(const float4*)&Wch[k][j0 + 12];
      float w[16] = {wa.x, wa.y, wa.z, wa.w, wb.x, wb.y, wb.z, wb.w,
                     wc4.x, wc4.y, wc4.z, wc4.w, wd.x, wd.y, wd.z, wd.w};
      float efk = EFL(el, kb + k);
      #pragma unroll
      for (int jj = 0; jj < 16; ++jj) acc2[jj] = fmaf(efk, w[jj], acc2[jj]);
    }
  }

  float cm0 = 0.f, cm1 = 0.f;
  #pragma unroll
  for (int jj = 0; jj < 16; ++jj) {
    float tv = RELU(acc2[jj] + bc1[j0 + jj]);
    float2 wp = *(const float2*)(Wc2 + 2 * (j0 + jj));
    cm0 = fmaf(tv, wp.x, cm0);
    cm1 = fmaf(tv, wp.y, cm1);
  }
  cmP[jg][el][0] = cm0; cmP[jg][el][1] = cm1;
  __syncthreads();
  if (t < ET && vE[t]) {
    float c0 = 0.f, c1 = 0.f;
    #pragma unroll
    for (int g = 0; g < 8; ++g) { c0 += cmP[g][t][0]; c1 += cmP[g][t][1]; }
    float dx = ped[8][t], dy = ped[9][t];
    float tx = fminf(fmaxf(dx * c0, -100.0f), 100.0f);
    float ty = fminf(fmaxf(dy * c1, -100.0f), 100.0f);
    const int r = rs[t];
    unsafeAtomicAdd(&agg[(size_t)r * 2], tx);
    unsafeAtomicAdd(&agg[(size_t)r * 2 + 1], ty);
    unsafeAtomicAdd(&cnt[r], 1.0f);
  }
}

__global__ __launch_bounds__(128) void node_pre_legacy(
    const float* __restrict__ h, const float* __restrict__ We1,
    const float* __restrict__ be1,
    const float* __restrict__ Wv1, const float* __restrict__ bv1,
    const float* __restrict__ Wv2, const float* __restrict__ bv2,
    float* __restrict__ Hr, float* __restrict__ Hc, float* __restrict__ velfac)
{
  const int j = threadIdx.x;
  const int n0 = blockIdx.x * 8;
  __shared__ __align__(16) float hl[128][8];
  __shared__ float vp[8][128];

  #pragma unroll
  for (int s = 0; s < 8; ++s) hl[j][s] = h[(size_t)(n0 + s) * 128 + j];
  __syncthreads();

  float aR[8], aC[8], aV[8];
  #pragma unroll
  for (int n = 0; n < 8; ++n) { aR[n] = 0.f; aC[n] = 0.f; aV[n] = 0.f; }

  for (int k = 0; k < 128; ++k) {
    float wr = We1[(size_t)k * 128 + j];
    float wc = We1[(size_t)(128 + k) * 128 + j];
    float wv = Wv1[(size_t)k * 128 + j];
    float4 h0 = *(const float4*)&hl[k][0];
    float4 h1 = *(const float4*)&hl[k][4];
    float hv[8] = {h0.x, h0.y, h0.z, h0.w, h1.x, h1.y, h1.z, h1.w};
    #pragma unroll
    for (int n = 0; n < 8; ++n) {
      aR[n] = fmaf(hv[n], wr, aR[n]);
      aC[n] = fmaf(hv[n], wc, aC[n]);
      aV[n] = fmaf(hv[n], wv, aV[n]);
    }
  }
  float b1 = be1[j], bv = bv1[j], w2 = Wv2[j];
  #pragma unroll
  for (int n = 0; n < 8; ++n) {
    Hr[(size_t)(n0 + n) * 128 + j] = aR[n] + b1;
    Hc[(size_t)(n0 + n) * 128 + j] = aC[n];
    vp[n][j] = RELU(aV[n] + bv) * w2;
  }
  __syncthreads();
  if (j < 8) {
    float s = 0.f;
    for (int k = 0; k < 128; ++k) s += vp[j][k];
    velfac[n0 + j] = s + bv2[0];
  }
}

__global__ __launch_bounds__(128) void node_final_legacy(
    const float* __restrict__ h, const float* __restrict__ coord,
    const float* __restrict__ vel,
    const float* __restrict__ Wn1, const float* __restrict__ bn1,
    const float* __restrict__ Wn2, const float* __restrict__ bn2,
    const float* __restrict__ agg, const float* __restrict__ cntbuf,
    const float* __restrict__ aggn, const float* __restrict__ velfac,
    float* __restrict__ hout, float* __restrict__ cout)
{
  const int j = threadIdx.x;
  const int n0 = blockIdx.x * 4;
  __shared__ __align__(16) float xl[256][4];
  __shared__ __align__(16) float tl[128][4];

  #pragma unroll
  for (int s = 0; s < 8; ++s) {
    int idx = s * 128 + j;
    int n = idx >> 8, k = idx & 255;
    float v = (k < 128) ? h[(size_t)(n0 + n) * 128 + k]
                        : aggn[(size_t)(n0 + n) * 128 + (k - 128)];
    xl[k][n] = v;
  }
  __syncthreads();
  float acc[4] = {0.f, 0.f, 0.f, 0.f};
  for (int k = 0; k < 256; ++k) {
    float w = Wn1[(size_t)k * 128 + j];
    float4 xv = *(const float4*)&xl[k][0];
    acc[0] = fmaf(xv.x, w, acc[0]);
    acc[1] = fmaf(xv.y, w, acc[1]);
    acc[2] = fmaf(xv.z, w, acc[2]);
    acc[3] = fmaf(xv.w, w, acc[3]);
  }
  float b = bn1[j];
  #pragma unroll
  for (int n = 0; n < 4; ++n) tl[j][n] = RELU(acc[n] + b);
  __syncthreads();
  float a2[4] = {0.f, 0.f, 0.f, 0.f};
  for (int k = 0; k < 128; ++k) {
    float w = Wn2[(size_t)k * 128 + j];
    float4 tv = *(const float4*)&tl[k][0];
    a2[0] = fmaf(tv.x, w, a2[0]);
    a2[1] = fmaf(tv.y, w, a2[1]);
    a2[2] = fmaf(tv.z, w, a2[2]);
    a2[3] = fmaf(tv.w, w, a2[3]);
  }
  float b2 = bn2[j];
  #pragma unroll
  for (int n = 0; n < 4; ++n)
    hout[(size_t)(n0 + n) * 128 + j] = h[(size_t)(n0 + n) * 128 + j] + a2[n] + b2;
  if (j < 8) {
    int n = j >> 1, d = j & 1;
    int node = n0 + n;
    float cdel = agg[(size_t)node * 2 + d] / fmaxf(cntbuf[node], 1.0f);
    cout[(size_t)node * 2 + d] =
        coord[(size_t)node * 2 + d] + cdel + velfac[node] * vel[(size_t)node * 2 + d];
  }
}

// ---------------------------------------------------------------------------
extern "C" void kernel_launch(void* const* d_in, const int* in_sizes, int n_in,
                              void* d_out, int out_size, void* d_ws, size_t ws_size,
                              hipStream_t stream)
{
  const float* h     = (const float*)d_in[0];
  const float* coord = (const float*)d_in[1];
  const float* vel   = (const float*)d_in[2];
  const float* We1   = (const float*)d_in[3];
  const float* be1   = (const float*)d_in[4];
  const float* We2   = (const float*)d_in[5];
  const float* be2   = (const float*)d_in[6];
  const float* Wc1   = (const float*)d_in[7];
  const float* bc1   = (const float*)d_in[8];
  const float* Wc2   = (const float*)d_in[9];
  const float* Wn1   = (const float*)d_in[10];
  const float* bn1   = (const float*)d_in[11];
  const float* Wn2   = (const float*)d_in[12];
  const float* bn2   = (const float*)d_in[13];
  const float* Wv1   = (const float*)d_in[14];
  const float* bv1   = (const float*)d_in[15];
  const float* Wv2   = (const float*)d_in[16];
  const float* bv2   = (const float*)d_in[17];
  const int*   ei    = (const int*)d_in[18];

  const int N = in_sizes[0] / 128;
  const int E = in_sizes[18] / 2;
  const int* row = ei;
  const int* col = ei + E;
  // int4-vectorizable iff E is a multiple of 4 (keeps row/col 16B-aligned views)
  const int E4 = ((E & 3) == 0) ? (E >> 2) : 0;

  char* base = (char*)d_ws;
  size_t off = 0;
  auto alloc = [&](size_t bytes) -> char* {
    char* p = base + off;
    off += (bytes + 255) & ~(size_t)255;
    return p;
  };
  float* Hr     = (float*)alloc((size_t)N * 128 * 4);
  float* Hc     = (float*)alloc((size_t)N * 128 * 4);
  float* velfac = (float*)alloc((size_t)N * 4);
  float* zblk   = (float*)alloc((size_t)132 * N * 4);  // deg|agg|cnt|aggn
  int*   deg    = (int*)zblk;
  float* agg    = zblk + N;
  float* cnt    = agg + (size_t)2 * N;
  float* aggn   = cnt + N;
  unsigned short* aggnb = (unsigned short*)aggn;
  int*   ptr    = (int*)alloc((size_t)(N + 1) * 4);
  int*   wptr   = (int*)alloc((size_t)N * 4);
  int2*  ecS    = (int2*)alloc((size_t)E * 8);
  float* trans  = (float*)alloc((size_t)E * 2 * 4);
  unsigned short* wfall = (unsigned short*)alloc((size_t)8 * 16384 * 2);
  int*   bsum   = (int*)alloc((size_t)1024 * 4);
  int*   boff   = (int*)alloc((size_t)1024 * 4);
  size_t fixed_end = off;
  unsigned short* efbuf = (unsigned short*)(base + fixed_end);

  unsigned short* WFe1r = wfall;
  unsigned short* WFe1c = wfall + 16384;
  unsigned short* WFv1  = wfall + 2 * 16384;
  unsigned short* WFe2  = wfall + 3 * 16384;
  unsigned short* WFc1  = wfall + 4 * 16384;
  unsigned short* WFn1a = wfall + 5 * 16384;
  unsigned short* WFn1b = wfall + 6 * 16384;
  unsigned short* WFn2  = wfall + 7 * 16384;

  const int nbS = (N + 1023) / 1024;
  int use_csr = 0, EC = 0, nch = 1;
  if (ws_size > fixed_end) {
    size_t ec_max = (ws_size - fixed_end) / 256;
    ec_max &= ~(size_t)31;
    if (ec_max >= 32768 && nbS <= 1024) {
      use_csr = 1;
      size_t e_pad = ((size_t)E + 31) & ~(size_t)31;
      EC = (int)((ec_max < e_pad) ? ec_max : e_pad);
      nch = (E + EC - 1) / EC;
    }
  }

  const int nblk32 = (N + 31) / 32;
  float* hout = (float*)d_out;
  float* cout = hout + (size_t)N * 128;

  if (use_csr) {
    hipMemsetAsync(deg, 0, (size_t)N * 4, stream);
    hipLaunchKernelGGL(deg_wprep_kernel, dim3(DEGB + 512), dim3(256), 0, stream,
                       row, deg, E, E4, We1, Wv1, We2, Wc1, Wn1, Wn2, wfall);
    hipLaunchKernelGGL(scan_sum_kernel, dim3(nbS), dim3(1024), 0, stream,
                       deg, bsum, N);
    hipLaunchKernelGGL(scan_off_kernel, dim3(1), dim3(1024), 0, stream,
                       bsum, boff, nbS);
    hipLaunchKernelGGL(scan_write_kernel, dim3(nbS), dim3(1024), 0, stream,
                       deg, boff, ptr, wptr, N, E);
    hipLaunchKernelGGL(scatter_nodepre_kernel, dim3(SCATB + nblk32), dim3(256), 0,
                       stream, row, col, wptr, ecS, E, E4,
                       h, WFe1r, WFe1c, WFv1, be1, bv1, Wv2, bv2,
                       Hr, Hc, velfac, N);
    if (nch == 1) {
      hipLaunchKernelGGL(edge_mfma_kernel, dim3((E + ET - 1) / ET), dim3(256), 0,
                         stream, ecS, Hr, Hc, coord, vel, We1,
                         WFe2, WFc1, be2, bc1, Wc2, efbuf, trans, 0, E);
      hipLaunchKernelGGL(gather_final_mfma, dim3(nblk32), dim3(256), 0, stream,
                         h, coord, vel, WFn1a, WFn1b, WFn2, bn1, bn2,
                         ptr, efbuf, trans, velfac, hout, cout, N);
    } else {
      for (int c = 0; c < nch; ++c) {
        int lo = c * EC;
        int hi = (lo + EC < E) ? lo + EC : E;
        int nb = (hi - lo + ET - 1) / ET;
        hipLaunchKernelGGL(edge_mfma_kernel, dim3(nb), dim3(256), 0, stream,
                           ecS, Hr, Hc, coord, vel, We1,
                           WFe2, WFc1, be2, bc1, Wc2, efbuf, trans, lo, hi);
        hipLaunchKernelGGL(gather_kernel, dim3((N + 3) / 4), dim3(256), 0, stream,
                           ptr, efbuf, trans, aggnb, agg, N, lo, hi, (c == 0) ? 1 : 0);
      }
      hipLaunchKernelGGL(node_final_mfma, dim3(nblk32), dim3(256), 0, stream,
                         h, coord, vel, WFn1a, WFn1b, WFn2, bn1, bn2,
                         agg, ptr, aggnb, velfac, hout, cout, N);
    }
  } else {
    hipMemsetAsync(zblk, 0, (size_t)132 * N * 4, stream);
    hipLaunchKernelGGL(node_pre_legacy, dim3(N / 8), dim3(128), 0, stream,
                       h, We1, be1, Wv1, bv1, Wv2, bv2, Hr, Hc, velfac);
    hipLaunchKernelGGL(edge_kernel_legacy, dim3((E + ET - 1) / ET), dim3(256), 0,
                       stream, row, col, Hr, Hc, coord, vel, We1, We2, be2,
                       Wc1, bc1, Wc2, agg, cnt, aggn, E);
    hipLaunchKernelGGL(node_final_legacy, dim3(N / 4), dim3(128), 0, stream,
                       h, coord, vel, Wn1, bn1, Wn2, bn2, agg, cnt,
                       aggn, velfac, hout, cout);
  }
}